// Round 9
// baseline (799.100 us; speedup 1.0000x reference)
//
#include <hip/hip_runtime.h>
#include <hip/hip_bf16.h>
#include <cmath>

#define CDIV(a, b) (((a) + (b) - 1) / (b))

typedef __attribute__((ext_vector_type(8))) short bf16x8;
typedef __attribute__((ext_vector_type(4))) short s16x4;
typedef __attribute__((ext_vector_type(4))) float f32x4;

__device__ __forceinline__ short f2bf(float f) {
    unsigned u = __float_as_uint(f);
    unsigned r = (u + 0x7fff + ((u >> 16) & 1)) >> 16;
    return (short)r;
}
__device__ __forceinline__ float bf2f(short s) {
    return __uint_as_float(((unsigned)(unsigned short)s) << 16);
}

__device__ __forceinline__ void gll16(const void* g, void* l) {
    __builtin_amdgcn_global_load_lds((const __attribute__((address_space(1))) void*)g,
                                     (__attribute__((address_space(3))) void*)l, 16, 0, 0);
}

// ---------------------------------------------------------------------------
// Fusion v3: 4 channels x 8 pixels per thread, uniform border handling via
// address-clamped neighbor chunks + selects (no scalar border path).
// TIN: 0 fp32, 1 bf16 NCHW input. Output fp32 NCHW.
// ---------------------------------------------------------------------------
template <int TIN>
__global__ void fusionC_kernel(const void* __restrict__ featv,
                               const float* __restrict__ kv,
                               const float* __restrict__ kh,
                               const float* __restrict__ m,
                               float* __restrict__ out,
                               int B, int C, int H, int W, int total) {
    int idx = blockIdx.x * blockDim.x + threadIdx.x;
    if (idx >= total) return;
    int Wg = W >> 3;
    int C4 = C >> 2;
    int g = idx % Wg;
    int cg = (idx / Wg) % C4;
    int y = (idx / (Wg * C4)) % H;
    int b = idx / (Wg * C4 * H);
    int x0 = g << 3, c0 = cg << 2;
    int HW = H * W;

    int ry[5];
#pragma unroll
    for (int i = 0; i < 5; ++i) {
        int t = y + i - 2;
        ry[i] = t < 0 ? 0 : (t >= H ? H - 1 : t);
    }
    bool hasL = (g > 0), hasR = (g < Wg - 1);
    int offL = hasL ? -8 : 0;
    int offR = hasR ? 8 : 0;

    const float* kvb = kv + ((size_t)b * 5 * H + y) * W + x0;
    const float* khb = kh + ((size_t)b * 5 * H + y) * W + x0;
    float kvv[5][8], khv[5][8];
#pragma unroll
    for (int i = 0; i < 5; ++i) {
        f32x4 a0 = *(const f32x4*)(kvb + (size_t)i * HW);
        f32x4 a1 = *(const f32x4*)(kvb + (size_t)i * HW + 4);
        f32x4 h0 = *(const f32x4*)(khb + (size_t)i * HW);
        f32x4 h1 = *(const f32x4*)(khb + (size_t)i * HW + 4);
#pragma unroll
        for (int o = 0; o < 4; ++o) {
            kvv[i][o] = a0[o]; kvv[i][o + 4] = a1[o];
            khv[i][o] = h0[o]; khv[i][o + 4] = h1[o];
        }
    }
    float m8[8];
    {
        const float* mp = m + ((size_t)b * H + y) * W + x0;
        f32x4 q0 = *(const f32x4*)mp;
        f32x4 q1 = *(const f32x4*)(mp + 4);
#pragma unroll
        for (int o = 0; o < 4; ++o) { m8[o] = q0[o]; m8[o + 4] = q1[o]; }
    }

#pragma unroll
    for (int cc = 0; cc < 4; ++cc) {
        size_t plane = (size_t)(b * C + c0 + cc) * HW;
        const float* fpf = (const float*)featv + plane;
        const short* fpb = (const short*)featv + plane;
        float acc[8];
        float ctr[8];
#pragma unroll
        for (int o = 0; o < 8; ++o) acc[o] = 0.f;

#pragma unroll
        for (int i = 0; i < 5; ++i) {
            float w12[12];
            if (TIN == 1) {
                const short* row = fpb + (size_t)ry[i] * W + x0;
                bf16x8 Bv = *(const bf16x8*)(row);
                bf16x8 Av = *(const bf16x8*)(row + offL);
                bf16x8 Cv = *(const bf16x8*)(row + offR);
                short w12s[12];
                w12s[0] = hasL ? Av[6] : Bv[0];
                w12s[1] = hasL ? Av[7] : Bv[0];
#pragma unroll
                for (int k = 0; k < 8; ++k) w12s[2 + k] = Bv[k];
                w12s[10] = hasR ? Cv[0] : Bv[7];
                w12s[11] = hasR ? Cv[1] : Bv[7];
#pragma unroll
                for (int k = 0; k < 12; ++k) w12[k] = bf2f(w12s[k]);
            } else {
                const float* row = fpf + (size_t)ry[i] * W + x0;
                f32x4 B0 = *(const f32x4*)(row);
                f32x4 B1 = *(const f32x4*)(row + 4);
                f32x4 A1 = *(const f32x4*)(row + offL + 4);
                f32x4 C0 = *(const f32x4*)(row + offR);
                w12[0] = hasL ? A1[2] : B0[0];
                w12[1] = hasL ? A1[3] : B0[0];
#pragma unroll
                for (int k = 0; k < 4; ++k) { w12[2 + k] = B0[k]; w12[6 + k] = B1[k]; }
                w12[10] = hasR ? C0[0] : B1[3];
                w12[11] = hasR ? C0[1] : B1[3];
            }
            if (i == 2) {
#pragma unroll
                for (int o = 0; o < 8; ++o) ctr[o] = w12[o + 2];
            }
#pragma unroll
            for (int o = 0; o < 8; ++o) {
                float r = 0.f;
#pragma unroll
                for (int j = 0; j < 5; ++j) r = fmaf(khv[j][o], w12[o + j], r);
                acc[o] = fmaf(kvv[i][o], r, acc[o]);
            }
        }
        f32x4 o0, o1;
#pragma unroll
        for (int o = 0; o < 4; ++o) {
            o0[o] = m8[o] * acc[o] + (1.f - m8[o]) * ctr[o];
            o1[o] = m8[o + 4] * acc[o + 4] + (1.f - m8[o + 4]) * ctr[o + 4];
        }
        float* op = out + plane + (size_t)y * W + x0;
        *(f32x4*)(op) = o0;
        *(f32x4*)(op + 4) = o1;
    }
}

// scalar-C fusion for C=3 final output, bf16 input (round-6 proven)
__global__ void fusion4b_kernel(const short* __restrict__ feat,
                                const float* __restrict__ kv,
                                const float* __restrict__ kh,
                                const float* __restrict__ m,
                                float* __restrict__ out,
                                int B, int C, int H, int W, int total) {
    int idx = blockIdx.x * blockDim.x + threadIdx.x;
    if (idx >= total) return;
    int Wg = W >> 2;
    int g = idx % Wg;
    int y = (idx / Wg) % H;
    int c = (idx / (Wg * H)) % C;
    int b = idx / (Wg * H * C);
    int x0 = g << 2;
    int HW = H * W;

    const short* fp = feat + (size_t)(b * C + c) * HW;
    int yy[5];
#pragma unroll
    for (int i = 0; i < 5; ++i) {
        int t = y + i - 2;
        yy[i] = t < 0 ? 0 : (t >= H ? H - 1 : t);
    }
    const float* kvb = kv + ((size_t)b * 5 * H + y) * W + x0;
    const float* khb = kh + ((size_t)b * 5 * H + y) * W + x0;

    f32x4 res, c4;
    if (g >= 1 && g <= Wg - 2) {
        f32x4 kvv[5], khv[5];
#pragma unroll
        for (int i = 0; i < 5; ++i) {
            kvv[i] = *(const f32x4*)(kvb + (size_t)i * HW);
            khv[i] = *(const f32x4*)(khb + (size_t)i * HW);
        }
        f32x4 acc = (f32x4){0.f, 0.f, 0.f, 0.f};
#pragma unroll
        for (int i = 0; i < 5; ++i) {
            const short* row = fp + (size_t)yy[i] * W + x0;
            s16x4 Lv = *(const s16x4*)(row - 4);
            s16x4 Cv = *(const s16x4*)(row);
            s16x4 Rv = *(const s16x4*)(row + 4);
            float w8[8] = {bf2f(Lv[2]), bf2f(Lv[3]), bf2f(Cv[0]), bf2f(Cv[1]),
                           bf2f(Cv[2]), bf2f(Cv[3]), bf2f(Rv[0]), bf2f(Rv[1])};
            if (i == 2) { c4[0] = w8[2]; c4[1] = w8[3]; c4[2] = w8[4]; c4[3] = w8[5]; }
#pragma unroll
            for (int o = 0; o < 4; ++o) {
                float r = 0.f;
#pragma unroll
                for (int j = 0; j < 5; ++j) r = fmaf(khv[j][o], w8[o + j], r);
                acc[o] = fmaf(kvv[i][o], r, acc[o]);
            }
        }
        res = acc;
    } else {
#pragma unroll
        for (int o = 0; o < 4; ++o) {
            int x = x0 + o;
            int xx[5];
#pragma unroll
            for (int j = 0; j < 5; ++j) {
                int u = x + j - 2;
                xx[j] = u < 0 ? 0 : (u >= W ? W - 1 : u);
            }
            float acc = 0.f;
#pragma unroll
            for (int i = 0; i < 5; ++i) {
                float r = 0.f;
#pragma unroll
                for (int j = 0; j < 5; ++j)
                    r = fmaf(khb[(size_t)j * HW + o], bf2f(fp[(size_t)yy[i] * W + xx[j]]), r);
                acc = fmaf(kvb[(size_t)i * HW + o], r, acc);
            }
            res[o] = acc;
            c4[o] = bf2f(fp[(size_t)y * W + x]);
        }
    }
    f32x4 m4 = *(const f32x4*)(m + ((size_t)b * H + y) * W + x0);
    f32x4 o4;
#pragma unroll
    for (int o = 0; o < 4; ++o) o4[o] = m4[o] * res[o] + (1.f - m4[o]) * c4[o];
    *(f32x4*)(out + ((size_t)(b * C + c) * H + y) * W + x0) = o4;
}

// ---------------------------------------------------------------------------
// Pad v2 (round-6 verified): line-complete both sides. xp fastest, then c8.
// ---------------------------------------------------------------------------
__global__ void pad_kernel(const float* __restrict__ in, short* __restrict__ pin,
                           int C, int H, int W, int Hp, int Wp, int po,
                           int xt, int nxt) {
    int b = blockIdx.z, yp = blockIdx.y;
    int ct = 256 / xt;
    int xtile = blockIdx.x % nxt;
    int cb = blockIdx.x / nxt;
    int xl = threadIdx.x % xt;
    int cl = threadIdx.x / xt;
    int xp = xtile * xt + xl;
    int c8 = cb * ct + cl;
    if (xp >= Wp) return;

    int y = yp - po, x = xp - po;
    bf16x8 v;
    if (y >= 0 && y < H && x >= 0 && x < W) {
        const float* ip = in + ((size_t)(b * C + c8 * 8) * H + y) * W + x;
        size_t HW = (size_t)H * W;
#pragma unroll
        for (int k = 0; k < 8; ++k) v[k] = f2bf(ip[k * HW]);
    } else {
        v = (bf16x8)0;
    }
    *(bf16x8*)(pin + (((size_t)b * Hp + yp) * Wp + xp) * C + c8 * 8) = v;
}

// zero pad borders of NHWC bf16 pin. mode1: all 4 edges; mode0: high edges only.
__global__ void zb_kernel(short* __restrict__ buf, int Hp, int Wp, int C8, int mode,
                          int total) {
    int tid = blockIdx.x * blockDim.x + threadIdx.x;
    if (tid >= total) return;
    int xp = (tid / C8) % Wp;
    int yp = (tid / (C8 * Wp)) % Hp;
    bool border = mode ? (yp == 0 || yp == Hp - 1 || xp == 0 || xp == Wp - 1)
                       : (yp == Hp - 1 || xp == Wp - 1);
    if (border) *(bf16x8*)(buf + (size_t)tid * 8) = (bf16x8)0;
}

// ---------------------------------------------------------------------------
// Weight transform (verified): wt[t9][m][ci]; s2 packs phase blocks
// {1,2,2,4} at offsets {0,1,3,5}.
// ---------------------------------------------------------------------------
__global__ void wtrans_kernel(const float* __restrict__ w, short* __restrict__ wt,
                              int Cin, int Cout, int Mp, int stride, int total) {
    int tid = blockIdx.x * blockDim.x + threadIdx.x;
    if (tid >= total) return;
    int ci = tid % Cin;
    int mm = (tid / Cin) % Mp;
    int t9 = tid / (Cin * Mp);
    int i, j;
    if (stride == 1) {
        int a = t9 / 3, bb = t9 % 3;
        i = 2 - a; j = 2 - bb;
    } else {
        int py, px, a, bb;
        if (t9 == 0) { py = 0; px = 0; a = 0; bb = 0; }
        else if (t9 < 3) { py = 0; px = 1; a = 0; bb = t9 - 1; }
        else if (t9 < 5) { py = 1; px = 0; a = t9 - 3; bb = 0; }
        else { int tt = t9 - 5; py = 1; px = 1; a = tt >> 1; bb = tt & 1; }
        i = (py == 0) ? 1 : (a == 0 ? 2 : 0);
        j = (px == 0) ? 1 : (bb == 0 ? 2 : 0);
    }
    float v = 0.f;
    if (mm < Cout) v = w[((ci * Cout + mm) * 3 + i) * 3 + j];
    wt[tid] = f2bf(v);
}

// ---------------------------------------------------------------------------
// Implicit-GEMM convT (round-6 verified body), BM x BN tile, 4 waves, BK=64,
// XOR-swizzled LDS. K-loop: cc OUTER, taps inner (L2 reuse per cc-slice).
// S2: blockIdx.z = phase. OUTM 1: bf16 NHWC pin. OUTM 2: bf16 NCHW (+act).
// ---------------------------------------------------------------------------
template <int BM, int BN, bool S2, int OUTM, int ACT>
__global__ void convt_mfma(const short* __restrict__ pin, const short* __restrict__ wtc,
                           float* __restrict__ outf, short* __restrict__ outb,
                           int Hpin, int Wpin, int Cin, int Mp, int Cout,
                           int Ho, int Wo, int Hu, int Wv,
                           int Hop, int Wop, int poff) {
    constexpr int WAVES_M = (BM >= 128) ? 2 : 1;
    constexpr int WM = BM / WAVES_M;
    constexpr int WN = BN / (4 / WAVES_M);
    constexpr int FM = WM / 16, FN = WN / 16;
    constexpr int RB = BN / 32;
    __shared__ __align__(16) short Alds[BM * 64];
    __shared__ __align__(16) short Blds[BN * 64];

    int t = threadIdx.x, lane = t & 63, wid = t >> 6;
    int n0 = blockIdx.x * BN, m0 = blockIdx.y * BM;

    int py = 0, px = 0, ny = 3, nx = 3, dys = 0x210, dxs = 0x210, sy = 1;
    const short* wt = wtc;
    if (S2) {
        int pz = blockIdx.z;
        py = pz >> 1; px = pz & 1;
        ny = 1 + py; nx = 1 + px;
        dys = py ? 0x10 : 0; dxs = px ? 0x10 : 0;
        int pre = (pz == 0) ? 0 : (pz == 1) ? 1 : (pz == 2) ? 3 : 5;
        wt = wtc + (size_t)pre * Mp * Cin;
        sy = 2;
    }

    int rowS = t >> 3;
    int dS = (t & 7) ^ (rowS & 7);
    int HuWv = Hu * Wv;
    int pxg[RB];
#pragma unroll
    for (int rb = 0; rb < RB; ++rb) {
        int n = n0 + rowS + rb * 32;
        int b = n / HuWv, r = n % HuWv;
        int u = r / Wv, v = r % Wv;
        pxg[rb] = ((b * Hpin + u) * Wpin + v) * Cin + dS * 8;
    }
    int aoff = (m0 + rowS) * Cin + dS * 8;

    char* AB = (char*)Alds;
    char* BB = (char*)Blds;

    int wm = (WAVES_M == 2) ? (wid & 1) : 0;
    int wn = (WAVES_M == 2) ? (wid >> 1) : wid;
    int cb = lane >> 4;
    int rm[FM], rn[FN];
#pragma unroll
    for (int mf = 0; mf < FM; ++mf) rm[mf] = wm * WM + mf * 16 + (lane & 15);
#pragma unroll
    for (int nf = 0; nf < FN; ++nf) rn[nf] = wn * WN + nf * 16 + (lane & 15);

    f32x4 acc[FM][FN];
#pragma unroll
    for (int mf = 0; mf < FM; ++mf)
#pragma unroll
        for (int nf = 0; nf < FN; ++nf) acc[mf][nf] = (f32x4){0.f, 0.f, 0.f, 0.f};

    for (int cc = 0; cc < Cin; cc += 64) {
        for (int a = 0; a < ny; ++a) {
            int dy = (dys >> (4 * a)) & 15;
            for (int bx = 0; bx < nx; ++bx) {
                int dx = (dxs >> (4 * bx)) & 15;
                int tapoff = (dy * Wpin + dx) * Cin;
                const short* wblk = wt + (size_t)(a * nx + bx) * Mp * Cin;
                __syncthreads();
                if (BM >= 32) {
#pragma unroll
                    for (int r = 0; r < BM / 32; ++r)
                        gll16(wblk + cc + aoff + r * 32 * Cin,
                              AB + r * 4096 + (wid << 10));
                } else {
                    if (wid < BM / 8) gll16(wblk + cc + aoff, AB + (wid << 10));
                }
#pragma unroll
                for (int rb = 0; rb < RB; ++rb)
                    gll16(pin + tapoff + cc + pxg[rb], BB + rb * 4096 + (wid << 10));
                __syncthreads();
#pragma unroll
                for (int h = 0; h < 2; ++h) {
                    bf16x8 av[FM], bv[FN];
#pragma unroll
                    for (int mf = 0; mf < FM; ++mf)
                        av[mf] = *(const bf16x8*)(AB + rm[mf] * 128 +
                                                  (((h * 4 + cb) ^ (rm[mf] & 7)) << 4));
#pragma unroll
                    for (int nf = 0; nf < FN; ++nf)
                        bv[nf] = *(const bf16x8*)(BB + rn[nf] * 128 +
                                                  (((h * 4 + cb) ^ (rn[nf] & 7)) << 4));
#pragma unroll
                    for (int mf = 0; mf < FM; ++mf)
#pragma unroll
                        for (int nf = 0; nf < FN; ++nf)
                            acc[mf][nf] = __builtin_amdgcn_mfma_f32_16x16x32_bf16(
                                av[mf], bv[nf], acc[mf][nf], 0, 0, 0);
                }
            }
        }
    }

#pragma unroll
    for (int mf = 0; mf < FM; ++mf) {
#pragma unroll
        for (int nf = 0; nf < FN; ++nf) {
            int p = n0 + wn * WN + nf * 16 + (lane & 15);
            int b = p / HuWv, r = p % HuWv;
            int u = r / Wv, v = r % Wv;
            int y = sy * u + py, x = sy * v + px;
            int cobase = m0 + wm * WM + mf * 16 + (lane >> 4) * 4;
            f32x4 vv = acc[mf][nf];
            if (OUTM == 1) {
                s16x4 pk;
#pragma unroll
                for (int reg = 0; reg < 4; ++reg) {
                    float f = vv[reg];
                    f = f > 0.f ? f : 0.f;
                    pk[reg] = f2bf(f);
                }
                *(s16x4*)(outb + (((size_t)b * Hop + y + poff) * Wop + (x + poff)) * Cout +
                          cobase) = pk;
            } else {
#pragma unroll
                for (int reg = 0; reg < 4; ++reg) {
                    int co = cobase + reg;
                    if (co < Cout) {
                        float f = vv[reg];
                        if (ACT == 0) f = f > 0.f ? f : 0.f;
                        else f = tanhf(f);
                        outb[((size_t)(b * Cout + co) * Ho + y) * Wo + x] = f2bf(f);
                    }
                }
            }
        }
    }
}

// ---------------------------------------------------------------------------

extern "C" void kernel_launch(void* const* d_in, const int* in_sizes, int n_in,
                              void* d_out, int out_size, void* d_ws, size_t ws_size,
                              hipStream_t stream) {
    const float* cont = (const float*)d_in[0];
    const float* w1 = (const float*)d_in[1];
    const float* w2 = (const float*)d_in[2];
    const float* w3 = (const float*)d_in[3];
    const float* w4 = (const float*)d_in[4];
    const float* w5 = (const float*)d_in[5];
    const float* w6 = (const float*)d_in[6];
    const float* kv0 = (const float*)d_in[7];
    const float* kh0 = (const float*)d_in[8];
    const float* m0 = (const float*)d_in[9];
    const float* kv1 = (const float*)d_in[10];
    const float* kh1 = (const float*)d_in[11];
    const float* m1 = (const float*)d_in[12];
    const float* kv2 = (const float*)d_in[13];
    const float* kh2 = (const float*)d_in[14];
    const float* m2 = (const float*)d_in[15];
    const float* kv3 = (const float*)d_in[16];
    const float* kh3 = (const float*)d_in[17];
    const float* m3 = (const float*)d_in[18];

    float* out = (float*)d_out;
    float* OUT0 = out;
    float* F8 = out + 1572864;
    float* F16 = out + 2097152;
    float* F32 = out + 18874368;

    const size_t MiB = 1 << 20;
    char* wsb = (char*)d_ws;
    short* WT = (short*)wsb;                  // [0,4)
    short* pin1 = (short*)(wsb + 4 * MiB);    // [4,5.2)
    short* t16b = (short*)(wsb + 6 * MiB);    // [6,39.6)
    short* pin2 = (short*)(wsb + 40 * MiB);   // [40,78)
    short* pin3 = (short*)(wsb + 80 * MiB);   // [80,97.8)
    short* t32bb = (short*)(wsb + 6 * MiB);   // [6,39.6)  (t16b dead)
    short* pin4 = (short*)(wsb + 40 * MiB);   // [40,75.7) (pin2 dead)
    short* pin5 = (short*)(wsb + 80 * MiB);   // [80,114.6)(pin3 dead)
    short* pin6 = (short*)(wsb + 6 * MiB);    // [6,75.2)  (t32bb,pin4 dead)
    short* toutb = (short*)(wsb + 76 * MiB);  // [76,79.2)

    short* wt1 = WT;                    // 9*512*64
    short* wt2 = wt1 + 294912;          // 9*256*512
    short* wt3 = wt2 + 1179648;         // 9*128*256
    short* wt4 = wt3 + 294912;          // 9*128*128
    short* wt5 = wt4 + 147456;          // 9*64*128
    short* wt6 = wt5 + 73728;           // 9*16*64

    auto wtr = [&](const float* w, short* wt, int Cin, int Cout, int Mp, int stride) {
        int total = 9 * Mp * Cin;
        wtrans_kernel<<<CDIV(total, 256), 256, 0, stream>>>(w, wt, Cin, Cout, Mp,
                                                            stride, total);
    };
    wtr(w1, wt1, 64, 512, 512, 2);
    wtr(w2, wt2, 512, 256, 256, 1);
    wtr(w3, wt3, 256, 128, 128, 2);
    wtr(w4, wt4, 128, 128, 128, 1);
    wtr(w5, wt5, 128, 64, 64, 2);
    wtr(w6, wt6, 64, 3, 16, 1);

    auto zb = [&](short* buf, int Hp, int Wp, int C8, int mode) {
        int zt = 32 * Hp * Wp * C8;
        zb_kernel<<<CDIV(zt, 256), 256, 0, stream>>>(buf, Hp, Wp, C8, mode, zt);
    };
    auto pad = [&](const float* src, short* pin, int C, int H, int W, int Hp, int Wp,
                   int po) {
        int C8 = C >> 3;
        int xt = (C8 >= 16) ? 16 : 32;
        int ct = 256 / xt;
        int nxt = CDIV(Wp, xt);
        dim3 g(nxt * (C8 / ct < 1 ? 1 : C8 / ct), Hp, 32);
        pad_kernel<<<g, 256, 0, stream>>>(src, pin, C, H, W, Hp, Wp, po, xt, nxt);
    };
    auto fusF = [&](const float* feat, const float* kv, const float* kh, const float* m,
                    float* o, int C, int H, int W) {
        int total = 32 * H * (C >> 2) * (W >> 3);
        fusionC_kernel<0><<<CDIV(total, 256), 256, 0, stream>>>(feat, kv, kh, m, o, 32,
                                                                C, H, W, total);
    };
    auto fusB = [&](const short* feat, const float* kv, const float* kh, const float* m,
                    float* o, int C, int H, int W) {
        int total = 32 * H * (C >> 2) * (W >> 3);
        fusionC_kernel<1><<<CDIV(total, 256), 256, 0, stream>>>(feat, kv, kh, m, o, 32,
                                                                C, H, W, total);
    };

    // 1. f8 = fusion(cont) -> F8 ; pad1: F8 -> pin1 (17x17x64, po=0)
    fusF(cont, kv0, kh0, m0, F8, 64, 16, 16);
    pad(F8, pin1, 64, 16, 16, 17, 17, 0);

    // 2. conv1 (s2): pin1 -> t16b bf16 NCHW [32,512,32,32]
    {
        dim3 g(32 * 16 * 16 / 128, 512 / 128, 4);
        convt_mfma<128, 128, true, 2, 0><<<g, 256, 0, stream>>>(
            pin1, wt1, nullptr, t16b, 17, 17, 64, 512, 512, 32, 32, 16, 16, 0, 0, 0);
    }
    // 3. f16 = fusion(t16b) -> F16 ; pad2: F16 -> pin2 (34x34x512, po=1)
    fusB(t16b, kv1, kh1, m1, F16, 512, 32, 32);
    pad(F16, pin2, 512, 32, 32, 34, 34, 1);

    // 4. conv2 (s1): pin2 -> pin3 (33x33x256 NHWC)
    zb(pin3, 33, 33, 32, 0);
    {
        dim3 g(32 * 32 * 32 / 128, 256 / 128, 1);
        convt_mfma<128, 128, false, 1, 0><<<g, 256, 0, stream>>>(
            pin2, wt2, nullptr, pin3, 34, 34, 512, 256, 256, 32, 32, 32, 32, 33, 33, 0);
    }
    // 5. conv3 (s2): pin3 -> t32bb bf16 NCHW [32,128,64,64]
    {
        dim3 g(32 * 32 * 32 / 128, 1, 4);
        convt_mfma<128, 128, true, 2, 0><<<g, 256, 0, stream>>>(
            pin3, wt3, nullptr, t32bb, 33, 33, 256, 128, 128, 64, 64, 32, 32, 0, 0, 0);
    }
    // 6. f32 = fusion(t32bb) -> F32 ; pad4: F32 -> pin4 (66x66x128, po=1)
    fusB(t32bb, kv2, kh2, m2, F32, 128, 64, 64);
    pad(F32, pin4, 128, 64, 64, 66, 66, 1);

    // 7. conv4 (s1): pin4 -> pin5 (65x65x128 NHWC)
    zb(pin5, 65, 65, 16, 0);
    {
        dim3 g(32 * 64 * 64 / 128, 1, 1);
        convt_mfma<128, 128, false, 1, 0><<<g, 256, 0, stream>>>(
            pin4, wt4, nullptr, pin5, 66, 66, 128, 128, 128, 64, 64, 64, 64, 65, 65, 0);
    }
    // 8. conv5 (s2): pin5 -> pin6 (130x130x64 NHWC, poff=1)
    zb(pin6, 130, 130, 8, 1);
    {
        dim3 g(32 * 64 * 64 / 128, 1, 4);
        convt_mfma<64, 128, true, 1, 0><<<g, 256, 0, stream>>>(
            pin5, wt5, nullptr, pin6, 65, 65, 128, 64, 64, 128, 128, 64, 64, 130, 130, 1);
    }
    // 9. conv6 (s1): pin6 -> toutb bf16 NCHW [32,3,128,128] tanh
    {
        dim3 g(32 * 128 * 128 / 64, 1, 1);
        convt_mfma<16, 64, false, 2, 1><<<g, 256, 0, stream>>>(
            pin6, wt6, nullptr, toutb, 130, 130, 64, 16, 3, 128, 128, 128, 128, 0, 0, 0);
    }
    // 10. out = fusion(toutb) -> OUT0 (C=3, bf16 input)
    {
        int total = 32 * 3 * 128 * (128 >> 2);
        fusion4b_kernel<<<CDIV(total, 256), 256, 0, stream>>>(toutb, kv3, kh3, m3, OUT0,
                                                              32, 3, 128, 128, total);
    }
}

// Round 10
// 610.157 us; speedup vs baseline: 1.3097x; 1.3097x over previous
//
#include <hip/hip_runtime.h>
#include <hip/hip_bf16.h>
#include <cmath>

#define CDIV(a, b) (((a) + (b) - 1) / (b))

typedef __attribute__((ext_vector_type(8))) short bf16x8;
typedef __attribute__((ext_vector_type(4))) short s16x4;
typedef __attribute__((ext_vector_type(4))) float f32x4;

__device__ __forceinline__ short f2bf(float f) {
    unsigned u = __float_as_uint(f);
    unsigned r = (u + 0x7fff + ((u >> 16) & 1)) >> 16;
    return (short)r;
}
__device__ __forceinline__ float bf2f(short s) {
    return __uint_as_float(((unsigned)(unsigned short)s) << 16);
}

__device__ __forceinline__ void gll16(const void* g, void* l) {
    __builtin_amdgcn_global_load_lds((const __attribute__((address_space(1))) void*)g,
                                     (__attribute__((address_space(3))) void*)l, 16, 0, 0);
}

// ---------------------------------------------------------------------------
// C-blocked fusion (round-6 proven, DO NOT widen: >60 live floats spills).
// 4 channels x 4 pixels per thread. TIN: 0 fp32, 1 bf16 NCHW input.
// ---------------------------------------------------------------------------
template <int TIN>
__global__ void fusionC_kernel(const void* __restrict__ featv,
                               const float* __restrict__ kv,
                               const float* __restrict__ kh,
                               const float* __restrict__ m,
                               float* __restrict__ out,
                               int B, int C, int H, int W, int total) {
    int idx = blockIdx.x * blockDim.x + threadIdx.x;
    if (idx >= total) return;
    int Wg = W >> 2;
    int C4 = C >> 2;
    int g = idx % Wg;
    int cg = (idx / Wg) % C4;
    int y = (idx / (Wg * C4)) % H;
    int b = idx / (Wg * C4 * H);
    int x0 = g << 2, c0 = cg << 2;
    int HW = H * W;

    int yy[5];
#pragma unroll
    for (int i = 0; i < 5; ++i) {
        int t = y + i - 2;
        yy[i] = t < 0 ? 0 : (t >= H ? H - 1 : t);
    }
    const float* kvb = kv + ((size_t)b * 5 * H + y) * W + x0;
    const float* khb = kh + ((size_t)b * 5 * H + y) * W + x0;
    f32x4 kvv[5], khv[5];
#pragma unroll
    for (int i = 0; i < 5; ++i) {
        kvv[i] = *(const f32x4*)(kvb + (size_t)i * HW);
        khv[i] = *(const f32x4*)(khb + (size_t)i * HW);
    }
    f32x4 m4 = *(const f32x4*)(m + ((size_t)b * H + y) * W + x0);
    bool interior = (g >= 1 && g <= Wg - 2);

#pragma unroll
    for (int cc = 0; cc < 4; ++cc) {
        size_t plane = (size_t)(b * C + c0 + cc) * HW;
        const float* fpf = (const float*)featv + plane;
        const short* fpb = (const short*)featv + plane;
        f32x4 acc = (f32x4){0.f, 0.f, 0.f, 0.f};
        f32x4 ctr;
        if (interior) {
#pragma unroll
            for (int i = 0; i < 5; ++i) {
                float w8[8];
                if (TIN == 0) {
                    const float* row = fpf + (size_t)yy[i] * W + x0;
                    f32x4 Lv = *(const f32x4*)(row - 4);
                    f32x4 Cv = *(const f32x4*)(row);
                    f32x4 Rv = *(const f32x4*)(row + 4);
                    w8[0] = Lv[2]; w8[1] = Lv[3];
                    w8[2] = Cv[0]; w8[3] = Cv[1]; w8[4] = Cv[2]; w8[5] = Cv[3];
                    w8[6] = Rv[0]; w8[7] = Rv[1];
                    if (i == 2) ctr = Cv;
                } else {
                    const short* row = fpb + (size_t)yy[i] * W + x0;
                    s16x4 Lv = *(const s16x4*)(row - 4);
                    s16x4 Cv = *(const s16x4*)(row);
                    s16x4 Rv = *(const s16x4*)(row + 4);
                    w8[0] = bf2f(Lv[2]); w8[1] = bf2f(Lv[3]);
                    w8[2] = bf2f(Cv[0]); w8[3] = bf2f(Cv[1]);
                    w8[4] = bf2f(Cv[2]); w8[5] = bf2f(Cv[3]);
                    w8[6] = bf2f(Rv[0]); w8[7] = bf2f(Rv[1]);
                    if (i == 2) {
                        ctr[0] = w8[2]; ctr[1] = w8[3]; ctr[2] = w8[4]; ctr[3] = w8[5];
                    }
                }
#pragma unroll
                for (int o = 0; o < 4; ++o) {
                    float r = 0.f;
#pragma unroll
                    for (int j = 0; j < 5; ++j) r = fmaf(khv[j][o], w8[o + j], r);
                    acc[o] = fmaf(kvv[i][o], r, acc[o]);
                }
            }
        } else {
#pragma unroll
            for (int o = 0; o < 4; ++o) {
                int x = x0 + o;
                int xx[5];
#pragma unroll
                for (int j = 0; j < 5; ++j) {
                    int u = x + j - 2;
                    xx[j] = u < 0 ? 0 : (u >= W ? W - 1 : u);
                }
                float a = 0.f;
#pragma unroll
                for (int i = 0; i < 5; ++i) {
                    float r = 0.f;
#pragma unroll
                    for (int j = 0; j < 5; ++j) {
                        float fv = (TIN == 0) ? fpf[(size_t)yy[i] * W + xx[j]]
                                              : bf2f(fpb[(size_t)yy[i] * W + xx[j]]);
                        r = fmaf(khv[j][o], fv, r);
                    }
                    a = fmaf(kvv[i][o], r, a);
                }
                acc[o] = a;
                ctr[o] = (TIN == 0) ? fpf[(size_t)y * W + x] : bf2f(fpb[(size_t)y * W + x]);
            }
        }
        f32x4 o4;
#pragma unroll
        for (int o = 0; o < 4; ++o) o4[o] = m4[o] * acc[o] + (1.f - m4[o]) * ctr[o];
        *(f32x4*)(out + plane + (size_t)y * W + x0) = o4;
    }
}

// scalar-C fusion for C=3 final output, bf16 input (round-6 proven)
__global__ void fusion4b_kernel(const short* __restrict__ feat,
                                const float* __restrict__ kv,
                                const float* __restrict__ kh,
                                const float* __restrict__ m,
                                float* __restrict__ out,
                                int B, int C, int H, int W, int total) {
    int idx = blockIdx.x * blockDim.x + threadIdx.x;
    if (idx >= total) return;
    int Wg = W >> 2;
    int g = idx % Wg;
    int y = (idx / Wg) % H;
    int c = (idx / (Wg * H)) % C;
    int b = idx / (Wg * H * C);
    int x0 = g << 2;
    int HW = H * W;

    const short* fp = feat + (size_t)(b * C + c) * HW;
    int yy[5];
#pragma unroll
    for (int i = 0; i < 5; ++i) {
        int t = y + i - 2;
        yy[i] = t < 0 ? 0 : (t >= H ? H - 1 : t);
    }
    const float* kvb = kv + ((size_t)b * 5 * H + y) * W + x0;
    const float* khb = kh + ((size_t)b * 5 * H + y) * W + x0;

    f32x4 res, c4;
    if (g >= 1 && g <= Wg - 2) {
        f32x4 kvv[5], khv[5];
#pragma unroll
        for (int i = 0; i < 5; ++i) {
            kvv[i] = *(const f32x4*)(kvb + (size_t)i * HW);
            khv[i] = *(const f32x4*)(khb + (size_t)i * HW);
        }
        f32x4 acc = (f32x4){0.f, 0.f, 0.f, 0.f};
#pragma unroll
        for (int i = 0; i < 5; ++i) {
            const short* row = fp + (size_t)yy[i] * W + x0;
            s16x4 Lv = *(const s16x4*)(row - 4);
            s16x4 Cv = *(const s16x4*)(row);
            s16x4 Rv = *(const s16x4*)(row + 4);
            float w8[8] = {bf2f(Lv[2]), bf2f(Lv[3]), bf2f(Cv[0]), bf2f(Cv[1]),
                           bf2f(Cv[2]), bf2f(Cv[3]), bf2f(Rv[0]), bf2f(Rv[1])};
            if (i == 2) { c4[0] = w8[2]; c4[1] = w8[3]; c4[2] = w8[4]; c4[3] = w8[5]; }
#pragma unroll
            for (int o = 0; o < 4; ++o) {
                float r = 0.f;
#pragma unroll
                for (int j = 0; j < 5; ++j) r = fmaf(khv[j][o], w8[o + j], r);
                acc[o] = fmaf(kvv[i][o], r, acc[o]);
            }
        }
        res = acc;
    } else {
#pragma unroll
        for (int o = 0; o < 4; ++o) {
            int x = x0 + o;
            int xx[5];
#pragma unroll
            for (int j = 0; j < 5; ++j) {
                int u = x + j - 2;
                xx[j] = u < 0 ? 0 : (u >= W ? W - 1 : u);
            }
            float acc = 0.f;
#pragma unroll
            for (int i = 0; i < 5; ++i) {
                float r = 0.f;
#pragma unroll
                for (int j = 0; j < 5; ++j)
                    r = fmaf(khb[(size_t)j * HW + o], bf2f(fp[(size_t)yy[i] * W + xx[j]]), r);
                acc = fmaf(kvb[(size_t)i * HW + o], r, acc);
            }
            res[o] = acc;
            c4[o] = bf2f(fp[(size_t)y * W + x]);
        }
    }
    f32x4 m4 = *(const f32x4*)(m + ((size_t)b * H + y) * W + x0);
    f32x4 o4;
#pragma unroll
    for (int o = 0; o < 4; ++o) o4[o] = m4[o] * res[o] + (1.f - m4[o]) * c4[o];
    *(f32x4*)(out + ((size_t)(b * C + c) * H + y) * W + x0) = o4;
}

// ---------------------------------------------------------------------------
// Pad v2 (round-6 verified): line-complete both sides. xp fastest, then c8.
// ---------------------------------------------------------------------------
__global__ void pad_kernel(const float* __restrict__ in, short* __restrict__ pin,
                           int C, int H, int W, int Hp, int Wp, int po,
                           int xt, int nxt) {
    int b = blockIdx.z, yp = blockIdx.y;
    int ct = 256 / xt;
    int xtile = blockIdx.x % nxt;
    int cb = blockIdx.x / nxt;
    int xl = threadIdx.x % xt;
    int cl = threadIdx.x / xt;
    int xp = xtile * xt + xl;
    int c8 = cb * ct + cl;
    if (xp >= Wp) return;

    int y = yp - po, x = xp - po;
    bf16x8 v;
    if (y >= 0 && y < H && x >= 0 && x < W) {
        const float* ip = in + ((size_t)(b * C + c8 * 8) * H + y) * W + x;
        size_t HW = (size_t)H * W;
#pragma unroll
        for (int k = 0; k < 8; ++k) v[k] = f2bf(ip[k * HW]);
    } else {
        v = (bf16x8)0;
    }
    *(bf16x8*)(pin + (((size_t)b * Hp + yp) * Wp + xp) * C + c8 * 8) = v;
}

// zero pad borders of NHWC bf16 pin. mode1: all 4 edges; mode0: high edges only.
__global__ void zb_kernel(short* __restrict__ buf, int Hp, int Wp, int C8, int mode,
                          int total) {
    int tid = blockIdx.x * blockDim.x + threadIdx.x;
    if (tid >= total) return;
    int xp = (tid / C8) % Wp;
    int yp = (tid / (C8 * Wp)) % Hp;
    bool border = mode ? (yp == 0 || yp == Hp - 1 || xp == 0 || xp == Wp - 1)
                       : (yp == Hp - 1 || xp == Wp - 1);
    if (border) *(bf16x8*)(buf + (size_t)tid * 8) = (bf16x8)0;
}

// ---------------------------------------------------------------------------
// Weight transform (verified): wt[t9][m][ci]; s2 packs phase blocks
// {1,2,2,4} at offsets {0,1,3,5}.
// ---------------------------------------------------------------------------
__global__ void wtrans_kernel(const float* __restrict__ w, short* __restrict__ wt,
                              int Cin, int Cout, int Mp, int stride, int total) {
    int tid = blockIdx.x * blockDim.x + threadIdx.x;
    if (tid >= total) return;
    int ci = tid % Cin;
    int mm = (tid / Cin) % Mp;
    int t9 = tid / (Cin * Mp);
    int i, j;
    if (stride == 1) {
        int a = t9 / 3, bb = t9 % 3;
        i = 2 - a; j = 2 - bb;
    } else {
        int py, px, a, bb;
        if (t9 == 0) { py = 0; px = 0; a = 0; bb = 0; }
        else if (t9 < 3) { py = 0; px = 1; a = 0; bb = t9 - 1; }
        else if (t9 < 5) { py = 1; px = 0; a = t9 - 3; bb = 0; }
        else { int tt = t9 - 5; py = 1; px = 1; a = tt >> 1; bb = tt & 1; }
        i = (py == 0) ? 1 : (a == 0 ? 2 : 0);
        j = (px == 0) ? 1 : (bb == 0 ? 2 : 0);
    }
    float v = 0.f;
    if (mm < Cout) v = w[((ci * Cout + mm) * 3 + i) * 3 + j];
    wt[tid] = f2bf(v);
}

#define WAITVM(n) asm volatile("s_waitcnt vmcnt(" #n ")" ::: "memory")

// ---------------------------------------------------------------------------
// Implicit-GEMM convT, BM x BN tile, 4 waves, BK=64, XOR-swizzled LDS.
// K-loop: cc OUTER, taps inner (L2 reuse). DBUF: 2-phase double-buffered
// staging with counted vmcnt (use only where grid <= 2 blocks/CU so the 2x
// LDS doesn't cost occupancy -- conv2). Round-7-verified correct.
// ---------------------------------------------------------------------------
template <int BM, int BN, bool S2, int OUTM, int ACT, bool DBUF>
__global__ void convt_mfma(const short* __restrict__ pin, const short* __restrict__ wtc,
                           float* __restrict__ outf, short* __restrict__ outb,
                           int Hpin, int Wpin, int Cin, int Mp, int Cout,
                           int Ho, int Wo, int Hu, int Wv,
                           int Hop, int Wop, int poff) {
    constexpr int WAVES_M = (BM >= 128) ? 2 : 1;
    constexpr int WM = BM / WAVES_M;
    constexpr int WN = BN / (4 / WAVES_M);
    constexpr int FM = WM / 16, FN = WN / 16;
    constexpr int RB = BN / 32;
    constexpr int AROUND = BM / 32;
    constexpr int NLOAD = AROUND + RB;
    constexpr int ABYTES = BM * 128;
    constexpr int BBYTES = BN * 128;
    __shared__ __align__(16) short Alds[(DBUF ? 2 : 1) * BM * 64];
    __shared__ __align__(16) short Blds[(DBUF ? 2 : 1) * BN * 64];

    int t = threadIdx.x, lane = t & 63, wid = t >> 6;
    int n0 = blockIdx.x * BN, m0 = blockIdx.y * BM;

    int py = 0, px = 0, ny = 3, nx = 3, dys = 0x210, dxs = 0x210, sy = 1;
    const short* wt = wtc;
    if (S2) {
        int pz = blockIdx.z;
        py = pz >> 1; px = pz & 1;
        ny = 1 + py; nx = 1 + px;
        dys = py ? 0x10 : 0; dxs = px ? 0x10 : 0;
        int pre = (pz == 0) ? 0 : (pz == 1) ? 1 : (pz == 2) ? 3 : 5;
        wt = wtc + (size_t)pre * Mp * Cin;
        sy = 2;
    }

    int rowS = t >> 3;
    int dS = (t & 7) ^ (rowS & 7);
    int HuWv = Hu * Wv;
    int pxg[RB];
#pragma unroll
    for (int rb = 0; rb < RB; ++rb) {
        int n = n0 + rowS + rb * 32;
        int b = n / HuWv, r = n % HuWv;
        int u = r / Wv, v = r % Wv;
        pxg[rb] = ((b * Hpin + u) * Wpin + v) * Cin + dS * 8;
    }
    int aoff = (m0 + rowS) * Cin + dS * 8;

    char* AB = (char*)Alds;
    char* BB = (char*)Blds;

    int wm = (WAVES_M == 2) ? (wid & 1) : 0;
    int wn = (WAVES_M == 2) ? (wid >> 1) : wid;
    int cb = lane >> 4;
    int rm[FM], rn[FN];
#pragma unroll
    for (int mf = 0; mf < FM; ++mf) rm[mf] = wm * WM + mf * 16 + (lane & 15);
#pragma unroll
    for (int nf = 0; nf < FN; ++nf) rn[nf] = wn * WN + nf * 16 + (lane & 15);

    f32x4 acc[FM][FN];
#pragma unroll
    for (int mf = 0; mf < FM; ++mf)
#pragma unroll
        for (int nf = 0; nf < FN; ++nf) acc[mf][nf] = (f32x4){0.f, 0.f, 0.f, 0.f};

    int ntap = ny * nx;
    int NK = (Cin >> 6) * ntap;

    auto COMPUTE = [&](int buf) {
        char* ABb = AB + buf * ABYTES;
        char* BBb = BB + buf * BBYTES;
#pragma unroll
        for (int h = 0; h < 2; ++h) {
            bf16x8 av[FM], bv[FN];
#pragma unroll
            for (int mf = 0; mf < FM; ++mf)
                av[mf] = *(const bf16x8*)(ABb + rm[mf] * 128 +
                                          (((h * 4 + cb) ^ (rm[mf] & 7)) << 4));
#pragma unroll
            for (int nf = 0; nf < FN; ++nf)
                bv[nf] = *(const bf16x8*)(BBb + rn[nf] * 128 +
                                          (((h * 4 + cb) ^ (rn[nf] & 7)) << 4));
#pragma unroll
            for (int mf = 0; mf < FM; ++mf)
#pragma unroll
                for (int nf = 0; nf < FN; ++nf)
                    acc[mf][nf] = __builtin_amdgcn_mfma_f32_16x16x32_bf16(
                        av[mf], bv[nf], acc[mf][nf], 0, 0, 0);
        }
    };

    if constexpr (DBUF) {
        auto STAGE = [&](int ks, int buf) {
            int ccq = ks / ntap;
            int ti = ks - ccq * ntap;
            int cc = ccq << 6;
            int a = ti / nx, bxx = ti - (ti / nx) * nx;
            int dy = (dys >> (4 * a)) & 15, dxv = (dxs >> (4 * bxx)) & 15;
            int tapoff = (dy * Wpin + dxv) * Cin;
            const short* wblk = wt + (size_t)ti * Mp * Cin;
            char* ABb = AB + buf * ABYTES;
            char* BBb = BB + buf * BBYTES;
#pragma unroll
            for (int r = 0; r < AROUND; ++r)
                gll16(wblk + cc + aoff + r * 32 * Cin, ABb + r * 4096 + (wid << 10));
#pragma unroll
            for (int rb = 0; rb < RB; ++rb)
                gll16(pin + tapoff + cc + pxg[rb], BBb + rb * 4096 + (wid << 10));
        };

        STAGE(0, 0);
        for (int ks = 0; ks < NK; ++ks) {
            int cur = ks & 1;
            bool more = (ks + 1 < NK);
            if (more) STAGE(ks + 1, cur ^ 1);
            if (more) {
                static_assert(!DBUF || NLOAD == 8, "vmcnt literal");
                WAITVM(8);
            } else {
                WAITVM(0);
            }
            __builtin_amdgcn_sched_barrier(0);
            __builtin_amdgcn_s_barrier();
            __builtin_amdgcn_sched_barrier(0);
            COMPUTE(cur);
            asm volatile("s_waitcnt lgkmcnt(0)" ::: "memory");
            __builtin_amdgcn_sched_barrier(0);
            __builtin_amdgcn_s_barrier();
        }
    } else {
        for (int ks = 0; ks < NK; ++ks) {
            int ccq = ks / ntap;
            int ti = ks - ccq * ntap;
            int cc = ccq << 6;
            int a = ti / nx, bxx = ti - (ti / nx) * nx;
            int dy = (dys >> (4 * a)) & 15, dxv = (dxs >> (4 * bxx)) & 15;
            int tapoff = (dy * Wpin + dxv) * Cin;
            const short* wblk = wt + (size_t)ti * Mp * Cin;
            __syncthreads();
            if (BM >= 32) {
#pragma unroll
                for (int r = 0; r < AROUND; ++r)
                    gll16(wblk + cc + aoff + r * 32 * Cin, AB + r * 4096 + (wid << 10));
            } else {
                if (wid < BM / 8) gll16(wblk + cc + aoff, AB + (wid << 10));
            }
#pragma unroll
            for (int rb = 0; rb < RB; ++rb)
                gll16(pin + tapoff + cc + pxg[rb], BB + rb * 4096 + (wid << 10));
            __syncthreads();
            COMPUTE(0);
        }
    }

#pragma unroll
    for (int mf = 0; mf < FM; ++mf) {
#pragma unroll
        for (int nf = 0; nf < FN; ++nf) {
            int p = n0 + wn * WN + nf * 16 + (lane & 15);
            int b = p / HuWv, r = p % HuWv;
            int u = r / Wv, v = r % Wv;
            int y = sy * u + py, x = sy * v + px;
            int cobase = m0 + wm * WM + mf * 16 + (lane >> 4) * 4;
            f32x4 vv = acc[mf][nf];
            if (OUTM == 1) {
                s16x4 pk;
#pragma unroll
                for (int reg = 0; reg < 4; ++reg) {
                    float f = vv[reg];
                    f = f > 0.f ? f : 0.f;
                    pk[reg] = f2bf(f);
                }
                *(s16x4*)(outb + (((size_t)b * Hop + y + poff) * Wop + (x + poff)) * Cout +
                          cobase) = pk;
            } else {
#pragma unroll
                for (int reg = 0; reg < 4; ++reg) {
                    int co = cobase + reg;
                    if (co < Cout) {
                        float f = vv[reg];
                        if (ACT == 0) f = f > 0.f ? f : 0.f;
                        else f = tanhf(f);
                        outb[((size_t)(b * Cout + co) * Ho + y) * Wo + x] = f2bf(f);
                    }
                }
            }
        }
    }
}

// ---------------------------------------------------------------------------

extern "C" void kernel_launch(void* const* d_in, const int* in_sizes, int n_in,
                              void* d_out, int out_size, void* d_ws, size_t ws_size,
                              hipStream_t stream) {
    const float* cont = (const float*)d_in[0];
    const float* w1 = (const float*)d_in[1];
    const float* w2 = (const float*)d_in[2];
    const float* w3 = (const float*)d_in[3];
    const float* w4 = (const float*)d_in[4];
    const float* w5 = (const float*)d_in[5];
    const float* w6 = (const float*)d_in[6];
    const float* kv0 = (const float*)d_in[7];
    const float* kh0 = (const float*)d_in[8];
    const float* m0 = (const float*)d_in[9];
    const float* kv1 = (const float*)d_in[10];
    const float* kh1 = (const float*)d_in[11];
    const float* m1 = (const float*)d_in[12];
    const float* kv2 = (const float*)d_in[13];
    const float* kh2 = (const float*)d_in[14];
    const float* m2 = (const float*)d_in[15];
    const float* kv3 = (const float*)d_in[16];
    const float* kh3 = (const float*)d_in[17];
    const float* m3 = (const float*)d_in[18];

    float* out = (float*)d_out;
    float* OUT0 = out;
    float* F8 = out + 1572864;
    float* F16 = out + 2097152;
    float* F32 = out + 18874368;

    const size_t MiB = 1 << 20;
    char* wsb = (char*)d_ws;
    short* WT = (short*)wsb;                  // [0,4)
    short* pin1 = (short*)(wsb + 4 * MiB);    // [4,5.2)
    short* t16b = (short*)(wsb + 6 * MiB);    // [6,39.6)
    short* pin2 = (short*)(wsb + 40 * MiB);   // [40,78)
    short* pin3 = (short*)(wsb + 80 * MiB);   // [80,97.8)
    short* t32bb = (short*)(wsb + 6 * MiB);   // [6,39.6)  (t16b dead)
    short* pin4 = (short*)(wsb + 40 * MiB);   // [40,75.7) (pin2 dead)
    short* pin5 = (short*)(wsb + 80 * MiB);   // [80,114.6)(pin3 dead)
    short* pin6 = (short*)(wsb + 6 * MiB);    // [6,75.2)  (t32bb,pin4 dead)
    short* toutb = (short*)(wsb + 76 * MiB);  // [76,79.2)

    short* wt1 = WT;                    // 9*512*64
    short* wt2 = wt1 + 294912;          // 9*256*512
    short* wt3 = wt2 + 1179648;         // 9*128*256
    short* wt4 = wt3 + 294912;          // 9*128*128
    short* wt5 = wt4 + 147456;          // 9*64*128
    short* wt6 = wt5 + 73728;           // 9*16*64

    auto wtr = [&](const float* w, short* wt, int Cin, int Cout, int Mp, int stride) {
        int total = 9 * Mp * Cin;
        wtrans_kernel<<<CDIV(total, 256), 256, 0, stream>>>(w, wt, Cin, Cout, Mp,
                                                            stride, total);
    };
    wtr(w1, wt1, 64, 512, 512, 2);
    wtr(w2, wt2, 512, 256, 256, 1);
    wtr(w3, wt3, 256, 128, 128, 2);
    wtr(w4, wt4, 128, 128, 128, 1);
    wtr(w5, wt5, 128, 64, 64, 2);
    wtr(w6, wt6, 64, 3, 16, 1);

    auto zb = [&](short* buf, int Hp, int Wp, int C8, int mode) {
        int zt = 32 * Hp * Wp * C8;
        zb_kernel<<<CDIV(zt, 256), 256, 0, stream>>>(buf, Hp, Wp, C8, mode, zt);
    };
    auto pad = [&](const float* src, short* pin, int C, int H, int W, int Hp, int Wp,
                   int po) {
        int C8 = C >> 3;
        int xt = (C8 >= 16) ? 16 : 32;
        int ct = 256 / xt;
        int nxt = CDIV(Wp, xt);
        dim3 g(nxt * (C8 / ct < 1 ? 1 : C8 / ct), Hp, 32);
        pad_kernel<<<g, 256, 0, stream>>>(src, pin, C, H, W, Hp, Wp, po, xt, nxt);
    };
    auto fusF = [&](const float* feat, const float* kv, const float* kh, const float* m,
                    float* o, int C, int H, int W) {
        int total = 32 * H * (C >> 2) * (W >> 2);
        fusionC_kernel<0><<<CDIV(total, 256), 256, 0, stream>>>(feat, kv, kh, m, o, 32,
                                                                C, H, W, total);
    };
    auto fusB = [&](const short* feat, const float* kv, const float* kh, const float* m,
                    float* o, int C, int H, int W) {
        int total = 32 * H * (C >> 2) * (W >> 2);
        fusionC_kernel<1><<<CDIV(total, 256), 256, 0, stream>>>(feat, kv, kh, m, o, 32,
                                                                C, H, W, total);
    };

    // 1. f8 = fusion(cont) -> F8 ; pad1: F8 -> pin1 (17x17x64, po=0)
    fusF(cont, kv0, kh0, m0, F8, 64, 16, 16);
    pad(F8, pin1, 64, 16, 16, 17, 17, 0);

    // 2. conv1 (s2): pin1 -> t16b bf16 NCHW [32,512,32,32]
    {
        dim3 g(32 * 16 * 16 / 128, 512 / 128, 4);
        convt_mfma<128, 128, true, 2, 0, false><<<g, 256, 0, stream>>>(
            pin1, wt1, nullptr, t16b, 17, 17, 64, 512, 512, 32, 32, 16, 16, 0, 0, 0);
    }
    // 3. f16 = fusion(t16b) -> F16 ; pad2: F16 -> pin2 (34x34x512, po=1)
    fusB(t16b, kv1, kh1, m1, F16, 512, 32, 32);
    pad(F16, pin2, 512, 32, 32, 34, 34, 1);

    // 4. conv2 (s1): pin2 -> pin3 (33x33x256 NHWC). DBUF: grid=512=2/CU, LDS-free.
    zb(pin3, 33, 33, 32, 0);
    {
        dim3 g(32 * 32 * 32 / 128, 256 / 128, 1);
        convt_mfma<128, 128, false, 1, 0, true><<<g, 256, 0, stream>>>(
            pin2, wt2, nullptr, pin3, 34, 34, 512, 256, 256, 32, 32, 32, 32, 33, 33, 0);
    }
    // 5. conv3 (s2): pin3 -> t32bb bf16 NCHW [32,128,64,64]
    {
        dim3 g(32 * 32 * 32 / 128, 1, 4);
        convt_mfma<128, 128, true, 2, 0, false><<<g, 256, 0, stream>>>(
            pin3, wt3, nullptr, t32bb, 33, 33, 256, 128, 128, 64, 64, 32, 32, 0, 0, 0);
    }
    // 6. f32 = fusion(t32bb) -> F32 ; pad4: F32 -> pin4 (66x66x128, po=1)
    fusB(t32bb, kv2, kh2, m2, F32, 128, 64, 64);
    pad(F32, pin4, 128, 64, 64, 66, 66, 1);

    // 7. conv4 (s1): pin4 -> pin5 (65x65x128 NHWC)
    zb(pin5, 65, 65, 16, 0);
    {
        dim3 g(32 * 64 * 64 / 128, 1, 1);
        convt_mfma<128, 128, false, 1, 0, false><<<g, 256, 0, stream>>>(
            pin4, wt4, nullptr, pin5, 66, 66, 128, 128, 128, 64, 64, 64, 64, 65, 65, 0);
    }
    // 8. conv5 (s2): pin5 -> pin6 (130x130x64 NHWC, poff=1)
    zb(pin6, 130, 130, 8, 1);
    {
        dim3 g(32 * 64 * 64 / 128, 1, 4);
        convt_mfma<64, 128, true, 1, 0, false><<<g, 256, 0, stream>>>(
            pin5, wt5, nullptr, pin6, 65, 65, 128, 64, 64, 128, 128, 64, 64, 130, 130, 1);
    }
    // 9. conv6 (s1): pin6 -> toutb bf16 NCHW [32,3,128,128] tanh
    {
        dim3 g(32 * 128 * 128 / 64, 1, 1);
        convt_mfma<16, 64, false, 2, 1, false><<<g, 256, 0, stream>>>(
            pin6, wt6, nullptr, toutb, 130, 130, 64, 16, 3, 128, 128, 128, 128, 0, 0, 0);
    }
    // 10. out = fusion(toutb) -> OUT0 (C=3, bf16 input)
    {
        int total = 32 * 3 * 128 * (128 >> 2);
        fusion4b_kernel<<<CDIV(total, 256), 256, 0, stream>>>(toutb, kv3, kh3, m3, OUT0,
                                                              32, 3, 128, 128, total);
    }
}

// Round 11
// 543.047 us; speedup vs baseline: 1.4715x; 1.1236x over previous
//
#include <hip/hip_runtime.h>
#include <hip/hip_bf16.h>
#include <cmath>

#define CDIV(a, b) (((a) + (b) - 1) / (b))

typedef __attribute__((ext_vector_type(8))) short bf16x8;
typedef __attribute__((ext_vector_type(4))) short s16x4;
typedef __attribute__((ext_vector_type(4))) float f32x4;
typedef __attribute__((ext_vector_type(2))) float f32x2;

__device__ __forceinline__ short f2bf(float f) {
    unsigned u = __float_as_uint(f);
    unsigned r = (u + 0x7fff + ((u >> 16) & 1)) >> 16;
    return (short)r;
}
__device__ __forceinline__ float bf2f(short s) {
    return __uint_as_float(((unsigned)(unsigned short)s) << 16);
}

__device__ __forceinline__ void gll16(const void* g, void* l) {
    __builtin_amdgcn_global_load_lds((const __attribute__((address_space(1))) void*)g,
                                     (__attribute__((address_space(3))) void*)l, 16, 0, 0);
}

// ---------------------------------------------------------------------------
// LDS-staged fusion (bf16 NCHW input, fp32 NCHW out). Block = CB channels x
// one y x full W. Stage 5 clamped rows as fp32 with 2-cell replicated
// x-borders; window read = 2x aligned ds_read_b128, no border branch.
// W in {32,64}, CB = 1024/W, 256 threads, 4 px/thread.
// ---------------------------------------------------------------------------
template <int W, int CB>
__global__ void fusionL_kernel(const short* __restrict__ feat,
                               const float* __restrict__ kv,
                               const float* __restrict__ kh,
                               const float* __restrict__ m,
                               float* __restrict__ out,
                               int C, int H) {
    constexpr int ROWF = W + 4;
    constexpr int W8 = W / 8;
    constexpr int XG = W / 4;
    __shared__ float L[CB * 5 * ROWF];

    int tid = threadIdx.x;
    int cblk = blockIdx.x, y = blockIdx.y, b = blockIdx.z;
    int c0 = cblk * CB;
    int HW = H * W;

    int ry[5];
#pragma unroll
    for (int i = 0; i < 5; ++i) {
        int t = y + i - 2;
        ry[i] = t < 0 ? 0 : (t >= H ? H - 1 : t);
    }

    // ---- stage 5 rows x CB channels (bf16 -> fp32), interior
    for (int s = tid; s < CB * 5 * W8; s += 256) {
        int c = s / (5 * W8);
        int rr = (s / W8) % 5;
        int xc = s % W8;
        const short* src = feat + ((size_t)(b * C + c0 + c) * H + ry[rr]) * W + xc * 8;
        bf16x8 v = *(const bf16x8*)src;
        float* dst = L + (c * 5 + rr) * ROWF + 2 + xc * 8;
#pragma unroll
        for (int k = 0; k < 8; k += 2) {
            f32x2 t2 = {bf2f(v[k]), bf2f(v[k + 1])};
            *(f32x2*)(dst + k) = t2;  // 8B aligned
        }
    }
    // ---- replicated x-borders
    if (tid < CB * 5) {
        int c = tid / 5, rr = tid % 5;
        const short* srow = feat + ((size_t)(b * C + c0 + c) * H + ry[rr]) * W;
        float v0 = bf2f(srow[0]), v1 = bf2f(srow[W - 1]);
        float* base = L + (c * 5 + rr) * ROWF;
        base[0] = v0; base[1] = v0;
        base[W + 2] = v1; base[W + 3] = v1;
    }
    __syncthreads();

    // ---- compute: thread (c, xg), 4 px
    int xg = tid % XG;
    int c = tid / XG;
    int x0 = xg * 4;

    const float* kvb = kv + ((size_t)b * 5 * H + y) * W + x0;
    const float* khb = kh + ((size_t)b * 5 * H + y) * W + x0;
    f32x4 kvv[5], khv[5];
#pragma unroll
    for (int i = 0; i < 5; ++i) {
        kvv[i] = *(const f32x4*)(kvb + (size_t)i * HW);
        khv[i] = *(const f32x4*)(khb + (size_t)i * HW);
    }
    f32x4 m4 = *(const f32x4*)(m + ((size_t)b * H + y) * W + x0);

    f32x4 acc = (f32x4){0.f, 0.f, 0.f, 0.f};
    f32x4 ctr;
    const float* Lc = L + c * 5 * ROWF + x0;  // window x0-2 -> LDS idx x0
#pragma unroll
    for (int i = 0; i < 5; ++i) {
        f32x4 wa = *(const f32x4*)(Lc + i * ROWF);       // 16B aligned
        f32x4 wb = *(const f32x4*)(Lc + i * ROWF + 4);
        float w8[8] = {wa[0], wa[1], wa[2], wa[3], wb[0], wb[1], wb[2], wb[3]};
        if (i == 2) { ctr[0] = w8[2]; ctr[1] = w8[3]; ctr[2] = w8[4]; ctr[3] = w8[5]; }
#pragma unroll
        for (int o = 0; o < 4; ++o) {
            float r = 0.f;
#pragma unroll
            for (int j = 0; j < 5; ++j) r = fmaf(khv[j][o], w8[o + j], r);
            acc[o] = fmaf(kvv[i][o], r, acc[o]);
        }
    }
    f32x4 o4;
#pragma unroll
    for (int o = 0; o < 4; ++o) o4[o] = m4[o] * acc[o] + (1.f - m4[o]) * ctr[o];
    *(f32x4*)(out + (size_t)(b * C + c0 + c) * HW + (size_t)y * W + x0) = o4;
}

// ---------------------------------------------------------------------------
// C-blocked fusion (round-6 proven): 4 channels x 4 pixels per thread.
// TIN: 0 fp32 input. Used for the small f8 fusion.
// ---------------------------------------------------------------------------
template <int TIN>
__global__ void fusionC_kernel(const void* __restrict__ featv,
                               const float* __restrict__ kv,
                               const float* __restrict__ kh,
                               const float* __restrict__ m,
                               float* __restrict__ out,
                               int B, int C, int H, int W, int total) {
    int idx = blockIdx.x * blockDim.x + threadIdx.x;
    if (idx >= total) return;
    int Wg = W >> 2;
    int C4 = C >> 2;
    int g = idx % Wg;
    int cg = (idx / Wg) % C4;
    int y = (idx / (Wg * C4)) % H;
    int b = idx / (Wg * C4 * H);
    int x0 = g << 2, c0 = cg << 2;
    int HW = H * W;

    int yy[5];
#pragma unroll
    for (int i = 0; i < 5; ++i) {
        int t = y + i - 2;
        yy[i] = t < 0 ? 0 : (t >= H ? H - 1 : t);
    }
    const float* kvb = kv + ((size_t)b * 5 * H + y) * W + x0;
    const float* khb = kh + ((size_t)b * 5 * H + y) * W + x0;
    f32x4 kvv[5], khv[5];
#pragma unroll
    for (int i = 0; i < 5; ++i) {
        kvv[i] = *(const f32x4*)(kvb + (size_t)i * HW);
        khv[i] = *(const f32x4*)(khb + (size_t)i * HW);
    }
    f32x4 m4 = *(const f32x4*)(m + ((size_t)b * H + y) * W + x0);
    bool interior = (g >= 1 && g <= Wg - 2);

#pragma unroll
    for (int cc = 0; cc < 4; ++cc) {
        size_t plane = (size_t)(b * C + c0 + cc) * HW;
        const float* fpf = (const float*)featv + plane;
        const short* fpb = (const short*)featv + plane;
        f32x4 acc = (f32x4){0.f, 0.f, 0.f, 0.f};
        f32x4 ctr;
        if (interior) {
#pragma unroll
            for (int i = 0; i < 5; ++i) {
                float w8[8];
                if (TIN == 0) {
                    const float* row = fpf + (size_t)yy[i] * W + x0;
                    f32x4 Lv = *(const f32x4*)(row - 4);
                    f32x4 Cv = *(const f32x4*)(row);
                    f32x4 Rv = *(const f32x4*)(row + 4);
                    w8[0] = Lv[2]; w8[1] = Lv[3];
                    w8[2] = Cv[0]; w8[3] = Cv[1]; w8[4] = Cv[2]; w8[5] = Cv[3];
                    w8[6] = Rv[0]; w8[7] = Rv[1];
                    if (i == 2) ctr = Cv;
                } else {
                    const short* row = fpb + (size_t)yy[i] * W + x0;
                    s16x4 Lv = *(const s16x4*)(row - 4);
                    s16x4 Cv = *(const s16x4*)(row);
                    s16x4 Rv = *(const s16x4*)(row + 4);
                    w8[0] = bf2f(Lv[2]); w8[1] = bf2f(Lv[3]);
                    w8[2] = bf2f(Cv[0]); w8[3] = bf2f(Cv[1]);
                    w8[4] = bf2f(Cv[2]); w8[5] = bf2f(Cv[3]);
                    w8[6] = bf2f(Rv[0]); w8[7] = bf2f(Rv[1]);
                    if (i == 2) {
                        ctr[0] = w8[2]; ctr[1] = w8[3]; ctr[2] = w8[4]; ctr[3] = w8[5];
                    }
                }
#pragma unroll
                for (int o = 0; o < 4; ++o) {
                    float r = 0.f;
#pragma unroll
                    for (int j = 0; j < 5; ++j) r = fmaf(khv[j][o], w8[o + j], r);
                    acc[o] = fmaf(kvv[i][o], r, acc[o]);
                }
            }
        } else {
#pragma unroll
            for (int o = 0; o < 4; ++o) {
                int x = x0 + o;
                int xx[5];
#pragma unroll
                for (int j = 0; j < 5; ++j) {
                    int u = x + j - 2;
                    xx[j] = u < 0 ? 0 : (u >= W ? W - 1 : u);
                }
                float a = 0.f;
#pragma unroll
                for (int i = 0; i < 5; ++i) {
                    float r = 0.f;
#pragma unroll
                    for (int j = 0; j < 5; ++j) {
                        float fv = (TIN == 0) ? fpf[(size_t)yy[i] * W + xx[j]]
                                              : bf2f(fpb[(size_t)yy[i] * W + xx[j]]);
                        r = fmaf(khv[j][o], fv, r);
                    }
                    a = fmaf(kvv[i][o], r, a);
                }
                acc[o] = a;
                ctr[o] = (TIN == 0) ? fpf[(size_t)y * W + x] : bf2f(fpb[(size_t)y * W + x]);
            }
        }
        f32x4 o4;
#pragma unroll
        for (int o = 0; o < 4; ++o) o4[o] = m4[o] * acc[o] + (1.f - m4[o]) * ctr[o];
        *(f32x4*)(out + plane + (size_t)y * W + x0) = o4;
    }
}

// scalar-C fusion for C=3 final output, bf16 input (round-6 proven)
__global__ void fusion4b_kernel(const short* __restrict__ feat,
                                const float* __restrict__ kv,
                                const float* __restrict__ kh,
                                const float* __restrict__ m,
                                float* __restrict__ out,
                                int B, int C, int H, int W, int total) {
    int idx = blockIdx.x * blockDim.x + threadIdx.x;
    if (idx >= total) return;
    int Wg = W >> 2;
    int g = idx % Wg;
    int y = (idx / Wg) % H;
    int c = (idx / (Wg * H)) % C;
    int b = idx / (Wg * H * C);
    int x0 = g << 2;
    int HW = H * W;

    const short* fp = feat + (size_t)(b * C + c) * HW;
    int yy[5];
#pragma unroll
    for (int i = 0; i < 5; ++i) {
        int t = y + i - 2;
        yy[i] = t < 0 ? 0 : (t >= H ? H - 1 : t);
    }
    const float* kvb = kv + ((size_t)b * 5 * H + y) * W + x0;
    const float* khb = kh + ((size_t)b * 5 * H + y) * W + x0;

    f32x4 res, c4;
    if (g >= 1 && g <= Wg - 2) {
        f32x4 kvv[5], khv[5];
#pragma unroll
        for (int i = 0; i < 5; ++i) {
            kvv[i] = *(const f32x4*)(kvb + (size_t)i * HW);
            khv[i] = *(const f32x4*)(khb + (size_t)i * HW);
        }
        f32x4 acc = (f32x4){0.f, 0.f, 0.f, 0.f};
#pragma unroll
        for (int i = 0; i < 5; ++i) {
            const short* row = fp + (size_t)yy[i] * W + x0;
            s16x4 Lv = *(const s16x4*)(row - 4);
            s16x4 Cv = *(const s16x4*)(row);
            s16x4 Rv = *(const s16x4*)(row + 4);
            float w8[8] = {bf2f(Lv[2]), bf2f(Lv[3]), bf2f(Cv[0]), bf2f(Cv[1]),
                           bf2f(Cv[2]), bf2f(Cv[3]), bf2f(Rv[0]), bf2f(Rv[1])};
            if (i == 2) { c4[0] = w8[2]; c4[1] = w8[3]; c4[2] = w8[4]; c4[3] = w8[5]; }
#pragma unroll
            for (int o = 0; o < 4; ++o) {
                float r = 0.f;
#pragma unroll
                for (int j = 0; j < 5; ++j) r = fmaf(khv[j][o], w8[o + j], r);
                acc[o] = fmaf(kvv[i][o], r, acc[o]);
            }
        }
        res = acc;
    } else {
#pragma unroll
        for (int o = 0; o < 4; ++o) {
            int x = x0 + o;
            int xx[5];
#pragma unroll
            for (int j = 0; j < 5; ++j) {
                int u = x + j - 2;
                xx[j] = u < 0 ? 0 : (u >= W ? W - 1 : u);
            }
            float acc = 0.f;
#pragma unroll
            for (int i = 0; i < 5; ++i) {
                float r = 0.f;
#pragma unroll
                for (int j = 0; j < 5; ++j)
                    r = fmaf(khb[(size_t)j * HW + o], bf2f(fp[(size_t)yy[i] * W + xx[j]]), r);
                acc = fmaf(kvb[(size_t)i * HW + o], r, acc);
            }
            res[o] = acc;
            c4[o] = bf2f(fp[(size_t)y * W + x]);
        }
    }
    f32x4 m4 = *(const f32x4*)(m + ((size_t)b * H + y) * W + x0);
    f32x4 o4;
#pragma unroll
    for (int o = 0; o < 4; ++o) o4[o] = m4[o] * res[o] + (1.f - m4[o]) * c4[o];
    *(f32x4*)(out + ((size_t)(b * C + c) * H + y) * W + x0) = o4;
}

// ---------------------------------------------------------------------------
// Pad v2 (round-6 verified): line-complete both sides. xp fastest, then c8.
// ---------------------------------------------------------------------------
__global__ void pad_kernel(const float* __restrict__ in, short* __restrict__ pin,
                           int C, int H, int W, int Hp, int Wp, int po,
                           int xt, int nxt) {
    int b = blockIdx.z, yp = blockIdx.y;
    int ct = 256 / xt;
    int xtile = blockIdx.x % nxt;
    int cb = blockIdx.x / nxt;
    int xl = threadIdx.x % xt;
    int cl = threadIdx.x / xt;
    int xp = xtile * xt + xl;
    int c8 = cb * ct + cl;
    if (xp >= Wp) return;

    int y = yp - po, x = xp - po;
    bf16x8 v;
    if (y >= 0 && y < H && x >= 0 && x < W) {
        const float* ip = in + ((size_t)(b * C + c8 * 8) * H + y) * W + x;
        size_t HW = (size_t)H * W;
#pragma unroll
        for (int k = 0; k < 8; ++k) v[k] = f2bf(ip[k * HW]);
    } else {
        v = (bf16x8)0;
    }
    *(bf16x8*)(pin + (((size_t)b * Hp + yp) * Wp + xp) * C + c8 * 8) = v;
}

// zero pad borders of NHWC bf16 pin. mode1: all 4 edges; mode0: high edges only.
__global__ void zb_kernel(short* __restrict__ buf, int Hp, int Wp, int C8, int mode,
                          int total) {
    int tid = blockIdx.x * blockDim.x + threadIdx.x;
    if (tid >= total) return;
    int xp = (tid / C8) % Wp;
    int yp = (tid / (C8 * Wp)) % Hp;
    bool border = mode ? (yp == 0 || yp == Hp - 1 || xp == 0 || xp == Wp - 1)
                       : (yp == Hp - 1 || xp == Wp - 1);
    if (border) *(bf16x8*)(buf + (size_t)tid * 8) = (bf16x8)0;
}

// ---------------------------------------------------------------------------
// Weight transform (verified): wt[t9][m][ci]; s2 packs phase blocks
// {1,2,2,4} at offsets {0,1,3,5}.
// ---------------------------------------------------------------------------
__global__ void wtrans_kernel(const float* __restrict__ w, short* __restrict__ wt,
                              int Cin, int Cout, int Mp, int stride, int total) {
    int tid = blockIdx.x * blockDim.x + threadIdx.x;
    if (tid >= total) return;
    int ci = tid % Cin;
    int mm = (tid / Cin) % Mp;
    int t9 = tid / (Cin * Mp);
    int i, j;
    if (stride == 1) {
        int a = t9 / 3, bb = t9 % 3;
        i = 2 - a; j = 2 - bb;
    } else {
        int py, px, a, bb;
        if (t9 == 0) { py = 0; px = 0; a = 0; bb = 0; }
        else if (t9 < 3) { py = 0; px = 1; a = 0; bb = t9 - 1; }
        else if (t9 < 5) { py = 1; px = 0; a = t9 - 3; bb = 0; }
        else { int tt = t9 - 5; py = 1; px = 1; a = tt >> 1; bb = tt & 1; }
        i = (py == 0) ? 1 : (a == 0 ? 2 : 0);
        j = (px == 0) ? 1 : (bb == 0 ? 2 : 0);
    }
    float v = 0.f;
    if (mm < Cout) v = w[((ci * Cout + mm) * 3 + i) * 3 + j];
    wt[tid] = f2bf(v);
}

#define WAITVM(n) asm volatile("s_waitcnt vmcnt(" #n ")" ::: "memory")

// ---------------------------------------------------------------------------
// Implicit-GEMM convT, BM x BN tile, 4 waves, BK=64, XOR-swizzled LDS.
// K-loop: cc OUTER, taps inner. DBUF (counted vmcnt 2-phase) only where
// grid <= 2 blocks/CU (conv2). Round-10-verified.
// ---------------------------------------------------------------------------
template <int BM, int BN, bool S2, int OUTM, int ACT, bool DBUF>
__global__ void convt_mfma(const short* __restrict__ pin, const short* __restrict__ wtc,
                           float* __restrict__ outf, short* __restrict__ outb,
                           int Hpin, int Wpin, int Cin, int Mp, int Cout,
                           int Ho, int Wo, int Hu, int Wv,
                           int Hop, int Wop, int poff) {
    constexpr int WAVES_M = (BM >= 128) ? 2 : 1;
    constexpr int WM = BM / WAVES_M;
    constexpr int WN = BN / (4 / WAVES_M);
    constexpr int FM = WM / 16, FN = WN / 16;
    constexpr int RB = BN / 32;
    constexpr int AROUND = BM / 32;
    constexpr int NLOAD = AROUND + RB;
    constexpr int ABYTES = BM * 128;
    constexpr int BBYTES = BN * 128;
    __shared__ __align__(16) short Alds[(DBUF ? 2 : 1) * BM * 64];
    __shared__ __align__(16) short Blds[(DBUF ? 2 : 1) * BN * 64];

    int t = threadIdx.x, lane = t & 63, wid = t >> 6;
    int n0 = blockIdx.x * BN, m0 = blockIdx.y * BM;

    int py = 0, px = 0, ny = 3, nx = 3, dys = 0x210, dxs = 0x210, sy = 1;
    const short* wt = wtc;
    if (S2) {
        int pz = blockIdx.z;
        py = pz >> 1; px = pz & 1;
        ny = 1 + py; nx = 1 + px;
        dys = py ? 0x10 : 0; dxs = px ? 0x10 : 0;
        int pre = (pz == 0) ? 0 : (pz == 1) ? 1 : (pz == 2) ? 3 : 5;
        wt = wtc + (size_t)pre * Mp * Cin;
        sy = 2;
    }

    int rowS = t >> 3;
    int dS = (t & 7) ^ (rowS & 7);
    int HuWv = Hu * Wv;
    int pxg[RB];
#pragma unroll
    for (int rb = 0; rb < RB; ++rb) {
        int n = n0 + rowS + rb * 32;
        int b = n / HuWv, r = n % HuWv;
        int u = r / Wv, v = r % Wv;
        pxg[rb] = ((b * Hpin + u) * Wpin + v) * Cin + dS * 8;
    }
    int aoff = (m0 + rowS) * Cin + dS * 8;

    char* AB = (char*)Alds;
    char* BB = (char*)Blds;

    int wm = (WAVES_M == 2) ? (wid & 1) : 0;
    int wn = (WAVES_M == 2) ? (wid >> 1) : wid;
    int cb = lane >> 4;
    int rm[FM], rn[FN];
#pragma unroll
    for (int mf = 0; mf < FM; ++mf) rm[mf] = wm * WM + mf * 16 + (lane & 15);
#pragma unroll
    for (int nf = 0; nf < FN; ++nf) rn[nf] = wn * WN + nf * 16 + (lane & 15);

    f32x4 acc[FM][FN];
#pragma unroll
    for (int mf = 0; mf < FM; ++mf)
#pragma unroll
        for (int nf = 0; nf < FN; ++nf) acc[mf][nf] = (f32x4){0.f, 0.f, 0.f, 0.f};

    int ntap = ny * nx;
    int NK = (Cin >> 6) * ntap;

    auto COMPUTE = [&](int buf) {
        char* ABb = AB + buf * ABYTES;
        char* BBb = BB + buf * BBYTES;
#pragma unroll
        for (int h = 0; h < 2; ++h) {
            bf16x8 av[FM], bv[FN];
#pragma unroll
            for (int mf = 0; mf < FM; ++mf)
                av[mf] = *(const bf16x8*)(ABb + rm[mf] * 128 +
                                          (((h * 4 + cb) ^ (rm[mf] & 7)) << 4));
#pragma unroll
            for (int nf = 0; nf < FN; ++nf)
                bv[nf] = *(const bf16x8*)(BBb + rn[nf] * 128 +
                                          (((h * 4 + cb) ^ (rn[nf] & 7)) << 4));
#pragma unroll
            for (int mf = 0; mf < FM; ++mf)
#pragma unroll
                for (int nf = 0; nf < FN; ++nf)
                    acc[mf][nf] = __builtin_amdgcn_mfma_f32_16x16x32_bf16(
                        av[mf], bv[nf], acc[mf][nf], 0, 0, 0);
        }
    };

    if constexpr (DBUF) {
        auto STAGE = [&](int ks, int buf) {
            int ccq = ks / ntap;
            int ti = ks - ccq * ntap;
            int cc = ccq << 6;
            int a = ti / nx, bxx = ti - (ti / nx) * nx;
            int dy = (dys >> (4 * a)) & 15, dxv = (dxs >> (4 * bxx)) & 15;
            int tapoff = (dy * Wpin + dxv) * Cin;
            const short* wblk = wt + (size_t)ti * Mp * Cin;
            char* ABb = AB + buf * ABYTES;
            char* BBb = BB + buf * BBYTES;
#pragma unroll
            for (int r = 0; r < AROUND; ++r)
                gll16(wblk + cc + aoff + r * 32 * Cin, ABb + r * 4096 + (wid << 10));
#pragma unroll
            for (int rb = 0; rb < RB; ++rb)
                gll16(pin + tapoff + cc + pxg[rb], BBb + rb * 4096 + (wid << 10));
        };

        STAGE(0, 0);
        for (int ks = 0; ks < NK; ++ks) {
            int cur = ks & 1;
            bool more = (ks + 1 < NK);
            if (more) STAGE(ks + 1, cur ^ 1);
            if (more) {
                static_assert(!DBUF || NLOAD == 8, "vmcnt literal");
                WAITVM(8);
            } else {
                WAITVM(0);
            }
            __builtin_amdgcn_sched_barrier(0);
            __builtin_amdgcn_s_barrier();
            __builtin_amdgcn_sched_barrier(0);
            COMPUTE(cur);
            asm volatile("s_waitcnt lgkmcnt(0)" ::: "memory");
            __builtin_amdgcn_sched_barrier(0);
            __builtin_amdgcn_s_barrier();
        }
    } else {
        for (int ks = 0; ks < NK; ++ks) {
            int ccq = ks / ntap;
            int ti = ks - ccq * ntap;
            int cc = ccq << 6;
            int a = ti / nx, bxx = ti - (ti / nx) * nx;
            int dy = (dys >> (4 * a)) & 15, dxv = (dxs >> (4 * bxx)) & 15;
            int tapoff = (dy * Wpin + dxv) * Cin;
            const short* wblk = wt + (size_t)ti * Mp * Cin;
            __syncthreads();
            if (BM >= 32) {
#pragma unroll
                for (int r = 0; r < AROUND; ++r)
                    gll16(wblk + cc + aoff + r * 32 * Cin, AB + r * 4096 + (wid << 10));
            } else {
                if (wid < BM / 8) gll16(wblk + cc + aoff, AB + (wid << 10));
            }
#pragma unroll
            for (int rb = 0; rb < RB; ++rb)
                gll16(pin + tapoff + cc + pxg[rb], BB + rb * 4096 + (wid << 10));
            __syncthreads();
            COMPUTE(0);
        }
    }

#pragma unroll
    for (int mf = 0; mf < FM; ++mf) {
#pragma unroll
        for (int nf = 0; nf < FN; ++nf) {
            int p = n0 + wn * WN + nf * 16 + (lane & 15);
            int b = p / HuWv, r = p % HuWv;
            int u = r / Wv, v = r % Wv;
            int y = sy * u + py, x = sy * v + px;
            int cobase = m0 + wm * WM + mf * 16 + (lane >> 4) * 4;
            f32x4 vv = acc[mf][nf];
            if (OUTM == 1) {
                s16x4 pk;
#pragma unroll
                for (int reg = 0; reg < 4; ++reg) {
                    float f = vv[reg];
                    f = f > 0.f ? f : 0.f;
                    pk[reg] = f2bf(f);
                }
                *(s16x4*)(outb + (((size_t)b * Hop + y + poff) * Wop + (x + poff)) * Cout +
                          cobase) = pk;
            } else {
#pragma unroll
                for (int reg = 0; reg < 4; ++reg) {
                    int co = cobase + reg;
                    if (co < Cout) {
                        float f = vv[reg];
                        if (ACT == 0) f = f > 0.f ? f : 0.f;
                        else f = tanhf(f);
                        outb[((size_t)(b * Cout + co) * Ho + y) * Wo + x] = f2bf(f);
                    }
                }
            }
        }
    }
}

// ---------------------------------------------------------------------------

extern "C" void kernel_launch(void* const* d_in, const int* in_sizes, int n_in,
                              void* d_out, int out_size, void* d_ws, size_t ws_size,
                              hipStream_t stream) {
    const float* cont = (const float*)d_in[0];
    const float* w1 = (const float*)d_in[1];
    const float* w2 = (const float*)d_in[2];
    const float* w3 = (const float*)d_in[3];
    const float* w4 = (const float*)d_in[4];
    const float* w5 = (const float*)d_in[5];
    const float* w6 = (const float*)d_in[6];
    const float* kv0 = (const float*)d_in[7];
    const float* kh0 = (const float*)d_in[8];
    const float* m0 = (const float*)d_in[9];
    const float* kv1 = (const float*)d_in[10];
    const float* kh1 = (const float*)d_in[11];
    const float* m1 = (const float*)d_in[12];
    const float* kv2 = (const float*)d_in[13];
    const float* kh2 = (const float*)d_in[14];
    const float* m2 = (const float*)d_in[15];
    const float* kv3 = (const float*)d_in[16];
    const float* kh3 = (const float*)d_in[17];
    const float* m3 = (const float*)d_in[18];

    float* out = (float*)d_out;
    float* OUT0 = out;
    float* F8 = out + 1572864;
    float* F16 = out + 2097152;
    float* F32 = out + 18874368;

    const size_t MiB = 1 << 20;
    char* wsb = (char*)d_ws;
    short* WT = (short*)wsb;                  // [0,4)
    short* pin1 = (short*)(wsb + 4 * MiB);    // [4,5.2)
    short* t16b = (short*)(wsb + 6 * MiB);    // [6,39.6)
    short* pin2 = (short*)(wsb + 40 * MiB);   // [40,78)
    short* pin3 = (short*)(wsb + 80 * MiB);   // [80,97.8)
    short* t32bb = (short*)(wsb + 6 * MiB);   // [6,39.6)  (t16b dead)
    short* pin4 = (short*)(wsb + 40 * MiB);   // [40,75.7) (pin2 dead)
    short* pin5 = (short*)(wsb + 80 * MiB);   // [80,114.6)(pin3 dead)
    short* pin6 = (short*)(wsb + 6 * MiB);    // [6,75.2)  (t32bb,pin4 dead)
    short* toutb = (short*)(wsb + 76 * MiB);  // [76,79.2)

    short* wt1 = WT;                    // 9*512*64
    short* wt2 = wt1 + 294912;          // 9*256*512
    short* wt3 = wt2 + 1179648;         // 9*128*256
    short* wt4 = wt3 + 294912;          // 9*128*128
    short* wt5 = wt4 + 147456;          // 9*64*128
    short* wt6 = wt5 + 73728;           // 9*16*64

    auto wtr = [&](const float* w, short* wt, int Cin, int Cout, int Mp, int stride) {
        int total = 9 * Mp * Cin;
        wtrans_kernel<<<CDIV(total, 256), 256, 0, stream>>>(w, wt, Cin, Cout, Mp,
                                                            stride, total);
    };
    wtr(w1, wt1, 64, 512, 512, 2);
    wtr(w2, wt2, 512, 256, 256, 1);
    wtr(w3, wt3, 256, 128, 128, 2);
    wtr(w4, wt4, 128, 128, 128, 1);
    wtr(w5, wt5, 128, 64, 64, 2);
    wtr(w6, wt6, 64, 3, 16, 1);

    auto zb = [&](short* buf, int Hp, int Wp, int C8, int mode) {
        int zt = 32 * Hp * Wp * C8;
        zb_kernel<<<CDIV(zt, 256), 256, 0, stream>>>(buf, Hp, Wp, C8, mode, zt);
    };
    auto pad = [&](const float* src, short* pin, int C, int H, int W, int Hp, int Wp,
                   int po) {
        int C8 = C >> 3;
        int xt = (C8 >= 16) ? 16 : 32;
        int ct = 256 / xt;
        int nxt = CDIV(Wp, xt);
        dim3 g(nxt * (C8 / ct < 1 ? 1 : C8 / ct), Hp, 32);
        pad_kernel<<<g, 256, 0, stream>>>(src, pin, C, H, W, Hp, Wp, po, xt, nxt);
    };

    // 1. f8 = fusion(cont) -> F8 ; pad1: F8 -> pin1 (17x17x64, po=0)
    {
        int total = 32 * 16 * 16 * (16 >> 2);
        fusionC_kernel<0><<<CDIV(total, 256), 256, 0, stream>>>(cont, kv0, kh0, m0, F8,
                                                                32, 64, 16, 16, total);
    }
    pad(F8, pin1, 64, 16, 16, 17, 17, 0);

    // 2. conv1 (s2): pin1 -> t16b bf16 NCHW [32,512,32,32]
    {
        dim3 g(32 * 16 * 16 / 128, 512 / 128, 4);
        convt_mfma<128, 128, true, 2, 0, false><<<g, 256, 0, stream>>>(
            pin1, wt1, nullptr, t16b, 17, 17, 64, 512, 512, 32, 32, 16, 16, 0, 0, 0);
    }
    // 3. f16 = fusionL(t16b) -> F16 ; pad2: F16 -> pin2 (34x34x512, po=1)
    {
        dim3 g(512 / 32, 32, 32);
        fusionL_kernel<32, 32><<<g, 256, 0, stream>>>(t16b, kv1, kh1, m1, F16, 512, 32);
    }
    pad(F16, pin2, 512, 32, 32, 34, 34, 1);

    // 4. conv2 (s1): pin2 -> pin3 (33x33x256 NHWC). DBUF: grid=512=2/CU.
    zb(pin3, 33, 33, 32, 0);
    {
        dim3 g(32 * 32 * 32 / 128, 256 / 128, 1);
        convt_mfma<128, 128, false, 1, 0, true><<<g, 256, 0, stream>>>(
            pin2, wt2, nullptr, pin3, 34, 34, 512, 256, 256, 32, 32, 32, 32, 33, 33, 0);
    }
    // 5. conv3 (s2): pin3 -> t32bb bf16 NCHW [32,128,64,64]
    {
        dim3 g(32 * 32 * 32 / 128, 1, 4);
        convt_mfma<128, 128, true, 2, 0, false><<<g, 256, 0, stream>>>(
            pin3, wt3, nullptr, t32bb, 33, 33, 256, 128, 128, 64, 64, 32, 32, 0, 0, 0);
    }
    // 6. f32 = fusionL(t32bb) -> F32 ; pad4: F32 -> pin4 (66x66x128, po=1)
    {
        dim3 g(128 / 16, 64, 32);
        fusionL_kernel<64, 16><<<g, 256, 0, stream>>>(t32bb, kv2, kh2, m2, F32, 128, 64);
    }
    pad(F32, pin4, 128, 64, 64, 66, 66, 1);

    // 7. conv4 (s1): pin4 -> pin5 (65x65x128 NHWC)
    zb(pin5, 65, 65, 16, 0);
    {
        dim3 g(32 * 64 * 64 / 128, 1, 1);
        convt_mfma<128, 128, false, 1, 0, false><<<g, 256, 0, stream>>>(
            pin4, wt4, nullptr, pin5, 66, 66, 128, 128, 128, 64, 64, 64, 64, 65, 65, 0);
    }
    // 8. conv5 (s2): pin5 -> pin6 (130x130x64 NHWC, poff=1)
    zb(pin6, 130, 130, 8, 1);
    {
        dim3 g(32 * 64 * 64 / 128, 1, 4);
        convt_mfma<64, 128, true, 1, 0, false><<<g, 256, 0, stream>>>(
            pin5, wt5, nullptr, pin6, 65, 65, 128, 64, 64, 128, 128, 64, 64, 130, 130, 1);
    }
    // 9. conv6 (s1): pin6 -> toutb bf16 NCHW [32,3,128,128] tanh
    {
        dim3 g(32 * 128 * 128 / 64, 1, 1);
        convt_mfma<16, 64, false, 2, 1, false><<<g, 256, 0, stream>>>(
            pin6, wt6, nullptr, toutb, 130, 130, 64, 16, 3, 128, 128, 128, 128, 0, 0, 0);
    }
    // 10. out = fusion(toutb) -> OUT0 (C=3, bf16 input)
    {
        int total = 32 * 3 * 128 * (128 >> 2);
        fusion4b_kernel<<<CDIV(total, 256), 256, 0, stream>>>(toutb, kv3, kh3, m3, OUT0,
                                                              32, 3, 128, 128, total);
    }
}

// Round 12
// 502.900 us; speedup vs baseline: 1.5890x; 1.0798x over previous
//
#include <hip/hip_runtime.h>
#include <hip/hip_bf16.h>
#include <cmath>

#define CDIV(a, b) (((a) + (b) - 1) / (b))

typedef __attribute__((ext_vector_type(8))) short bf16x8;
typedef __attribute__((ext_vector_type(4))) short s16x4;
typedef __attribute__((ext_vector_type(4))) float f32x4;
typedef __attribute__((ext_vector_type(2))) float f32x2;

__device__ __forceinline__ short f2bf(float f) {
    unsigned u = __float_as_uint(f);
    unsigned r = (u + 0x7fff + ((u >> 16) & 1)) >> 16;
    return (short)r;
}
__device__ __forceinline__ float bf2f(short s) {
    return __uint_as_float(((unsigned)(unsigned short)s) << 16);
}

__device__ __forceinline__ void gll16(const void* g, void* l) {
    __builtin_amdgcn_global_load_lds((const __attribute__((address_space(1))) void*)g,
                                     (__attribute__((address_space(3))) void*)l, 16, 0, 0);
}

// ---------------------------------------------------------------------------
// LDS-staged fusion (bf16 NCHW in, fp32 NCHW out, optional bf16 NHWC pin out).
// Block = CB channels x one y x full W. THREADS = CB*W/4.
// PIN: transpose results in LDS (Lout[x][c]) then line-complete NHWC write
// at (y+1, x+1) with c0 64B-aligned chunks. Borders zeroed by zb (mode 1).
// ---------------------------------------------------------------------------
template <int W, int CB, int THREADS, bool PIN>
__global__ void fusionL_kernel(const short* __restrict__ feat,
                               const float* __restrict__ kv,
                               const float* __restrict__ kh,
                               const float* __restrict__ m,
                               float* __restrict__ out, short* __restrict__ pin,
                               int C, int H, int Hp, int Wp) {
    constexpr int ROWF = W + 4;
    constexpr int W8 = W / 8;
    constexpr int XG = W / 4;
    __shared__ float L[CB * 5 * ROWF];
    __shared__ short Lout[PIN ? CB * W : 1];

    int tid = threadIdx.x;
    int cblk = blockIdx.x, y = blockIdx.y, b = blockIdx.z;
    int c0 = cblk * CB;
    int HW = H * W;

    int ry[5];
#pragma unroll
    for (int i = 0; i < 5; ++i) {
        int t = y + i - 2;
        ry[i] = t < 0 ? 0 : (t >= H ? H - 1 : t);
    }

    // ---- stage 5 rows x CB channels (bf16 -> fp32), interior
    for (int s = tid; s < CB * 5 * W8; s += THREADS) {
        int c = s / (5 * W8);
        int rr = (s / W8) % 5;
        int xc = s % W8;
        const short* src = feat + ((size_t)(b * C + c0 + c) * H + ry[rr]) * W + xc * 8;
        bf16x8 v = *(const bf16x8*)src;
        float* dst = L + (c * 5 + rr) * ROWF + 2 + xc * 8;
#pragma unroll
        for (int k = 0; k < 8; k += 2) {
            f32x2 t2 = {bf2f(v[k]), bf2f(v[k + 1])};
            *(f32x2*)(dst + k) = t2;
        }
    }
    // ---- replicated x-borders
    if (tid < CB * 5) {
        int c = tid / 5, rr = tid % 5;
        const short* srow = feat + ((size_t)(b * C + c0 + c) * H + ry[rr]) * W;
        float v0 = bf2f(srow[0]), v1 = bf2f(srow[W - 1]);
        float* base = L + (c * 5 + rr) * ROWF;
        base[0] = v0; base[1] = v0;
        base[W + 2] = v1; base[W + 3] = v1;
    }
    __syncthreads();

    // ---- compute: thread (c, xg), 4 px
    int xg = tid % XG;
    int c = tid / XG;
    int x0 = xg * 4;

    const float* kvb = kv + ((size_t)b * 5 * H + y) * W + x0;
    const float* khb = kh + ((size_t)b * 5 * H + y) * W + x0;
    f32x4 kvv[5], khv[5];
#pragma unroll
    for (int i = 0; i < 5; ++i) {
        kvv[i] = *(const f32x4*)(kvb + (size_t)i * HW);
        khv[i] = *(const f32x4*)(khb + (size_t)i * HW);
    }
    f32x4 m4 = *(const f32x4*)(m + ((size_t)b * H + y) * W + x0);

    f32x4 acc = (f32x4){0.f, 0.f, 0.f, 0.f};
    f32x4 ctr;
    const float* Lc = L + c * 5 * ROWF + x0;
#pragma unroll
    for (int i = 0; i < 5; ++i) {
        f32x4 wa = *(const f32x4*)(Lc + i * ROWF);
        f32x4 wb = *(const f32x4*)(Lc + i * ROWF + 4);
        float w8[8] = {wa[0], wa[1], wa[2], wa[3], wb[0], wb[1], wb[2], wb[3]};
        if (i == 2) { ctr[0] = w8[2]; ctr[1] = w8[3]; ctr[2] = w8[4]; ctr[3] = w8[5]; }
#pragma unroll
        for (int o = 0; o < 4; ++o) {
            float r = 0.f;
#pragma unroll
            for (int j = 0; j < 5; ++j) r = fmaf(khv[j][o], w8[o + j], r);
            acc[o] = fmaf(kvv[i][o], r, acc[o]);
        }
    }
    f32x4 o4;
#pragma unroll
    for (int o = 0; o < 4; ++o) o4[o] = m4[o] * acc[o] + (1.f - m4[o]) * ctr[o];
    *(f32x4*)(out + (size_t)(b * C + c0 + c) * HW + (size_t)y * W + x0) = o4;

    if (PIN) {
        // transpose to x-major bf16 and write NHWC lines
#pragma unroll
        for (int o = 0; o < 4; ++o) Lout[(x0 + o) * CB + c] = f2bf(o4[o]);
        __syncthreads();
        constexpr int CK = CB / 8;                 // 16B chunks per x
        for (int s = tid; s < W * CK; s += THREADS) {
            int xp = s / CK, ck = s % CK;
            bf16x8 v = *(const bf16x8*)(Lout + xp * CB + ck * 8);
            *(bf16x8*)(pin + (((size_t)b * Hp + y + 1) * Wp + xp + 1) * C + c0 + ck * 8) = v;
        }
    }
}

// ---------------------------------------------------------------------------
// C-blocked fusion (round-6 proven): 4 channels x 4 pixels, fp32 input.
// ---------------------------------------------------------------------------
template <int TIN>
__global__ void fusionC_kernel(const void* __restrict__ featv,
                               const float* __restrict__ kv,
                               const float* __restrict__ kh,
                               const float* __restrict__ m,
                               float* __restrict__ out,
                               int B, int C, int H, int W, int total) {
    int idx = blockIdx.x * blockDim.x + threadIdx.x;
    if (idx >= total) return;
    int Wg = W >> 2;
    int C4 = C >> 2;
    int g = idx % Wg;
    int cg = (idx / Wg) % C4;
    int y = (idx / (Wg * C4)) % H;
    int b = idx / (Wg * C4 * H);
    int x0 = g << 2, c0 = cg << 2;
    int HW = H * W;

    int yy[5];
#pragma unroll
    for (int i = 0; i < 5; ++i) {
        int t = y + i - 2;
        yy[i] = t < 0 ? 0 : (t >= H ? H - 1 : t);
    }
    const float* kvb = kv + ((size_t)b * 5 * H + y) * W + x0;
    const float* khb = kh + ((size_t)b * 5 * H + y) * W + x0;
    f32x4 kvv[5], khv[5];
#pragma unroll
    for (int i = 0; i < 5; ++i) {
        kvv[i] = *(const f32x4*)(kvb + (size_t)i * HW);
        khv[i] = *(const f32x4*)(khb + (size_t)i * HW);
    }
    f32x4 m4 = *(const f32x4*)(m + ((size_t)b * H + y) * W + x0);
    bool interior = (g >= 1 && g <= Wg - 2);

#pragma unroll
    for (int cc = 0; cc < 4; ++cc) {
        size_t plane = (size_t)(b * C + c0 + cc) * HW;
        const float* fpf = (const float*)featv + plane;
        const short* fpb = (const short*)featv + plane;
        f32x4 acc = (f32x4){0.f, 0.f, 0.f, 0.f};
        f32x4 ctr;
        if (interior) {
#pragma unroll
            for (int i = 0; i < 5; ++i) {
                float w8[8];
                if (TIN == 0) {
                    const float* row = fpf + (size_t)yy[i] * W + x0;
                    f32x4 Lv = *(const f32x4*)(row - 4);
                    f32x4 Cv = *(const f32x4*)(row);
                    f32x4 Rv = *(const f32x4*)(row + 4);
                    w8[0] = Lv[2]; w8[1] = Lv[3];
                    w8[2] = Cv[0]; w8[3] = Cv[1]; w8[4] = Cv[2]; w8[5] = Cv[3];
                    w8[6] = Rv[0]; w8[7] = Rv[1];
                    if (i == 2) ctr = Cv;
                } else {
                    const short* row = fpb + (size_t)yy[i] * W + x0;
                    s16x4 Lv = *(const s16x4*)(row - 4);
                    s16x4 Cv = *(const s16x4*)(row);
                    s16x4 Rv = *(const s16x4*)(row + 4);
                    w8[0] = bf2f(Lv[2]); w8[1] = bf2f(Lv[3]);
                    w8[2] = bf2f(Cv[0]); w8[3] = bf2f(Cv[1]);
                    w8[4] = bf2f(Cv[2]); w8[5] = bf2f(Cv[3]);
                    w8[6] = bf2f(Rv[0]); w8[7] = bf2f(Rv[1]);
                    if (i == 2) {
                        ctr[0] = w8[2]; ctr[1] = w8[3]; ctr[2] = w8[4]; ctr[3] = w8[5];
                    }
                }
#pragma unroll
                for (int o = 0; o < 4; ++o) {
                    float r = 0.f;
#pragma unroll
                    for (int j = 0; j < 5; ++j) r = fmaf(khv[j][o], w8[o + j], r);
                    acc[o] = fmaf(kvv[i][o], r, acc[o]);
                }
            }
        } else {
#pragma unroll
            for (int o = 0; o < 4; ++o) {
                int x = x0 + o;
                int xx[5];
#pragma unroll
                for (int j = 0; j < 5; ++j) {
                    int u = x + j - 2;
                    xx[j] = u < 0 ? 0 : (u >= W ? W - 1 : u);
                }
                float a = 0.f;
#pragma unroll
                for (int i = 0; i < 5; ++i) {
                    float r = 0.f;
#pragma unroll
                    for (int j = 0; j < 5; ++j) {
                        float fv = (TIN == 0) ? fpf[(size_t)yy[i] * W + xx[j]]
                                              : bf2f(fpb[(size_t)yy[i] * W + xx[j]]);
                        r = fmaf(khv[j][o], fv, r);
                    }
                    a = fmaf(kvv[i][o], r, a);
                }
                acc[o] = a;
                ctr[o] = (TIN == 0) ? fpf[(size_t)y * W + x] : bf2f(fpb[(size_t)y * W + x]);
            }
        }
        f32x4 o4;
#pragma unroll
        for (int o = 0; o < 4; ++o) o4[o] = m4[o] * acc[o] + (1.f - m4[o]) * ctr[o];
        *(f32x4*)(out + plane + (size_t)y * W + x0) = o4;
    }
}

// scalar-C fusion for C=3 final output, bf16 input (round-6 proven)
__global__ void fusion4b_kernel(const short* __restrict__ feat,
                                const float* __restrict__ kv,
                                const float* __restrict__ kh,
                                const float* __restrict__ m,
                                float* __restrict__ out,
                                int B, int C, int H, int W, int total) {
    int idx = blockIdx.x * blockDim.x + threadIdx.x;
    if (idx >= total) return;
    int Wg = W >> 2;
    int g = idx % Wg;
    int y = (idx / Wg) % H;
    int c = (idx / (Wg * H)) % C;
    int b = idx / (Wg * H * C);
    int x0 = g << 2;
    int HW = H * W;

    const short* fp = feat + (size_t)(b * C + c) * HW;
    int yy[5];
#pragma unroll
    for (int i = 0; i < 5; ++i) {
        int t = y + i - 2;
        yy[i] = t < 0 ? 0 : (t >= H ? H - 1 : t);
    }
    const float* kvb = kv + ((size_t)b * 5 * H + y) * W + x0;
    const float* khb = kh + ((size_t)b * 5 * H + y) * W + x0;

    f32x4 res, c4;
    if (g >= 1 && g <= Wg - 2) {
        f32x4 kvv[5], khv[5];
#pragma unroll
        for (int i = 0; i < 5; ++i) {
            kvv[i] = *(const f32x4*)(kvb + (size_t)i * HW);
            khv[i] = *(const f32x4*)(khb + (size_t)i * HW);
        }
        f32x4 acc = (f32x4){0.f, 0.f, 0.f, 0.f};
#pragma unroll
        for (int i = 0; i < 5; ++i) {
            const short* row = fp + (size_t)yy[i] * W + x0;
            s16x4 Lv = *(const s16x4*)(row - 4);
            s16x4 Cv = *(const s16x4*)(row);
            s16x4 Rv = *(const s16x4*)(row + 4);
            float w8[8] = {bf2f(Lv[2]), bf2f(Lv[3]), bf2f(Cv[0]), bf2f(Cv[1]),
                           bf2f(Cv[2]), bf2f(Cv[3]), bf2f(Rv[0]), bf2f(Rv[1])};
            if (i == 2) { c4[0] = w8[2]; c4[1] = w8[3]; c4[2] = w8[4]; c4[3] = w8[5]; }
#pragma unroll
            for (int o = 0; o < 4; ++o) {
                float r = 0.f;
#pragma unroll
                for (int j = 0; j < 5; ++j) r = fmaf(khv[j][o], w8[o + j], r);
                acc[o] = fmaf(kvv[i][o], r, acc[o]);
            }
        }
        res = acc;
    } else {
#pragma unroll
        for (int o = 0; o < 4; ++o) {
            int x = x0 + o;
            int xx[5];
#pragma unroll
            for (int j = 0; j < 5; ++j) {
                int u = x + j - 2;
                xx[j] = u < 0 ? 0 : (u >= W ? W - 1 : u);
            }
            float acc = 0.f;
#pragma unroll
            for (int i = 0; i < 5; ++i) {
                float r = 0.f;
#pragma unroll
                for (int j = 0; j < 5; ++j)
                    r = fmaf(khb[(size_t)j * HW + o], bf2f(fp[(size_t)yy[i] * W + xx[j]]), r);
                acc = fmaf(kvb[(size_t)i * HW + o], r, acc);
            }
            res[o] = acc;
            c4[o] = bf2f(fp[(size_t)y * W + x]);
        }
    }
    f32x4 m4 = *(const f32x4*)(m + ((size_t)b * H + y) * W + x0);
    f32x4 o4;
#pragma unroll
    for (int o = 0; o < 4; ++o) o4[o] = m4[o] * res[o] + (1.f - m4[o]) * c4[o];
    *(f32x4*)(out + ((size_t)(b * C + c) * H + y) * W + x0) = o4;
}

// ---------------------------------------------------------------------------
// Pad v2 (round-6 verified): used only for pin1 now.
// ---------------------------------------------------------------------------
__global__ void pad_kernel(const float* __restrict__ in, short* __restrict__ pin,
                           int C, int H, int W, int Hp, int Wp, int po,
                           int xt, int nxt) {
    int b = blockIdx.z, yp = blockIdx.y;
    int ct = 256 / xt;
    int xtile = blockIdx.x % nxt;
    int cb = blockIdx.x / nxt;
    int xl = threadIdx.x % xt;
    int cl = threadIdx.x / xt;
    int xp = xtile * xt + xl;
    int c8 = cb * ct + cl;
    if (xp >= Wp) return;

    int y = yp - po, x = xp - po;
    bf16x8 v;
    if (y >= 0 && y < H && x >= 0 && x < W) {
        const float* ip = in + ((size_t)(b * C + c8 * 8) * H + y) * W + x;
        size_t HW = (size_t)H * W;
#pragma unroll
        for (int k = 0; k < 8; ++k) v[k] = f2bf(ip[k * HW]);
    } else {
        v = (bf16x8)0;
    }
    *(bf16x8*)(pin + (((size_t)b * Hp + yp) * Wp + xp) * C + c8 * 8) = v;
}

// zero pad borders of NHWC bf16 pin. mode1: all 4 edges; mode0: high edges only.
__global__ void zb_kernel(short* __restrict__ buf, int Hp, int Wp, int C8, int mode,
                          int total) {
    int tid = blockIdx.x * blockDim.x + threadIdx.x;
    if (tid >= total) return;
    int xp = (tid / C8) % Wp;
    int yp = (tid / (C8 * Wp)) % Hp;
    bool border = mode ? (yp == 0 || yp == Hp - 1 || xp == 0 || xp == Wp - 1)
                       : (yp == Hp - 1 || xp == Wp - 1);
    if (border) *(bf16x8*)(buf + (size_t)tid * 8) = (bf16x8)0;
}

// ---------------------------------------------------------------------------
// Weight transform (verified): wt[t9][m][ci]; s2 packs phase blocks
// {1,2,2,4} at offsets {0,1,3,5}.
// ---------------------------------------------------------------------------
__global__ void wtrans_kernel(const float* __restrict__ w, short* __restrict__ wt,
                              int Cin, int Cout, int Mp, int stride, int total) {
    int tid = blockIdx.x * blockDim.x + threadIdx.x;
    if (tid >= total) return;
    int ci = tid % Cin;
    int mm = (tid / Cin) % Mp;
    int t9 = tid / (Cin * Mp);
    int i, j;
    if (stride == 1) {
        int a = t9 / 3, bb = t9 % 3;
        i = 2 - a; j = 2 - bb;
    } else {
        int py, px, a, bb;
        if (t9 == 0) { py = 0; px = 0; a = 0; bb = 0; }
        else if (t9 < 3) { py = 0; px = 1; a = 0; bb = t9 - 1; }
        else if (t9 < 5) { py = 1; px = 0; a = t9 - 3; bb = 0; }
        else { int tt = t9 - 5; py = 1; px = 1; a = tt >> 1; bb = tt & 1; }
        i = (py == 0) ? 1 : (a == 0 ? 2 : 0);
        j = (px == 0) ? 1 : (bb == 0 ? 2 : 0);
    }
    float v = 0.f;
    if (mm < Cout) v = w[((ci * Cout + mm) * 3 + i) * 3 + j];
    wt[tid] = f2bf(v);
}

#define WAITVM(n) asm volatile("s_waitcnt vmcnt(" #n ")" ::: "memory")

// ---------------------------------------------------------------------------
// Implicit-GEMM convT, BM x BN tile, 4 waves, BK=64, XOR-swizzled LDS.
// K-loop: cc OUTER, taps inner. DBUF only where grid <= 2 blocks/CU (conv2).
// ---------------------------------------------------------------------------
template <int BM, int BN, bool S2, int OUTM, int ACT, bool DBUF>
__global__ void convt_mfma(const short* __restrict__ pin, const short* __restrict__ wtc,
                           float* __restrict__ outf, short* __restrict__ outb,
                           int Hpin, int Wpin, int Cin, int Mp, int Cout,
                           int Ho, int Wo, int Hu, int Wv,
                           int Hop, int Wop, int poff) {
    constexpr int WAVES_M = (BM >= 128) ? 2 : 1;
    constexpr int WM = BM / WAVES_M;
    constexpr int WN = BN / (4 / WAVES_M);
    constexpr int FM = WM / 16, FN = WN / 16;
    constexpr int RB = BN / 32;
    constexpr int AROUND = BM / 32;
    constexpr int NLOAD = AROUND + RB;
    constexpr int ABYTES = BM * 128;
    constexpr int BBYTES = BN * 128;
    __shared__ __align__(16) short Alds[(DBUF ? 2 : 1) * BM * 64];
    __shared__ __align__(16) short Blds[(DBUF ? 2 : 1) * BN * 64];

    int t = threadIdx.x, lane = t & 63, wid = t >> 6;
    int n0 = blockIdx.x * BN, m0 = blockIdx.y * BM;

    int py = 0, px = 0, ny = 3, nx = 3, dys = 0x210, dxs = 0x210, sy = 1;
    const short* wt = wtc;
    if (S2) {
        int pz = blockIdx.z;
        py = pz >> 1; px = pz & 1;
        ny = 1 + py; nx = 1 + px;
        dys = py ? 0x10 : 0; dxs = px ? 0x10 : 0;
        int pre = (pz == 0) ? 0 : (pz == 1) ? 1 : (pz == 2) ? 3 : 5;
        wt = wtc + (size_t)pre * Mp * Cin;
        sy = 2;
    }

    int rowS = t >> 3;
    int dS = (t & 7) ^ (rowS & 7);
    int HuWv = Hu * Wv;
    int pxg[RB];
#pragma unroll
    for (int rb = 0; rb < RB; ++rb) {
        int n = n0 + rowS + rb * 32;
        int b = n / HuWv, r = n % HuWv;
        int u = r / Wv, v = r % Wv;
        pxg[rb] = ((b * Hpin + u) * Wpin + v) * Cin + dS * 8;
    }
    int aoff = (m0 + rowS) * Cin + dS * 8;

    char* AB = (char*)Alds;
    char* BB = (char*)Blds;

    int wm = (WAVES_M == 2) ? (wid & 1) : 0;
    int wn = (WAVES_M == 2) ? (wid >> 1) : wid;
    int cb = lane >> 4;
    int rm[FM], rn[FN];
#pragma unroll
    for (int mf = 0; mf < FM; ++mf) rm[mf] = wm * WM + mf * 16 + (lane & 15);
#pragma unroll
    for (int nf = 0; nf < FN; ++nf) rn[nf] = wn * WN + nf * 16 + (lane & 15);

    f32x4 acc[FM][FN];
#pragma unroll
    for (int mf = 0; mf < FM; ++mf)
#pragma unroll
        for (int nf = 0; nf < FN; ++nf) acc[mf][nf] = (f32x4){0.f, 0.f, 0.f, 0.f};

    int ntap = ny * nx;
    int NK = (Cin >> 6) * ntap;

    auto COMPUTE = [&](int buf) {
        char* ABb = AB + buf * ABYTES;
        char* BBb = BB + buf * BBYTES;
#pragma unroll
        for (int h = 0; h < 2; ++h) {
            bf16x8 av[FM], bv[FN];
#pragma unroll
            for (int mf = 0; mf < FM; ++mf)
                av[mf] = *(const bf16x8*)(ABb + rm[mf] * 128 +
                                          (((h * 4 + cb) ^ (rm[mf] & 7)) << 4));
#pragma unroll
            for (int nf = 0; nf < FN; ++nf)
                bv[nf] = *(const bf16x8*)(BBb + rn[nf] * 128 +
                                          (((h * 4 + cb) ^ (rn[nf] & 7)) << 4));
#pragma unroll
            for (int mf = 0; mf < FM; ++mf)
#pragma unroll
                for (int nf = 0; nf < FN; ++nf)
                    acc[mf][nf] = __builtin_amdgcn_mfma_f32_16x16x32_bf16(
                        av[mf], bv[nf], acc[mf][nf], 0, 0, 0);
        }
    };

    if constexpr (DBUF) {
        auto STAGE = [&](int ks, int buf) {
            int ccq = ks / ntap;
            int ti = ks - ccq * ntap;
            int cc = ccq << 6;
            int a = ti / nx, bxx = ti - (ti / nx) * nx;
            int dy = (dys >> (4 * a)) & 15, dxv = (dxs >> (4 * bxx)) & 15;
            int tapoff = (dy * Wpin + dxv) * Cin;
            const short* wblk = wt + (size_t)ti * Mp * Cin;
            char* ABb = AB + buf * ABYTES;
            char* BBb = BB + buf * BBYTES;
#pragma unroll
            for (int r = 0; r < AROUND; ++r)
                gll16(wblk + cc + aoff + r * 32 * Cin, ABb + r * 4096 + (wid << 10));
#pragma unroll
            for (int rb = 0; rb < RB; ++rb)
                gll16(pin + tapoff + cc + pxg[rb], BBb + rb * 4096 + (wid << 10));
        };

        STAGE(0, 0);
        for (int ks = 0; ks < NK; ++ks) {
            int cur = ks & 1;
            bool more = (ks + 1 < NK);
            if (more) STAGE(ks + 1, cur ^ 1);
            if (more) {
                static_assert(!DBUF || NLOAD == 8, "vmcnt literal");
                WAITVM(8);
            } else {
                WAITVM(0);
            }
            __builtin_amdgcn_sched_barrier(0);
            __builtin_amdgcn_s_barrier();
            __builtin_amdgcn_sched_barrier(0);
            COMPUTE(cur);
            asm volatile("s_waitcnt lgkmcnt(0)" ::: "memory");
            __builtin_amdgcn_sched_barrier(0);
            __builtin_amdgcn_s_barrier();
        }
    } else {
        for (int ks = 0; ks < NK; ++ks) {
            int ccq = ks / ntap;
            int ti = ks - ccq * ntap;
            int cc = ccq << 6;
            int a = ti / nx, bxx = ti - (ti / nx) * nx;
            int dy = (dys >> (4 * a)) & 15, dxv = (dxs >> (4 * bxx)) & 15;
            int tapoff = (dy * Wpin + dxv) * Cin;
            const short* wblk = wt + (size_t)ti * Mp * Cin;
            __syncthreads();
            if (BM >= 32) {
#pragma unroll
                for (int r = 0; r < AROUND; ++r)
                    gll16(wblk + cc + aoff + r * 32 * Cin, AB + r * 4096 + (wid << 10));
            } else {
                if (wid < BM / 8) gll16(wblk + cc + aoff, AB + (wid << 10));
            }
#pragma unroll
            for (int rb = 0; rb < RB; ++rb)
                gll16(pin + tapoff + cc + pxg[rb], BB + rb * 4096 + (wid << 10));
            __syncthreads();
            COMPUTE(0);
        }
    }

#pragma unroll
    for (int mf = 0; mf < FM; ++mf) {
#pragma unroll
        for (int nf = 0; nf < FN; ++nf) {
            int p = n0 + wn * WN + nf * 16 + (lane & 15);
            int b = p / HuWv, r = p % HuWv;
            int u = r / Wv, v = r % Wv;
            int y = sy * u + py, x = sy * v + px;
            int cobase = m0 + wm * WM + mf * 16 + (lane >> 4) * 4;
            f32x4 vv = acc[mf][nf];
            if (OUTM == 1) {
                s16x4 pk;
#pragma unroll
                for (int reg = 0; reg < 4; ++reg) {
                    float f = vv[reg];
                    f = f > 0.f ? f : 0.f;
                    pk[reg] = f2bf(f);
                }
                *(s16x4*)(outb + (((size_t)b * Hop + y + poff) * Wop + (x + poff)) * Cout +
                          cobase) = pk;
            } else {
#pragma unroll
                for (int reg = 0; reg < 4; ++reg) {
                    int co = cobase + reg;
                    if (co < Cout) {
                        float f = vv[reg];
                        if (ACT == 0) f = f > 0.f ? f : 0.f;
                        else f = tanhf(f);
                        outb[((size_t)(b * Cout + co) * Ho + y) * Wo + x] = f2bf(f);
                    }
                }
            }
        }
    }
}

// ---------------------------------------------------------------------------

extern "C" void kernel_launch(void* const* d_in, const int* in_sizes, int n_in,
                              void* d_out, int out_size, void* d_ws, size_t ws_size,
                              hipStream_t stream) {
    const float* cont = (const float*)d_in[0];
    const float* w1 = (const float*)d_in[1];
    const float* w2 = (const float*)d_in[2];
    const float* w3 = (const float*)d_in[3];
    const float* w4 = (const float*)d_in[4];
    const float* w5 = (const float*)d_in[5];
    const float* w6 = (const float*)d_in[6];
    const float* kv0 = (const float*)d_in[7];
    const float* kh0 = (const float*)d_in[8];
    const float* m0 = (const float*)d_in[9];
    const float* kv1 = (const float*)d_in[10];
    const float* kh1 = (const float*)d_in[11];
    const float* m1 = (const float*)d_in[12];
    const float* kv2 = (const float*)d_in[13];
    const float* kh2 = (const float*)d_in[14];
    const float* m2 = (const float*)d_in[15];
    const float* kv3 = (const float*)d_in[16];
    const float* kh3 = (const float*)d_in[17];
    const float* m3 = (const float*)d_in[18];

    float* out = (float*)d_out;
    float* OUT0 = out;
    float* F8 = out + 1572864;
    float* F16 = out + 2097152;
    float* F32 = out + 18874368;

    const size_t MiB = 1 << 20;
    char* wsb = (char*)d_ws;
    short* WT = (short*)wsb;                  // [0,4)
    short* pin1 = (short*)(wsb + 4 * MiB);    // [4,5.2)
    short* t16b = (short*)(wsb + 6 * MiB);    // [6,39.6)
    short* pin2 = (short*)(wsb + 40 * MiB);   // [40,78)
    short* pin3 = (short*)(wsb + 80 * MiB);   // [80,97.8)
    short* t32bb = (short*)(wsb + 6 * MiB);   // [6,39.6)  (t16b dead)
    short* pin4 = (short*)(wsb + 40 * MiB);   // [40,75.7) (pin2 dead)
    short* pin5 = (short*)(wsb + 80 * MiB);   // [80,114.6)(pin3 dead)
    short* pin6 = (short*)(wsb + 6 * MiB);    // [6,75.2)  (t32bb,pin4 dead)
    short* toutb = (short*)(wsb + 76 * MiB);  // [76,79.2)

    short* wt1 = WT;                    // 9*512*64
    short* wt2 = wt1 + 294912;          // 9*256*512
    short* wt3 = wt2 + 1179648;         // 9*128*256
    short* wt4 = wt3 + 294912;          // 9*128*128
    short* wt5 = wt4 + 147456;          // 9*64*128
    short* wt6 = wt5 + 73728;           // 9*16*64

    auto wtr = [&](const float* w, short* wt, int Cin, int Cout, int Mp, int stride) {
        int total = 9 * Mp * Cin;
        wtrans_kernel<<<CDIV(total, 256), 256, 0, stream>>>(w, wt, Cin, Cout, Mp,
                                                            stride, total);
    };
    wtr(w1, wt1, 64, 512, 512, 2);
    wtr(w2, wt2, 512, 256, 256, 1);
    wtr(w3, wt3, 256, 128, 128, 2);
    wtr(w4, wt4, 128, 128, 128, 1);
    wtr(w5, wt5, 128, 64, 64, 2);
    wtr(w6, wt6, 64, 3, 16, 1);

    auto zb = [&](short* buf, int Hp, int Wp, int C8, int mode) {
        int zt = 32 * Hp * Wp * C8;
        zb_kernel<<<CDIV(zt, 256), 256, 0, stream>>>(buf, Hp, Wp, C8, mode, zt);
    };
    auto pad = [&](const float* src, short* pin, int C, int H, int W, int Hp, int Wp,
                   int po) {
        int C8 = C >> 3;
        int xt = (C8 >= 16) ? 16 : 32;
        int ct = 256 / xt;
        int nxt = CDIV(Wp, xt);
        dim3 g(nxt * (C8 / ct < 1 ? 1 : C8 / ct), Hp, 32);
        pad_kernel<<<g, 256, 0, stream>>>(src, pin, C, H, W, Hp, Wp, po, xt, nxt);
    };

    // 1. f8 = fusion(cont) -> F8 ; pad1: F8 -> pin1 (17x17x64, po=0)
    {
        int total = 32 * 16 * 16 * (16 >> 2);
        fusionC_kernel<0><<<CDIV(total, 256), 256, 0, stream>>>(cont, kv0, kh0, m0, F8,
                                                                32, 64, 16, 16, total);
    }
    pad(F8, pin1, 64, 16, 16, 17, 17, 0);

    // 2. conv1 (s2): pin1 -> t16b bf16 NCHW [32,512,32,32]
    {
        dim3 g(32 * 16 * 16 / 128, 512 / 128, 4);
        convt_mfma<128, 128, true, 2, 0, false><<<g, 256, 0, stream>>>(
            pin1, wt1, nullptr, t16b, 17, 17, 64, 512, 512, 32, 32, 16, 16, 0, 0, 0);
    }
    // 3. f16 = fusionL(t16b) -> F16 + pin2 (34x34x512 NHWC interior; zb borders)
    zb(pin2, 34, 34, 64, 1);
    {
        dim3 g(512 / 32, 32, 32);
        fusionL_kernel<32, 32, 256, true><<<g, 256, 0, stream>>>(
            t16b, kv1, kh1, m1, F16, pin2, 512, 32, 34, 34);
    }
    // 4. conv2 (s1): pin2 -> pin3 (33x33x256 NHWC). DBUF: grid=512=2/CU.
    zb(pin3, 33, 33, 32, 0);
    {
        dim3 g(32 * 32 * 32 / 128, 256 / 128, 1);
        convt_mfma<128, 128, false, 1, 0, true><<<g, 256, 0, stream>>>(
            pin2, wt2, nullptr, pin3, 34, 34, 512, 256, 256, 32, 32, 32, 32, 33, 33, 0);
    }
    // 5. conv3 (s2): pin3 -> t32bb bf16 NCHW [32,128,64,64]
    {
        dim3 g(32 * 32 * 32 / 128, 1, 4);
        convt_mfma<128, 128, true, 2, 0, false><<<g, 256, 0, stream>>>(
            pin3, wt3, nullptr, t32bb, 33, 33, 256, 128, 128, 64, 64, 32, 32, 0, 0, 0);
    }
    // 6. f32 = fusionL(t32bb) -> F32 + pin4 (66x66x128 NHWC interior; zb borders)
    zb(pin4, 66, 66, 16, 1);
    {
        dim3 g(128 / 32, 64, 32);
        fusionL_kernel<64, 32, 512, true><<<g, 512, 0, stream>>>(
            t32bb, kv2, kh2, m2, F32, pin4, 128, 64, 66, 66);
    }
    // 7. conv4 (s1): pin4 -> pin5 (65x65x128 NHWC)
    zb(pin5, 65, 65, 16, 0);
    {
        dim3 g(32 * 64 * 64 / 128, 1, 1);
        convt_mfma<128, 128, false, 1, 0, false><<<g, 256, 0, stream>>>(
            pin4, wt4, nullptr, pin5, 66, 66, 128, 128, 128, 64, 64, 64, 64, 65, 65, 0);
    }
    // 8. conv5 (s2): pin5 -> pin6 (130x130x64 NHWC, poff=1)
    zb(pin6, 130, 130, 8, 1);
    {
        dim3 g(32 * 64 * 64 / 128, 1, 4);
        convt_mfma<64, 128, true, 1, 0, false><<<g, 256, 0, stream>>>(
            pin5, wt5, nullptr, pin6, 65, 65, 128, 64, 64, 128, 128, 64, 64, 130, 130, 1);
    }
    // 9. conv6 (s1): pin6 -> toutb bf16 NCHW [32,3,128,128] tanh
    {
        dim3 g(32 * 128 * 128 / 64, 1, 1);
        convt_mfma<16, 64, false, 2, 1, false><<<g, 256, 0, stream>>>(
            pin6, wt6, nullptr, toutb, 130, 130, 64, 16, 3, 128, 128, 128, 128, 0, 0, 0);
    }
    // 10. out = fusion(toutb) -> OUT0 (C=3, bf16 input)
    {
        int total = 32 * 3 * 128 * (128 >> 2);
        fusion4b_kernel<<<CDIV(total, 256), 256, 0, stream>>>(toutb, kv3, kh3, m3, OUT0,
                                                              32, 3, 128, 128, total);
    }
}

// Round 13
// 481.439 us; speedup vs baseline: 1.6598x; 1.0446x over previous
//
#include <hip/hip_runtime.h>
#include <hip/hip_bf16.h>
#include <cmath>

#define CDIV(a, b) (((a) + (b) - 1) / (b))

typedef __attribute__((ext_vector_type(8))) short bf16x8;
typedef __attribute__((ext_vector_type(4))) short s16x4;
typedef __attribute__((ext_vector_type(4))) float f32x4;
typedef __attribute__((ext_vector_type(2))) float f32x2;

__device__ __forceinline__ short f2bf(float f) {
    unsigned u = __float_as_uint(f);
    unsigned r = (u + 0x7fff + ((u >> 16) & 1)) >> 16;
    return (short)r;
}
__device__ __forceinline__ float bf2f(short s) {
    return __uint_as_float(((unsigned)(unsigned short)s) << 16);
}

__device__ __forceinline__ void gll16(const void* g, void* l) {
    __builtin_amdgcn_global_load_lds((const __attribute__((address_space(1))) void*)g,
                                     (__attribute__((address_space(3))) void*)l, 16, 0, 0);
}

// ---------------------------------------------------------------------------
// LDS-staged fusion (round-12 verified). bf16 NCHW in, fp32 NCHW out,
// optional bf16 NHWC pin out (line-complete, interior; borders via zb2).
// ---------------------------------------------------------------------------
template <int W, int CB, int THREADS, bool PIN>
__global__ void fusionL_kernel(const short* __restrict__ feat,
                               const float* __restrict__ kv,
                               const float* __restrict__ kh,
                               const float* __restrict__ m,
                               float* __restrict__ out, short* __restrict__ pin,
                               int C, int H, int Hp, int Wp) {
    constexpr int ROWF = W + 4;
    constexpr int W8 = W / 8;
    constexpr int XG = W / 4;
    __shared__ float L[CB * 5 * ROWF];
    __shared__ short Lout[PIN ? CB * W : 1];

    int tid = threadIdx.x;
    int cblk = blockIdx.x, y = blockIdx.y, b = blockIdx.z;
    int c0 = cblk * CB;
    int HW = H * W;

    int ry[5];
#pragma unroll
    for (int i = 0; i < 5; ++i) {
        int t = y + i - 2;
        ry[i] = t < 0 ? 0 : (t >= H ? H - 1 : t);
    }

    for (int s = tid; s < CB * 5 * W8; s += THREADS) {
        int c = s / (5 * W8);
        int rr = (s / W8) % 5;
        int xc = s % W8;
        const short* src = feat + ((size_t)(b * C + c0 + c) * H + ry[rr]) * W + xc * 8;
        bf16x8 v = *(const bf16x8*)src;
        float* dst = L + (c * 5 + rr) * ROWF + 2 + xc * 8;
#pragma unroll
        for (int k = 0; k < 8; k += 2) {
            f32x2 t2 = {bf2f(v[k]), bf2f(v[k + 1])};
            *(f32x2*)(dst + k) = t2;
        }
    }
    if (tid < CB * 5) {
        int c = tid / 5, rr = tid % 5;
        const short* srow = feat + ((size_t)(b * C + c0 + c) * H + ry[rr]) * W;
        float v0 = bf2f(srow[0]), v1 = bf2f(srow[W - 1]);
        float* base = L + (c * 5 + rr) * ROWF;
        base[0] = v0; base[1] = v0;
        base[W + 2] = v1; base[W + 3] = v1;
    }
    __syncthreads();

    int xg = tid % XG;
    int c = tid / XG;
    int x0 = xg * 4;

    const float* kvb = kv + ((size_t)b * 5 * H + y) * W + x0;
    const float* khb = kh + ((size_t)b * 5 * H + y) * W + x0;
    f32x4 kvv[5], khv[5];
#pragma unroll
    for (int i = 0; i < 5; ++i) {
        kvv[i] = *(const f32x4*)(kvb + (size_t)i * HW);
        khv[i] = *(const f32x4*)(khb + (size_t)i * HW);
    }
    f32x4 m4 = *(const f32x4*)(m + ((size_t)b * H + y) * W + x0);

    f32x4 acc = (f32x4){0.f, 0.f, 0.f, 0.f};
    f32x4 ctr;
    const float* Lc = L + c * 5 * ROWF + x0;
#pragma unroll
    for (int i = 0; i < 5; ++i) {
        f32x4 wa = *(const f32x4*)(Lc + i * ROWF);
        f32x4 wb = *(const f32x4*)(Lc + i * ROWF + 4);
        float w8[8] = {wa[0], wa[1], wa[2], wa[3], wb[0], wb[1], wb[2], wb[3]};
        if (i == 2) { ctr[0] = w8[2]; ctr[1] = w8[3]; ctr[2] = w8[4]; ctr[3] = w8[5]; }
#pragma unroll
        for (int o = 0; o < 4; ++o) {
            float r = 0.f;
#pragma unroll
            for (int j = 0; j < 5; ++j) r = fmaf(khv[j][o], w8[o + j], r);
            acc[o] = fmaf(kvv[i][o], r, acc[o]);
        }
    }
    f32x4 o4;
#pragma unroll
    for (int o = 0; o < 4; ++o) o4[o] = m4[o] * acc[o] + (1.f - m4[o]) * ctr[o];
    *(f32x4*)(out + (size_t)(b * C + c0 + c) * HW + (size_t)y * W + x0) = o4;

    if (PIN) {
#pragma unroll
        for (int o = 0; o < 4; ++o) Lout[(x0 + o) * CB + c] = f2bf(o4[o]);
        __syncthreads();
        constexpr int CK = CB / 8;
        for (int s = tid; s < W * CK; s += THREADS) {
            int xp = s / CK, ck = s % CK;
            bf16x8 v = *(const bf16x8*)(Lout + xp * CB + ck * 8);
            *(bf16x8*)(pin + (((size_t)b * Hp + y + 1) * Wp + xp + 1) * C + c0 + ck * 8) = v;
        }
    }
}

// ---------------------------------------------------------------------------
// C-blocked fusion (round-6 proven): 4 channels x 4 pixels, fp32 input.
// ---------------------------------------------------------------------------
template <int TIN>
__global__ void fusionC_kernel(const void* __restrict__ featv,
                               const float* __restrict__ kv,
                               const float* __restrict__ kh,
                               const float* __restrict__ m,
                               float* __restrict__ out,
                               int B, int C, int H, int W, int total) {
    int idx = blockIdx.x * blockDim.x + threadIdx.x;
    if (idx >= total) return;
    int Wg = W >> 2;
    int C4 = C >> 2;
    int g = idx % Wg;
    int cg = (idx / Wg) % C4;
    int y = (idx / (Wg * C4)) % H;
    int b = idx / (Wg * C4 * H);
    int x0 = g << 2, c0 = cg << 2;
    int HW = H * W;

    int yy[5];
#pragma unroll
    for (int i = 0; i < 5; ++i) {
        int t = y + i - 2;
        yy[i] = t < 0 ? 0 : (t >= H ? H - 1 : t);
    }
    const float* kvb = kv + ((size_t)b * 5 * H + y) * W + x0;
    const float* khb = kh + ((size_t)b * 5 * H + y) * W + x0;
    f32x4 kvv[5], khv[5];
#pragma unroll
    for (int i = 0; i < 5; ++i) {
        kvv[i] = *(const f32x4*)(kvb + (size_t)i * HW);
        khv[i] = *(const f32x4*)(khb + (size_t)i * HW);
    }
    f32x4 m4 = *(const f32x4*)(m + ((size_t)b * H + y) * W + x0);
    bool interior = (g >= 1 && g <= Wg - 2);

#pragma unroll
    for (int cc = 0; cc < 4; ++cc) {
        size_t plane = (size_t)(b * C + c0 + cc) * HW;
        const float* fpf = (const float*)featv + plane;
        const short* fpb = (const short*)featv + plane;
        f32x4 acc = (f32x4){0.f, 0.f, 0.f, 0.f};
        f32x4 ctr;
        if (interior) {
#pragma unroll
            for (int i = 0; i < 5; ++i) {
                float w8[8];
                if (TIN == 0) {
                    const float* row = fpf + (size_t)yy[i] * W + x0;
                    f32x4 Lv = *(const f32x4*)(row - 4);
                    f32x4 Cv = *(const f32x4*)(row);
                    f32x4 Rv = *(const f32x4*)(row + 4);
                    w8[0] = Lv[2]; w8[1] = Lv[3];
                    w8[2] = Cv[0]; w8[3] = Cv[1]; w8[4] = Cv[2]; w8[5] = Cv[3];
                    w8[6] = Rv[0]; w8[7] = Rv[1];
                    if (i == 2) ctr = Cv;
                } else {
                    const short* row = fpb + (size_t)yy[i] * W + x0;
                    s16x4 Lv = *(const s16x4*)(row - 4);
                    s16x4 Cv = *(const s16x4*)(row);
                    s16x4 Rv = *(const s16x4*)(row + 4);
                    w8[0] = bf2f(Lv[2]); w8[1] = bf2f(Lv[3]);
                    w8[2] = bf2f(Cv[0]); w8[3] = bf2f(Cv[1]);
                    w8[4] = bf2f(Cv[2]); w8[5] = bf2f(Cv[3]);
                    w8[6] = bf2f(Rv[0]); w8[7] = bf2f(Rv[1]);
                    if (i == 2) {
                        ctr[0] = w8[2]; ctr[1] = w8[3]; ctr[2] = w8[4]; ctr[3] = w8[5];
                    }
                }
#pragma unroll
                for (int o = 0; o < 4; ++o) {
                    float r = 0.f;
#pragma unroll
                    for (int j = 0; j < 5; ++j) r = fmaf(khv[j][o], w8[o + j], r);
                    acc[o] = fmaf(kvv[i][o], r, acc[o]);
                }
            }
        } else {
#pragma unroll
            for (int o = 0; o < 4; ++o) {
                int x = x0 + o;
                int xx[5];
#pragma unroll
                for (int j = 0; j < 5; ++j) {
                    int u = x + j - 2;
                    xx[j] = u < 0 ? 0 : (u >= W ? W - 1 : u);
                }
                float a = 0.f;
#pragma unroll
                for (int i = 0; i < 5; ++i) {
                    float r = 0.f;
#pragma unroll
                    for (int j = 0; j < 5; ++j) {
                        float fv = (TIN == 0) ? fpf[(size_t)yy[i] * W + xx[j]]
                                              : bf2f(fpb[(size_t)yy[i] * W + xx[j]]);
                        r = fmaf(khv[j][o], fv, r);
                    }
                    a = fmaf(kvv[i][o], r, a);
                }
                acc[o] = a;
                ctr[o] = (TIN == 0) ? fpf[(size_t)y * W + x] : bf2f(fpb[(size_t)y * W + x]);
            }
        }
        f32x4 o4;
#pragma unroll
        for (int o = 0; o < 4; ++o) o4[o] = m4[o] * acc[o] + (1.f - m4[o]) * ctr[o];
        *(f32x4*)(out + plane + (size_t)y * W + x0) = o4;
    }
}

// scalar-C fusion for C=3 final output, bf16 input (round-6 proven)
__global__ void fusion4b_kernel(const short* __restrict__ feat,
                                const float* __restrict__ kv,
                                const float* __restrict__ kh,
                                const float* __restrict__ m,
                                float* __restrict__ out,
                                int B, int C, int H, int W, int total) {
    int idx = blockIdx.x * blockDim.x + threadIdx.x;
    if (idx >= total) return;
    int Wg = W >> 2;
    int g = idx % Wg;
    int y = (idx / Wg) % H;
    int c = (idx / (Wg * H)) % C;
    int b = idx / (Wg * H * C);
    int x0 = g << 2;
    int HW = H * W;

    const short* fp = feat + (size_t)(b * C + c) * HW;
    int yy[5];
#pragma unroll
    for (int i = 0; i < 5; ++i) {
        int t = y + i - 2;
        yy[i] = t < 0 ? 0 : (t >= H ? H - 1 : t);
    }
    const float* kvb = kv + ((size_t)b * 5 * H + y) * W + x0;
    const float* khb = kh + ((size_t)b * 5 * H + y) * W + x0;

    f32x4 res, c4;
    if (g >= 1 && g <= Wg - 2) {
        f32x4 kvv[5], khv[5];
#pragma unroll
        for (int i = 0; i < 5; ++i) {
            kvv[i] = *(const f32x4*)(kvb + (size_t)i * HW);
            khv[i] = *(const f32x4*)(khb + (size_t)i * HW);
        }
        f32x4 acc = (f32x4){0.f, 0.f, 0.f, 0.f};
#pragma unroll
        for (int i = 0; i < 5; ++i) {
            const short* row = fp + (size_t)yy[i] * W + x0;
            s16x4 Lv = *(const s16x4*)(row - 4);
            s16x4 Cv = *(const s16x4*)(row);
            s16x4 Rv = *(const s16x4*)(row + 4);
            float w8[8] = {bf2f(Lv[2]), bf2f(Lv[3]), bf2f(Cv[0]), bf2f(Cv[1]),
                           bf2f(Cv[2]), bf2f(Cv[3]), bf2f(Rv[0]), bf2f(Rv[1])};
            if (i == 2) { c4[0] = w8[2]; c4[1] = w8[3]; c4[2] = w8[4]; c4[3] = w8[5]; }
#pragma unroll
            for (int o = 0; o < 4; ++o) {
                float r = 0.f;
#pragma unroll
                for (int j = 0; j < 5; ++j) r = fmaf(khv[j][o], w8[o + j], r);
                acc[o] = fmaf(kvv[i][o], r, acc[o]);
            }
        }
        res = acc;
    } else {
#pragma unroll
        for (int o = 0; o < 4; ++o) {
            int x = x0 + o;
            int xx[5];
#pragma unroll
            for (int j = 0; j < 5; ++j) {
                int u = x + j - 2;
                xx[j] = u < 0 ? 0 : (u >= W ? W - 1 : u);
            }
            float acc = 0.f;
#pragma unroll
            for (int i = 0; i < 5; ++i) {
                float r = 0.f;
#pragma unroll
                for (int j = 0; j < 5; ++j)
                    r = fmaf(khb[(size_t)j * HW + o], bf2f(fp[(size_t)yy[i] * W + xx[j]]), r);
                acc = fmaf(kvb[(size_t)i * HW + o], r, acc);
            }
            res[o] = acc;
            c4[o] = bf2f(fp[(size_t)y * W + x]);
        }
    }
    f32x4 m4 = *(const f32x4*)(m + ((size_t)b * H + y) * W + x0);
    f32x4 o4;
#pragma unroll
    for (int o = 0; o < 4; ++o) o4[o] = m4[o] * res[o] + (1.f - m4[o]) * c4[o];
    *(f32x4*)(out + ((size_t)(b * C + c) * H + y) * W + x0) = o4;
}

// ---------------------------------------------------------------------------
// Pad v2 (round-6 verified): used only for pin1.
// ---------------------------------------------------------------------------
__global__ void pad_kernel(const float* __restrict__ in, short* __restrict__ pin,
                           int C, int H, int W, int Hp, int Wp, int po,
                           int xt, int nxt) {
    int b = blockIdx.z, yp = blockIdx.y;
    int ct = 256 / xt;
    int xtile = blockIdx.x % nxt;
    int cb = blockIdx.x / nxt;
    int xl = threadIdx.x % xt;
    int cl = threadIdx.x / xt;
    int xp = xtile * xt + xl;
    int c8 = cb * ct + cl;
    if (xp >= Wp) return;

    int y = yp - po, x = xp - po;
    bf16x8 v;
    if (y >= 0 && y < H && x >= 0 && x < W) {
        const float* ip = in + ((size_t)(b * C + c8 * 8) * H + y) * W + x;
        size_t HW = (size_t)H * W;
#pragma unroll
        for (int k = 0; k < 8; ++k) v[k] = f2bf(ip[k * HW]);
    } else {
        v = (bf16x8)0;
    }
    *(bf16x8*)(pin + (((size_t)b * Hp + yp) * Wp + xp) * C + c8 * 8) = v;
}

// ---------------------------------------------------------------------------
// zb2: border-only zero of NHWC bf16 pin. mode1: all 4 edges; mode0: high
// edges only. Enumerates border cells directly (no idle interior threads).
// ---------------------------------------------------------------------------
__global__ void zb2_kernel(short* __restrict__ buf, int Hp, int Wp, int C8, int mode,
                           int ncell, int total) {
    int tid = blockIdx.x * blockDim.x + threadIdx.x;
    if (tid >= total) return;
    int c8 = tid % C8;
    int cell = (tid / C8) % ncell;
    int b = tid / (C8 * ncell);
    int yp, xp;
    if (mode) {
        if (cell < Wp) { yp = 0; xp = cell; }
        else if (cell < 2 * Wp) { yp = Hp - 1; xp = cell - Wp; }
        else { int r = cell - 2 * Wp; yp = 1 + (r >> 1); xp = (r & 1) ? (Wp - 1) : 0; }
    } else {
        if (cell < Wp) { yp = Hp - 1; xp = cell; }
        else { yp = cell - Wp; xp = Wp - 1; }
    }
    *(bf16x8*)(buf + (((size_t)b * Hp + yp) * Wp + xp) * (C8 * 8) + c8 * 8) = (bf16x8)0;
}

// ---------------------------------------------------------------------------
// Merged weight transform: blockIdx.y selects one of 6 weights.
// wt[t9][m][ci]; s2 packs phase blocks {1,2,2,4} at offsets {0,1,3,5}.
// ---------------------------------------------------------------------------
struct WtAll {
    const float* w[6];
    short* wt[6];
    int Cin[6], Cout[6], Mp[6], stride[6], total[6];
};

__global__ void wtrans_all_kernel(WtAll d) {
    int wi = blockIdx.y;
    int tid = blockIdx.x * blockDim.x + threadIdx.x;
    if (tid >= d.total[wi]) return;
    int Cin = d.Cin[wi], Cout = d.Cout[wi], Mp = d.Mp[wi], stride = d.stride[wi];
    const float* w = d.w[wi];
    short* wt = d.wt[wi];

    int ci = tid % Cin;
    int mm = (tid / Cin) % Mp;
    int t9 = tid / (Cin * Mp);
    int i, j;
    if (stride == 1) {
        int a = t9 / 3, bb = t9 % 3;
        i = 2 - a; j = 2 - bb;
    } else {
        int py, px, a, bb;
        if (t9 == 0) { py = 0; px = 0; a = 0; bb = 0; }
        else if (t9 < 3) { py = 0; px = 1; a = 0; bb = t9 - 1; }
        else if (t9 < 5) { py = 1; px = 0; a = t9 - 3; bb = 0; }
        else { int tt = t9 - 5; py = 1; px = 1; a = tt >> 1; bb = tt & 1; }
        i = (py == 0) ? 1 : (a == 0 ? 2 : 0);
        j = (px == 0) ? 1 : (bb == 0 ? 2 : 0);
    }
    float v = 0.f;
    if (mm < Cout) v = w[((ci * Cout + mm) * 3 + i) * 3 + j];
    wt[tid] = f2bf(v);
}

#define WAITVM(n) asm volatile("s_waitcnt vmcnt(" #n ")" ::: "memory")

// ---------------------------------------------------------------------------
// Implicit-GEMM convT (round-10/12 verified), BM x BN tile, 4 waves, BK=64,
// XOR-swizzled LDS. cc outer, taps inner. DBUF only for conv2 (2 blocks/CU).
// ---------------------------------------------------------------------------
template <int BM, int BN, bool S2, int OUTM, int ACT, bool DBUF>
__global__ void convt_mfma(const short* __restrict__ pin, const short* __restrict__ wtc,
                           float* __restrict__ outf, short* __restrict__ outb,
                           int Hpin, int Wpin, int Cin, int Mp, int Cout,
                           int Ho, int Wo, int Hu, int Wv,
                           int Hop, int Wop, int poff) {
    constexpr int WAVES_M = (BM >= 128) ? 2 : 1;
    constexpr int WM = BM / WAVES_M;
    constexpr int WN = BN / (4 / WAVES_M);
    constexpr int FM = WM / 16, FN = WN / 16;
    constexpr int RB = BN / 32;
    constexpr int AROUND = BM / 32;
    constexpr int NLOAD = AROUND + RB;
    constexpr int ABYTES = BM * 128;
    constexpr int BBYTES = BN * 128;
    __shared__ __align__(16) short Alds[(DBUF ? 2 : 1) * BM * 64];
    __shared__ __align__(16) short Blds[(DBUF ? 2 : 1) * BN * 64];

    int t = threadIdx.x, lane = t & 63, wid = t >> 6;
    int n0 = blockIdx.x * BN, m0 = blockIdx.y * BM;

    int py = 0, px = 0, ny = 3, nx = 3, dys = 0x210, dxs = 0x210, sy = 1;
    const short* wt = wtc;
    if (S2) {
        int pz = blockIdx.z;
        py = pz >> 1; px = pz & 1;
        ny = 1 + py; nx = 1 + px;
        dys = py ? 0x10 : 0; dxs = px ? 0x10 : 0;
        int pre = (pz == 0) ? 0 : (pz == 1) ? 1 : (pz == 2) ? 3 : 5;
        wt = wtc + (size_t)pre * Mp * Cin;
        sy = 2;
    }

    int rowS = t >> 3;
    int dS = (t & 7) ^ (rowS & 7);
    int HuWv = Hu * Wv;
    int pxg[RB];
#pragma unroll
    for (int rb = 0; rb < RB; ++rb) {
        int n = n0 + rowS + rb * 32;
        int b = n / HuWv, r = n % HuWv;
        int u = r / Wv, v = r % Wv;
        pxg[rb] = ((b * Hpin + u) * Wpin + v) * Cin + dS * 8;
    }
    int aoff = (m0 + rowS) * Cin + dS * 8;

    char* AB = (char*)Alds;
    char* BB = (char*)Blds;

    int wm = (WAVES_M == 2) ? (wid & 1) : 0;
    int wn = (WAVES_M == 2) ? (wid >> 1) : wid;
    int cb = lane >> 4;
    int rm[FM], rn[FN];
#pragma unroll
    for (int mf = 0; mf < FM; ++mf) rm[mf] = wm * WM + mf * 16 + (lane & 15);
#pragma unroll
    for (int nf = 0; nf < FN; ++nf) rn[nf] = wn * WN + nf * 16 + (lane & 15);

    f32x4 acc[FM][FN];
#pragma unroll
    for (int mf = 0; mf < FM; ++mf)
#pragma unroll
        for (int nf = 0; nf < FN; ++nf) acc[mf][nf] = (f32x4){0.f, 0.f, 0.f, 0.f};

    int ntap = ny * nx;
    int NK = (Cin >> 6) * ntap;

    auto COMPUTE = [&](int buf) {
        char* ABb = AB + buf * ABYTES;
        char* BBb = BB + buf * BBYTES;
#pragma unroll
        for (int h = 0; h < 2; ++h) {
            bf16x8 av[FM], bv[FN];
#pragma unroll
            for (int mf = 0; mf < FM; ++mf)
                av[mf] = *(const bf16x8*)(ABb + rm[mf] * 128 +
                                          (((h * 4 + cb) ^ (rm[mf] & 7)) << 4));
#pragma unroll
            for (int nf = 0; nf < FN; ++nf)
                bv[nf] = *(const bf16x8*)(BBb + rn[nf] * 128 +
                                          (((h * 4 + cb) ^ (rn[nf] & 7)) << 4));
#pragma unroll
            for (int mf = 0; mf < FM; ++mf)
#pragma unroll
                for (int nf = 0; nf < FN; ++nf)
                    acc[mf][nf] = __builtin_amdgcn_mfma_f32_16x16x32_bf16(
                        av[mf], bv[nf], acc[mf][nf], 0, 0, 0);
        }
    };

    if constexpr (DBUF) {
        auto STAGE = [&](int ks, int buf) {
            int ccq = ks / ntap;
            int ti = ks - ccq * ntap;
            int cc = ccq << 6;
            int a = ti / nx, bxx = ti - (ti / nx) * nx;
            int dy = (dys >> (4 * a)) & 15, dxv = (dxs >> (4 * bxx)) & 15;
            int tapoff = (dy * Wpin + dxv) * Cin;
            const short* wblk = wt + (size_t)ti * Mp * Cin;
            char* ABb = AB + buf * ABYTES;
            char* BBb = BB + buf * BBYTES;
#pragma unroll
            for (int r = 0; r < AROUND; ++r)
                gll16(wblk + cc + aoff + r * 32 * Cin, ABb + r * 4096 + (wid << 10));
#pragma unroll
            for (int rb = 0; rb < RB; ++rb)
                gll16(pin + tapoff + cc + pxg[rb], BBb + rb * 4096 + (wid << 10));
        };

        STAGE(0, 0);
        for (int ks = 0; ks < NK; ++ks) {
            int cur = ks & 1;
            bool more = (ks + 1 < NK);
            if (more) STAGE(ks + 1, cur ^ 1);
            if (more) {
                static_assert(!DBUF || NLOAD == 8, "vmcnt literal");
                WAITVM(8);
            } else {
                WAITVM(0);
            }
            __builtin_amdgcn_sched_barrier(0);
            __builtin_amdgcn_s_barrier();
            __builtin_amdgcn_sched_barrier(0);
            COMPUTE(cur);
            asm volatile("s_waitcnt lgkmcnt(0)" ::: "memory");
            __builtin_amdgcn_sched_barrier(0);
            __builtin_amdgcn_s_barrier();
        }
    } else {
        for (int ks = 0; ks < NK; ++ks) {
            int ccq = ks / ntap;
            int ti = ks - ccq * ntap;
            int cc = ccq << 6;
            int a = ti / nx, bxx = ti - (ti / nx) * nx;
            int dy = (dys >> (4 * a)) & 15, dxv = (dxs >> (4 * bxx)) & 15;
            int tapoff = (dy * Wpin + dxv) * Cin;
            const short* wblk = wt + (size_t)ti * Mp * Cin;
            __syncthreads();
            if (BM >= 32) {
#pragma unroll
                for (int r = 0; r < AROUND; ++r)
                    gll16(wblk + cc + aoff + r * 32 * Cin, AB + r * 4096 + (wid << 10));
            } else {
                if (wid < BM / 8) gll16(wblk + cc + aoff, AB + (wid << 10));
            }
#pragma unroll
            for (int rb = 0; rb < RB; ++rb)
                gll16(pin + tapoff + cc + pxg[rb], BB + rb * 4096 + (wid << 10));
            __syncthreads();
            COMPUTE(0);
        }
    }

#pragma unroll
    for (int mf = 0; mf < FM; ++mf) {
#pragma unroll
        for (int nf = 0; nf < FN; ++nf) {
            int p = n0 + wn * WN + nf * 16 + (lane & 15);
            int b = p / HuWv, r = p % HuWv;
            int u = r / Wv, v = r % Wv;
            int y = sy * u + py, x = sy * v + px;
            int cobase = m0 + wm * WM + mf * 16 + (lane >> 4) * 4;
            f32x4 vv = acc[mf][nf];
            if (OUTM == 1) {
                s16x4 pk;
#pragma unroll
                for (int reg = 0; reg < 4; ++reg) {
                    float f = vv[reg];
                    f = f > 0.f ? f : 0.f;
                    pk[reg] = f2bf(f);
                }
                *(s16x4*)(outb + (((size_t)b * Hop + y + poff) * Wop + (x + poff)) * Cout +
                          cobase) = pk;
            } else {
#pragma unroll
                for (int reg = 0; reg < 4; ++reg) {
                    int co = cobase + reg;
                    if (co < Cout) {
                        float f = vv[reg];
                        if (ACT == 0) f = f > 0.f ? f : 0.f;
                        else f = tanhf(f);
                        outb[((size_t)(b * Cout + co) * Ho + y) * Wo + x] = f2bf(f);
                    }
                }
            }
        }
    }
}

// ---------------------------------------------------------------------------

extern "C" void kernel_launch(void* const* d_in, const int* in_sizes, int n_in,
                              void* d_out, int out_size, void* d_ws, size_t ws_size,
                              hipStream_t stream) {
    const float* cont = (const float*)d_in[0];
    const float* w1 = (const float*)d_in[1];
    const float* w2 = (const float*)d_in[2];
    const float* w3 = (const float*)d_in[3];
    const float* w4 = (const float*)d_in[4];
    const float* w5 = (const float*)d_in[5];
    const float* w6 = (const float*)d_in[6];
    const float* kv0 = (const float*)d_in[7];
    const float* kh0 = (const float*)d_in[8];
    const float* m0 = (const float*)d_in[9];
    const float* kv1 = (const float*)d_in[10];
    const float* kh1 = (const float*)d_in[11];
    const float* m1 = (const float*)d_in[12];
    const float* kv2 = (const float*)d_in[13];
    const float* kh2 = (const float*)d_in[14];
    const float* m2 = (const float*)d_in[15];
    const float* kv3 = (const float*)d_in[16];
    const float* kh3 = (const float*)d_in[17];
    const float* m3 = (const float*)d_in[18];

    float* out = (float*)d_out;
    float* OUT0 = out;
    float* F8 = out + 1572864;
    float* F16 = out + 2097152;
    float* F32 = out + 18874368;

    const size_t MiB = 1 << 20;
    char* wsb = (char*)d_ws;
    short* WT = (short*)wsb;                  // [0,4)
    short* pin1 = (short*)(wsb + 4 * MiB);    // [4,5.2)
    short* t16b = (short*)(wsb + 6 * MiB);    // [6,39.6)
    short* pin2 = (short*)(wsb + 40 * MiB);   // [40,78)
    short* pin3 = (short*)(wsb + 80 * MiB);   // [80,97.8)
    short* t32bb = (short*)(wsb + 6 * MiB);   // [6,39.6)  (t16b dead)
    short* pin4 = (short*)(wsb + 40 * MiB);   // [40,75.7) (pin2 dead)
    short* pin5 = (short*)(wsb + 80 * MiB);   // [80,114.6)(pin3 dead)
    short* pin6 = (short*)(wsb + 6 * MiB);    // [6,75.2)  (t32bb,pin4 dead)
    short* toutb = (short*)(wsb + 76 * MiB);  // [76,79.2)

    short* wt1 = WT;                    // 9*512*64
    short* wt2 = wt1 + 294912;          // 9*256*512
    short* wt3 = wt2 + 1179648;         // 9*128*256
    short* wt4 = wt3 + 294912;          // 9*128*128
    short* wt5 = wt4 + 147456;          // 9*64*128
    short* wt6 = wt5 + 73728;           // 9*16*64

    // merged weight transform: 1 launch
    {
        WtAll d;
        d.w[0] = w1; d.wt[0] = wt1; d.Cin[0] = 64;  d.Cout[0] = 512; d.Mp[0] = 512; d.stride[0] = 2;
        d.w[1] = w2; d.wt[1] = wt2; d.Cin[1] = 512; d.Cout[1] = 256; d.Mp[1] = 256; d.stride[1] = 1;
        d.w[2] = w3; d.wt[2] = wt3; d.Cin[2] = 256; d.Cout[2] = 128; d.Mp[2] = 128; d.stride[2] = 2;
        d.w[3] = w4; d.wt[3] = wt4; d.Cin[3] = 128; d.Cout[3] = 128; d.Mp[3] = 128; d.stride[3] = 1;
        d.w[4] = w5; d.wt[4] = wt5; d.Cin[4] = 128; d.Cout[4] = 64;  d.Mp[4] = 64;  d.stride[4] = 2;
        d.w[5] = w6; d.wt[5] = wt6; d.Cin[5] = 64;  d.Cout[5] = 3;   d.Mp[5] = 16;  d.stride[5] = 1;
        int maxtotal = 0;
        for (int k = 0; k < 6; ++k) {
            d.total[k] = 9 * d.Mp[k] * d.Cin[k];
            if (d.total[k] > maxtotal) maxtotal = d.total[k];
        }
        dim3 g(CDIV(maxtotal, 256), 6);
        wtrans_all_kernel<<<g, 256, 0, stream>>>(d);
    }

    auto zb = [&](short* buf, int Hp, int Wp, int C8, int mode) {
        int ncell = mode ? (2 * Wp + 2 * (Hp - 2)) : (Wp + Hp - 1);
        int total = 32 * ncell * C8;
        zb2_kernel<<<CDIV(total, 256), 256, 0, stream>>>(buf, Hp, Wp, C8, mode, ncell,
                                                         total);
    };
    auto pad = [&](const float* src, short* pin, int C, int H, int W, int Hp, int Wp,
                   int po) {
        int C8 = C >> 3;
        int xt = (C8 >= 16) ? 16 : 32;
        int ct = 256 / xt;
        int nxt = CDIV(Wp, xt);
        dim3 g(nxt * (C8 / ct < 1 ? 1 : C8 / ct), Hp, 32);
        pad_kernel<<<g, 256, 0, stream>>>(src, pin, C, H, W, Hp, Wp, po, xt, nxt);
    };

    // 1. f8 = fusion(cont) -> F8 ; pad1: F8 -> pin1 (17x17x64, po=0)
    {
        int total = 32 * 16 * 16 * (16 >> 2);
        fusionC_kernel<0><<<CDIV(total, 256), 256, 0, stream>>>(cont, kv0, kh0, m0, F8,
                                                                32, 64, 16, 16, total);
    }
    pad(F8, pin1, 64, 16, 16, 17, 17, 0);

    // 2. conv1 (s2): pin1 -> t16b bf16 NCHW [32,512,32,32]
    {
        dim3 g(32 * 16 * 16 / 128, 512 / 128, 4);
        convt_mfma<128, 128, true, 2, 0, false><<<g, 256, 0, stream>>>(
            pin1, wt1, nullptr, t16b, 17, 17, 64, 512, 512, 32, 32, 16, 16, 0, 0, 0);
    }
    // 3. f16 = fusionL(t16b) -> F16 + pin2 (34x34x512 NHWC interior; zb2 borders)
    zb(pin2, 34, 34, 64, 1);
    {
        dim3 g(512 / 32, 32, 32);
        fusionL_kernel<32, 32, 256, true><<<g, 256, 0, stream>>>(
            t16b, kv1, kh1, m1, F16, pin2, 512, 32, 34, 34);
    }
    // 4. conv2 (s1): pin2 -> pin3 (33x33x256 NHWC). DBUF: grid=512=2/CU.
    zb(pin3, 33, 33, 32, 0);
    {
        dim3 g(32 * 32 * 32 / 128, 256 / 128, 1);
        convt_mfma<128, 128, false, 1, 0, true><<<g, 256, 0, stream>>>(
            pin2, wt2, nullptr, pin3, 34, 34, 512, 256, 256, 32, 32, 32, 32, 33, 33, 0);
    }
    // 5. conv3 (s2): pin3 -> t32bb bf16 NCHW [32,128,64,64]
    {
        dim3 g(32 * 32 * 32 / 128, 1, 4);
        convt_mfma<128, 128, true, 2, 0, false><<<g, 256, 0, stream>>>(
            pin3, wt3, nullptr, t32bb, 33, 33, 256, 128, 128, 64, 64, 32, 32, 0, 0, 0);
    }
    // 6. f32 = fusionL(t32bb) -> F32 + pin4 (66x66x128 NHWC interior; zb2 borders)
    zb(pin4, 66, 66, 16, 1);
    {
        dim3 g(128 / 32, 64, 32);
        fusionL_kernel<64, 32, 512, true><<<g, 512, 0, stream>>>(
            t32bb, kv2, kh2, m2, F32, pin4, 128, 64, 66, 66);
    }
    // 7. conv4 (s1): pin4 -> pin5 (65x65x128 NHWC)
    zb(pin5, 65, 65, 16, 0);
    {
        dim3 g(32 * 64 * 64 / 128, 1, 1);
        convt_mfma<128, 128, false, 1, 0, false><<<g, 256, 0, stream>>>(
            pin4, wt4, nullptr, pin5, 66, 66, 128, 128, 128, 64, 64, 64, 64, 65, 65, 0);
    }
    // 8. conv5 (s2): pin5 -> pin6 (130x130x64 NHWC, poff=1)
    zb(pin6, 130, 130, 8, 1);
    {
        dim3 g(32 * 64 * 64 / 128, 1, 4);
        convt_mfma<64, 128, true, 1, 0, false><<<g, 256, 0, stream>>>(
            pin5, wt5, nullptr, pin6, 65, 65, 128, 64, 64, 128, 128, 64, 64, 130, 130, 1);
    }
    // 9. conv6 (s1): pin6 -> toutb bf16 NCHW [32,3,128,128] tanh
    {
        dim3 g(32 * 128 * 128 / 64, 1, 1);
        convt_mfma<16, 64, false, 2, 1, false><<<g, 256, 0, stream>>>(
            pin6, wt6, nullptr, toutb, 130, 130, 64, 16, 3, 128, 128, 128, 128, 0, 0, 0);
    }
    // 10. out = fusion(toutb) -> OUT0 (C=3, bf16 input)
    {
        int total = 32 * 3 * 128 * (128 >> 2);
        fusion4b_kernel<<<CDIV(total, 256), 256, 0, stream>>>(toutb, kv3, kh3, m3, OUT0,
                                                              32, 3, 128, 128, total);
    }
}

// Round 14
// 462.403 us; speedup vs baseline: 1.7281x; 1.0412x over previous
//
#include <hip/hip_runtime.h>
#include <hip/hip_bf16.h>
#include <cmath>

#define CDIV(a, b) (((a) + (b) - 1) / (b))

typedef __attribute__((ext_vector_type(8))) short bf16x8;
typedef __attribute__((ext_vector_type(4))) short s16x4;
typedef __attribute__((ext_vector_type(4))) float f32x4;
typedef __attribute__((ext_vector_type(2))) float f32x2;

__device__ __forceinline__ short f2bf(float f) {
    unsigned u = __float_as_uint(f);
    unsigned r = (u + 0x7fff + ((u >> 16) & 1)) >> 16;
    return (short)r;
}
__device__ __forceinline__ float bf2f(short s) {
    return __uint_as_float(((unsigned)(unsigned short)s) << 16);
}

__device__ __forceinline__ void gll16(const void* g, void* l) {
    __builtin_amdgcn_global_load_lds((const __attribute__((address_space(1))) void*)g,
                                     (__attribute__((address_space(3))) void*)l, 16, 0, 0);
}

// ---------------------------------------------------------------------------
// LDS-staged fusion (round-12 verified). bf16 NCHW in, fp32 NCHW out,
// optional bf16 NHWC pin out (line-complete, interior; borders via zb2).
// ---------------------------------------------------------------------------
template <int W, int CB, int THREADS, bool PIN>
__global__ void fusionL_kernel(const short* __restrict__ feat,
                               const float* __restrict__ kv,
                               const float* __restrict__ kh,
                               const float* __restrict__ m,
                               float* __restrict__ out, short* __restrict__ pin,
                               int C, int H, int Hp, int Wp) {
    constexpr int ROWF = W + 4;
    constexpr int W8 = W / 8;
    constexpr int XG = W / 4;
    __shared__ float L[CB * 5 * ROWF];
    __shared__ short Lout[PIN ? CB * W : 1];

    int tid = threadIdx.x;
    int cblk = blockIdx.x, y = blockIdx.y, b = blockIdx.z;
    int c0 = cblk * CB;
    int HW = H * W;

    int ry[5];
#pragma unroll
    for (int i = 0; i < 5; ++i) {
        int t = y + i - 2;
        ry[i] = t < 0 ? 0 : (t >= H ? H - 1 : t);
    }

    for (int s = tid; s < CB * 5 * W8; s += THREADS) {
        int c = s / (5 * W8);
        int rr = (s / W8) % 5;
        int xc = s % W8;
        const short* src = feat + ((size_t)(b * C + c0 + c) * H + ry[rr]) * W + xc * 8;
        bf16x8 v = *(const bf16x8*)src;
        float* dst = L + (c * 5 + rr) * ROWF + 2 + xc * 8;
#pragma unroll
        for (int k = 0; k < 8; k += 2) {
            f32x2 t2 = {bf2f(v[k]), bf2f(v[k + 1])};
            *(f32x2*)(dst + k) = t2;
        }
    }
    if (tid < CB * 5) {
        int c = tid / 5, rr = tid % 5;
        const short* srow = feat + ((size_t)(b * C + c0 + c) * H + ry[rr]) * W;
        float v0 = bf2f(srow[0]), v1 = bf2f(srow[W - 1]);
        float* base = L + (c * 5 + rr) * ROWF;
        base[0] = v0; base[1] = v0;
        base[W + 2] = v1; base[W + 3] = v1;
    }
    __syncthreads();

    int xg = tid % XG;
    int c = tid / XG;
    int x0 = xg * 4;

    const float* kvb = kv + ((size_t)b * 5 * H + y) * W + x0;
    const float* khb = kh + ((size_t)b * 5 * H + y) * W + x0;
    f32x4 kvv[5], khv[5];
#pragma unroll
    for (int i = 0; i < 5; ++i) {
        kvv[i] = *(const f32x4*)(kvb + (size_t)i * HW);
        khv[i] = *(const f32x4*)(khb + (size_t)i * HW);
    }
    f32x4 m4 = *(const f32x4*)(m + ((size_t)b * H + y) * W + x0);

    f32x4 acc = (f32x4){0.f, 0.f, 0.f, 0.f};
    f32x4 ctr;
    const float* Lc = L + c * 5 * ROWF + x0;
#pragma unroll
    for (int i = 0; i < 5; ++i) {
        f32x4 wa = *(const f32x4*)(Lc + i * ROWF);
        f32x4 wb = *(const f32x4*)(Lc + i * ROWF + 4);
        float w8[8] = {wa[0], wa[1], wa[2], wa[3], wb[0], wb[1], wb[2], wb[3]};
        if (i == 2) { ctr[0] = w8[2]; ctr[1] = w8[3]; ctr[2] = w8[4]; ctr[3] = w8[5]; }
#pragma unroll
        for (int o = 0; o < 4; ++o) {
            float r = 0.f;
#pragma unroll
            for (int j = 0; j < 5; ++j) r = fmaf(khv[j][o], w8[o + j], r);
            acc[o] = fmaf(kvv[i][o], r, acc[o]);
        }
    }
    f32x4 o4;
#pragma unroll
    for (int o = 0; o < 4; ++o) o4[o] = m4[o] * acc[o] + (1.f - m4[o]) * ctr[o];
    *(f32x4*)(out + (size_t)(b * C + c0 + c) * HW + (size_t)y * W + x0) = o4;

    if (PIN) {
#pragma unroll
        for (int o = 0; o < 4; ++o) Lout[(x0 + o) * CB + c] = f2bf(o4[o]);
        __syncthreads();
        constexpr int CK = CB / 8;
        for (int s = tid; s < W * CK; s += THREADS) {
            int xp = s / CK, ck = s % CK;
            bf16x8 v = *(const bf16x8*)(Lout + xp * CB + ck * 8);
            *(bf16x8*)(pin + (((size_t)b * Hp + y + 1) * Wp + xp + 1) * C + c0 + ck * 8) = v;
        }
    }
}

// ---------------------------------------------------------------------------
// C-blocked fusion (round-6 proven): 4 channels x 4 pixels, fp32 input.
// ---------------------------------------------------------------------------
template <int TIN>
__global__ void fusionC_kernel(const void* __restrict__ featv,
                               const float* __restrict__ kv,
                               const float* __restrict__ kh,
                               const float* __restrict__ m,
                               float* __restrict__ out,
                               int B, int C, int H, int W, int total) {
    int idx = blockIdx.x * blockDim.x + threadIdx.x;
    if (idx >= total) return;
    int Wg = W >> 2;
    int C4 = C >> 2;
    int g = idx % Wg;
    int cg = (idx / Wg) % C4;
    int y = (idx / (Wg * C4)) % H;
    int b = idx / (Wg * C4 * H);
    int x0 = g << 2, c0 = cg << 2;
    int HW = H * W;

    int yy[5];
#pragma unroll
    for (int i = 0; i < 5; ++i) {
        int t = y + i - 2;
        yy[i] = t < 0 ? 0 : (t >= H ? H - 1 : t);
    }
    const float* kvb = kv + ((size_t)b * 5 * H + y) * W + x0;
    const float* khb = kh + ((size_t)b * 5 * H + y) * W + x0;
    f32x4 kvv[5], khv[5];
#pragma unroll
    for (int i = 0; i < 5; ++i) {
        kvv[i] = *(const f32x4*)(kvb + (size_t)i * HW);
        khv[i] = *(const f32x4*)(khb + (size_t)i * HW);
    }
    f32x4 m4 = *(const f32x4*)(m + ((size_t)b * H + y) * W + x0);
    bool interior = (g >= 1 && g <= Wg - 2);

#pragma unroll
    for (int cc = 0; cc < 4; ++cc) {
        size_t plane = (size_t)(b * C + c0 + cc) * HW;
        const float* fpf = (const float*)featv + plane;
        const short* fpb = (const short*)featv + plane;
        f32x4 acc = (f32x4){0.f, 0.f, 0.f, 0.f};
        f32x4 ctr;
        if (interior) {
#pragma unroll
            for (int i = 0; i < 5; ++i) {
                float w8[8];
                if (TIN == 0) {
                    const float* row = fpf + (size_t)yy[i] * W + x0;
                    f32x4 Lv = *(const f32x4*)(row - 4);
                    f32x4 Cv = *(const f32x4*)(row);
                    f32x4 Rv = *(const f32x4*)(row + 4);
                    w8[0] = Lv[2]; w8[1] = Lv[3];
                    w8[2] = Cv[0]; w8[3] = Cv[1]; w8[4] = Cv[2]; w8[5] = Cv[3];
                    w8[6] = Rv[0]; w8[7] = Rv[1];
                    if (i == 2) ctr = Cv;
                } else {
                    const short* row = fpb + (size_t)yy[i] * W + x0;
                    s16x4 Lv = *(const s16x4*)(row - 4);
                    s16x4 Cv = *(const s16x4*)(row);
                    s16x4 Rv = *(const s16x4*)(row + 4);
                    w8[0] = bf2f(Lv[2]); w8[1] = bf2f(Lv[3]);
                    w8[2] = bf2f(Cv[0]); w8[3] = bf2f(Cv[1]);
                    w8[4] = bf2f(Cv[2]); w8[5] = bf2f(Cv[3]);
                    w8[6] = bf2f(Rv[0]); w8[7] = bf2f(Rv[1]);
                    if (i == 2) {
                        ctr[0] = w8[2]; ctr[1] = w8[3]; ctr[2] = w8[4]; ctr[3] = w8[5];
                    }
                }
#pragma unroll
                for (int o = 0; o < 4; ++o) {
                    float r = 0.f;
#pragma unroll
                    for (int j = 0; j < 5; ++j) r = fmaf(khv[j][o], w8[o + j], r);
                    acc[o] = fmaf(kvv[i][o], r, acc[o]);
                }
            }
        } else {
#pragma unroll
            for (int o = 0; o < 4; ++o) {
                int x = x0 + o;
                int xx[5];
#pragma unroll
                for (int j = 0; j < 5; ++j) {
                    int u = x + j - 2;
                    xx[j] = u < 0 ? 0 : (u >= W ? W - 1 : u);
                }
                float a = 0.f;
#pragma unroll
                for (int i = 0; i < 5; ++i) {
                    float r = 0.f;
#pragma unroll
                    for (int j = 0; j < 5; ++j) {
                        float fv = (TIN == 0) ? fpf[(size_t)yy[i] * W + xx[j]]
                                              : bf2f(fpb[(size_t)yy[i] * W + xx[j]]);
                        r = fmaf(khv[j][o], fv, r);
                    }
                    a = fmaf(kvv[i][o], r, a);
                }
                acc[o] = a;
                ctr[o] = (TIN == 0) ? fpf[(size_t)y * W + x] : bf2f(fpb[(size_t)y * W + x]);
            }
        }
        f32x4 o4;
#pragma unroll
        for (int o = 0; o < 4; ++o) o4[o] = m4[o] * acc[o] + (1.f - m4[o]) * ctr[o];
        *(f32x4*)(out + plane + (size_t)y * W + x0) = o4;
    }
}

// scalar-C fusion for C=3 final output, bf16 input (round-6 proven)
__global__ void fusion4b_kernel(const short* __restrict__ feat,
                                const float* __restrict__ kv,
                                const float* __restrict__ kh,
                                const float* __restrict__ m,
                                float* __restrict__ out,
                                int B, int C, int H, int W, int total) {
    int idx = blockIdx.x * blockDim.x + threadIdx.x;
    if (idx >= total) return;
    int Wg = W >> 2;
    int g = idx % Wg;
    int y = (idx / Wg) % H;
    int c = (idx / (Wg * H)) % C;
    int b = idx / (Wg * H * C);
    int x0 = g << 2;
    int HW = H * W;

    const short* fp = feat + (size_t)(b * C + c) * HW;
    int yy[5];
#pragma unroll
    for (int i = 0; i < 5; ++i) {
        int t = y + i - 2;
        yy[i] = t < 0 ? 0 : (t >= H ? H - 1 : t);
    }
    const float* kvb = kv + ((size_t)b * 5 * H + y) * W + x0;
    const float* khb = kh + ((size_t)b * 5 * H + y) * W + x0;

    f32x4 res, c4;
    if (g >= 1 && g <= Wg - 2) {
        f32x4 kvv[5], khv[5];
#pragma unroll
        for (int i = 0; i < 5; ++i) {
            kvv[i] = *(const f32x4*)(kvb + (size_t)i * HW);
            khv[i] = *(const f32x4*)(khb + (size_t)i * HW);
        }
        f32x4 acc = (f32x4){0.f, 0.f, 0.f, 0.f};
#pragma unroll
        for (int i = 0; i < 5; ++i) {
            const short* row = fp + (size_t)yy[i] * W + x0;
            s16x4 Lv = *(const s16x4*)(row - 4);
            s16x4 Cv = *(const s16x4*)(row);
            s16x4 Rv = *(const s16x4*)(row + 4);
            float w8[8] = {bf2f(Lv[2]), bf2f(Lv[3]), bf2f(Cv[0]), bf2f(Cv[1]),
                           bf2f(Cv[2]), bf2f(Cv[3]), bf2f(Rv[0]), bf2f(Rv[1])};
            if (i == 2) { c4[0] = w8[2]; c4[1] = w8[3]; c4[2] = w8[4]; c4[3] = w8[5]; }
#pragma unroll
            for (int o = 0; o < 4; ++o) {
                float r = 0.f;
#pragma unroll
                for (int j = 0; j < 5; ++j) r = fmaf(khv[j][o], w8[o + j], r);
                acc[o] = fmaf(kvv[i][o], r, acc[o]);
            }
        }
        res = acc;
    } else {
#pragma unroll
        for (int o = 0; o < 4; ++o) {
            int x = x0 + o;
            int xx[5];
#pragma unroll
            for (int j = 0; j < 5; ++j) {
                int u = x + j - 2;
                xx[j] = u < 0 ? 0 : (u >= W ? W - 1 : u);
            }
            float acc = 0.f;
#pragma unroll
            for (int i = 0; i < 5; ++i) {
                float r = 0.f;
#pragma unroll
                for (int j = 0; j < 5; ++j)
                    r = fmaf(khb[(size_t)j * HW + o], bf2f(fp[(size_t)yy[i] * W + xx[j]]), r);
                acc = fmaf(kvb[(size_t)i * HW + o], r, acc);
            }
            res[o] = acc;
            c4[o] = bf2f(fp[(size_t)y * W + x]);
        }
    }
    f32x4 m4 = *(const f32x4*)(m + ((size_t)b * H + y) * W + x0);
    f32x4 o4;
#pragma unroll
    for (int o = 0; o < 4; ++o) o4[o] = m4[o] * res[o] + (1.f - m4[o]) * c4[o];
    *(f32x4*)(out + ((size_t)(b * C + c) * H + y) * W + x0) = o4;
}

// ---------------------------------------------------------------------------
// Pad v2 (round-6 verified): used only for pin1.
// ---------------------------------------------------------------------------
__global__ void pad_kernel(const float* __restrict__ in, short* __restrict__ pin,
                           int C, int H, int W, int Hp, int Wp, int po,
                           int xt, int nxt) {
    int b = blockIdx.z, yp = blockIdx.y;
    int ct = 256 / xt;
    int xtile = blockIdx.x % nxt;
    int cb = blockIdx.x / nxt;
    int xl = threadIdx.x % xt;
    int cl = threadIdx.x / xt;
    int xp = xtile * xt + xl;
    int c8 = cb * ct + cl;
    if (xp >= Wp) return;

    int y = yp - po, x = xp - po;
    bf16x8 v;
    if (y >= 0 && y < H && x >= 0 && x < W) {
        const float* ip = in + ((size_t)(b * C + c8 * 8) * H + y) * W + x;
        size_t HW = (size_t)H * W;
#pragma unroll
        for (int k = 0; k < 8; ++k) v[k] = f2bf(ip[k * HW]);
    } else {
        v = (bf16x8)0;
    }
    *(bf16x8*)(pin + (((size_t)b * Hp + yp) * Wp + xp) * C + c8 * 8) = v;
}

// ---------------------------------------------------------------------------
// zb2: border-only zero of NHWC bf16 pin (round-13 verified).
// ---------------------------------------------------------------------------
__global__ void zb2_kernel(short* __restrict__ buf, int Hp, int Wp, int C8, int mode,
                           int ncell, int total) {
    int tid = blockIdx.x * blockDim.x + threadIdx.x;
    if (tid >= total) return;
    int c8 = tid % C8;
    int cell = (tid / C8) % ncell;
    int b = tid / (C8 * ncell);
    int yp, xp;
    if (mode) {
        if (cell < Wp) { yp = 0; xp = cell; }
        else if (cell < 2 * Wp) { yp = Hp - 1; xp = cell - Wp; }
        else { int r = cell - 2 * Wp; yp = 1 + (r >> 1); xp = (r & 1) ? (Wp - 1) : 0; }
    } else {
        if (cell < Wp) { yp = Hp - 1; xp = cell; }
        else { yp = cell - Wp; xp = Wp - 1; }
    }
    *(bf16x8*)(buf + (((size_t)b * Hp + yp) * Wp + xp) * (C8 * 8) + c8 * 8) = (bf16x8)0;
}

// ---------------------------------------------------------------------------
// Merged weight transform (round-13 verified).
// ---------------------------------------------------------------------------
struct WtAll {
    const float* w[6];
    short* wt[6];
    int Cin[6], Cout[6], Mp[6], stride[6], total[6];
};

__global__ void wtrans_all_kernel(WtAll d) {
    int wi = blockIdx.y;
    int tid = blockIdx.x * blockDim.x + threadIdx.x;
    if (tid >= d.total[wi]) return;
    int Cin = d.Cin[wi], Cout = d.Cout[wi], Mp = d.Mp[wi], stride = d.stride[wi];
    const float* w = d.w[wi];
    short* wt = d.wt[wi];

    int ci = tid % Cin;
    int mm = (tid / Cin) % Mp;
    int t9 = tid / (Cin * Mp);
    int i, j;
    if (stride == 1) {
        int a = t9 / 3, bb = t9 % 3;
        i = 2 - a; j = 2 - bb;
    } else {
        int py, px, a, bb;
        if (t9 == 0) { py = 0; px = 0; a = 0; bb = 0; }
        else if (t9 < 3) { py = 0; px = 1; a = 0; bb = t9 - 1; }
        else if (t9 < 5) { py = 1; px = 0; a = t9 - 3; bb = 0; }
        else { int tt = t9 - 5; py = 1; px = 1; a = tt >> 1; bb = tt & 1; }
        i = (py == 0) ? 1 : (a == 0 ? 2 : 0);
        j = (px == 0) ? 1 : (bb == 0 ? 2 : 0);
    }
    float v = 0.f;
    if (mm < Cout) v = w[((ci * Cout + mm) * 3 + i) * 3 + j];
    wt[tid] = f2bf(v);
}

#define WAITVM(n) asm volatile("s_waitcnt vmcnt(" #n ")" ::: "memory")

// ---------------------------------------------------------------------------
// Implicit-GEMM convT (round-10/12 verified), BM x BN tile, 4 waves, BK=64,
// XOR-swizzled LDS. cc outer, taps inner. DBUF only for conv2 (2 blocks/CU).
// ---------------------------------------------------------------------------
template <int BM, int BN, bool S2, int OUTM, int ACT, bool DBUF>
__global__ void convt_mfma(const short* __restrict__ pin, const short* __restrict__ wtc,
                           float* __restrict__ outf, short* __restrict__ outb,
                           int Hpin, int Wpin, int Cin, int Mp, int Cout,
                           int Ho, int Wo, int Hu, int Wv,
                           int Hop, int Wop, int poff) {
    constexpr int WAVES_M = (BM >= 128) ? 2 : 1;
    constexpr int WM = BM / WAVES_M;
    constexpr int WN = BN / (4 / WAVES_M);
    constexpr int FM = WM / 16, FN = WN / 16;
    constexpr int RB = BN / 32;
    constexpr int AROUND = BM / 32;
    constexpr int NLOAD = AROUND + RB;
    constexpr int ABYTES = BM * 128;
    constexpr int BBYTES = BN * 128;
    __shared__ __align__(16) short Alds[(DBUF ? 2 : 1) * BM * 64];
    __shared__ __align__(16) short Blds[(DBUF ? 2 : 1) * BN * 64];

    int t = threadIdx.x, lane = t & 63, wid = t >> 6;
    int n0 = blockIdx.x * BN, m0 = blockIdx.y * BM;

    int py = 0, px = 0, ny = 3, nx = 3, dys = 0x210, dxs = 0x210, sy = 1;
    const short* wt = wtc;
    if (S2) {
        int pz = blockIdx.z;
        py = pz >> 1; px = pz & 1;
        ny = 1 + py; nx = 1 + px;
        dys = py ? 0x10 : 0; dxs = px ? 0x10 : 0;
        int pre = (pz == 0) ? 0 : (pz == 1) ? 1 : (pz == 2) ? 3 : 5;
        wt = wtc + (size_t)pre * Mp * Cin;
        sy = 2;
    }

    int rowS = t >> 3;
    int dS = (t & 7) ^ (rowS & 7);
    int HuWv = Hu * Wv;
    int pxg[RB];
#pragma unroll
    for (int rb = 0; rb < RB; ++rb) {
        int n = n0 + rowS + rb * 32;
        int b = n / HuWv, r = n % HuWv;
        int u = r / Wv, v = r % Wv;
        pxg[rb] = ((b * Hpin + u) * Wpin + v) * Cin + dS * 8;
    }
    int aoff = (m0 + rowS) * Cin + dS * 8;

    char* AB = (char*)Alds;
    char* BB = (char*)Blds;

    int wm = (WAVES_M == 2) ? (wid & 1) : 0;
    int wn = (WAVES_M == 2) ? (wid >> 1) : wid;
    int cb = lane >> 4;
    int rm[FM], rn[FN];
#pragma unroll
    for (int mf = 0; mf < FM; ++mf) rm[mf] = wm * WM + mf * 16 + (lane & 15);
#pragma unroll
    for (int nf = 0; nf < FN; ++nf) rn[nf] = wn * WN + nf * 16 + (lane & 15);

    f32x4 acc[FM][FN];
#pragma unroll
    for (int mf = 0; mf < FM; ++mf)
#pragma unroll
        for (int nf = 0; nf < FN; ++nf) acc[mf][nf] = (f32x4){0.f, 0.f, 0.f, 0.f};

    int ntap = ny * nx;
    int NK = (Cin >> 6) * ntap;

    auto COMPUTE = [&](int buf) {
        char* ABb = AB + buf * ABYTES;
        char* BBb = BB + buf * BBYTES;
#pragma unroll
        for (int h = 0; h < 2; ++h) {
            bf16x8 av[FM], bv[FN];
#pragma unroll
            for (int mf = 0; mf < FM; ++mf)
                av[mf] = *(const bf16x8*)(ABb + rm[mf] * 128 +
                                          (((h * 4 + cb) ^ (rm[mf] & 7)) << 4));
#pragma unroll
            for (int nf = 0; nf < FN; ++nf)
                bv[nf] = *(const bf16x8*)(BBb + rn[nf] * 128 +
                                          (((h * 4 + cb) ^ (rn[nf] & 7)) << 4));
#pragma unroll
            for (int mf = 0; mf < FM; ++mf)
#pragma unroll
                for (int nf = 0; nf < FN; ++nf)
                    acc[mf][nf] = __builtin_amdgcn_mfma_f32_16x16x32_bf16(
                        av[mf], bv[nf], acc[mf][nf], 0, 0, 0);
        }
    };

    if constexpr (DBUF) {
        auto STAGE = [&](int ks, int buf) {
            int ccq = ks / ntap;
            int ti = ks - ccq * ntap;
            int cc = ccq << 6;
            int a = ti / nx, bxx = ti - (ti / nx) * nx;
            int dy = (dys >> (4 * a)) & 15, dxv = (dxs >> (4 * bxx)) & 15;
            int tapoff = (dy * Wpin + dxv) * Cin;
            const short* wblk = wt + (size_t)ti * Mp * Cin;
            char* ABb = AB + buf * ABYTES;
            char* BBb = BB + buf * BBYTES;
#pragma unroll
            for (int r = 0; r < AROUND; ++r)
                gll16(wblk + cc + aoff + r * 32 * Cin, ABb + r * 4096 + (wid << 10));
#pragma unroll
            for (int rb = 0; rb < RB; ++rb)
                gll16(pin + tapoff + cc + pxg[rb], BBb + rb * 4096 + (wid << 10));
        };

        STAGE(0, 0);
        for (int ks = 0; ks < NK; ++ks) {
            int cur = ks & 1;
            bool more = (ks + 1 < NK);
            if (more) STAGE(ks + 1, cur ^ 1);
            if (more) {
                static_assert(!DBUF || NLOAD == 8, "vmcnt literal");
                WAITVM(8);
            } else {
                WAITVM(0);
            }
            __builtin_amdgcn_sched_barrier(0);
            __builtin_amdgcn_s_barrier();
            __builtin_amdgcn_sched_barrier(0);
            COMPUTE(cur);
            asm volatile("s_waitcnt lgkmcnt(0)" ::: "memory");
            __builtin_amdgcn_sched_barrier(0);
            __builtin_amdgcn_s_barrier();
        }
    } else {
        for (int ks = 0; ks < NK; ++ks) {
            int ccq = ks / ntap;
            int ti = ks - ccq * ntap;
            int cc = ccq << 6;
            int a = ti / nx, bxx = ti - (ti / nx) * nx;
            int dy = (dys >> (4 * a)) & 15, dxv = (dxs >> (4 * bxx)) & 15;
            int tapoff = (dy * Wpin + dxv) * Cin;
            const short* wblk = wt + (size_t)ti * Mp * Cin;
            __syncthreads();
            if (BM >= 32) {
#pragma unroll
                for (int r = 0; r < AROUND; ++r)
                    gll16(wblk + cc + aoff + r * 32 * Cin, AB + r * 4096 + (wid << 10));
            } else {
                if (wid < BM / 8) gll16(wblk + cc + aoff, AB + (wid << 10));
            }
#pragma unroll
            for (int rb = 0; rb < RB; ++rb)
                gll16(pin + tapoff + cc + pxg[rb], BB + rb * 4096 + (wid << 10));
            __syncthreads();
            COMPUTE(0);
        }
    }

#pragma unroll
    for (int mf = 0; mf < FM; ++mf) {
#pragma unroll
        for (int nf = 0; nf < FN; ++nf) {
            int p = n0 + wn * WN + nf * 16 + (lane & 15);
            int b = p / HuWv, r = p % HuWv;
            int u = r / Wv, v = r % Wv;
            int y = sy * u + py, x = sy * v + px;
            int cobase = m0 + wm * WM + mf * 16 + (lane >> 4) * 4;
            f32x4 vv = acc[mf][nf];
            if (OUTM == 1) {
                s16x4 pk;
#pragma unroll
                for (int reg = 0; reg < 4; ++reg) {
                    float f = vv[reg];
                    f = f > 0.f ? f : 0.f;
                    pk[reg] = f2bf(f);
                }
                *(s16x4*)(outb + (((size_t)b * Hop + y + poff) * Wop + (x + poff)) * Cout +
                          cobase) = pk;
            } else {
#pragma unroll
                for (int reg = 0; reg < 4; ++reg) {
                    int co = cobase + reg;
                    if (co < Cout) {
                        float f = vv[reg];
                        if (ACT == 0) f = f > 0.f ? f : 0.f;
                        else f = tanhf(f);
                        outb[((size_t)(b * Cout + co) * Ho + y) * Wo + x] = f2bf(f);
                    }
                }
            }
        }
    }
}

// ---------------------------------------------------------------------------

extern "C" void kernel_launch(void* const* d_in, const int* in_sizes, int n_in,
                              void* d_out, int out_size, void* d_ws, size_t ws_size,
                              hipStream_t stream) {
    const float* cont = (const float*)d_in[0];
    const float* w1 = (const float*)d_in[1];
    const float* w2 = (const float*)d_in[2];
    const float* w3 = (const float*)d_in[3];
    const float* w4 = (const float*)d_in[4];
    const float* w5 = (const float*)d_in[5];
    const float* w6 = (const float*)d_in[6];
    const float* kv0 = (const float*)d_in[7];
    const float* kh0 = (const float*)d_in[8];
    const float* m0 = (const float*)d_in[9];
    const float* kv1 = (const float*)d_in[10];
    const float* kh1 = (const float*)d_in[11];
    const float* m1 = (const float*)d_in[12];
    const float* kv2 = (const float*)d_in[13];
    const float* kh2 = (const float*)d_in[14];
    const float* m2 = (const float*)d_in[15];
    const float* kv3 = (const float*)d_in[16];
    const float* kh3 = (const float*)d_in[17];
    const float* m3 = (const float*)d_in[18];

    float* out = (float*)d_out;
    float* OUT0 = out;
    float* F8 = out + 1572864;
    float* F16 = out + 2097152;
    float* F32 = out + 18874368;

    const size_t MiB = 1 << 20;
    char* wsb = (char*)d_ws;
    short* WT = (short*)wsb;                  // [0,4)
    short* pin1 = (short*)(wsb + 4 * MiB);    // [4,5.2)
    short* t16b = (short*)(wsb + 6 * MiB);    // [6,39.6)
    short* pin2 = (short*)(wsb + 40 * MiB);   // [40,78)
    short* pin3 = (short*)(wsb + 80 * MiB);   // [80,97.8)
    short* t32bb = (short*)(wsb + 6 * MiB);   // [6,39.6)  (t16b dead)
    short* pin4 = (short*)(wsb + 40 * MiB);   // [40,75.7) (pin2 dead)
    short* pin5 = (short*)(wsb + 80 * MiB);   // [80,114.6)(pin3 dead)
    short* pin6 = (short*)(wsb + 6 * MiB);    // [6,75.2)  (t32bb,pin4 dead)
    short* toutb = (short*)(wsb + 76 * MiB);  // [76,79.2)

    short* wt1 = WT;                    // 9*512*64
    short* wt2 = wt1 + 294912;          // 9*256*512
    short* wt3 = wt2 + 1179648;         // 9*128*256
    short* wt4 = wt3 + 294912;          // 9*128*128
    short* wt5 = wt4 + 147456;          // 9*64*128
    short* wt6 = wt5 + 73728;           // 9*16*64

    // merged weight transform: 1 launch
    {
        WtAll d;
        d.w[0] = w1; d.wt[0] = wt1; d.Cin[0] = 64;  d.Cout[0] = 512; d.Mp[0] = 512; d.stride[0] = 2;
        d.w[1] = w2; d.wt[1] = wt2; d.Cin[1] = 512; d.Cout[1] = 256; d.Mp[1] = 256; d.stride[1] = 1;
        d.w[2] = w3; d.wt[2] = wt3; d.Cin[2] = 256; d.Cout[2] = 128; d.Mp[2] = 128; d.stride[2] = 2;
        d.w[3] = w4; d.wt[3] = wt4; d.Cin[3] = 128; d.Cout[3] = 128; d.Mp[3] = 128; d.stride[3] = 1;
        d.w[4] = w5; d.wt[4] = wt5; d.Cin[4] = 128; d.Cout[4] = 64;  d.Mp[4] = 64;  d.stride[4] = 2;
        d.w[5] = w6; d.wt[5] = wt6; d.Cin[5] = 64;  d.Cout[5] = 3;   d.Mp[5] = 16;  d.stride[5] = 1;
        int maxtotal = 0;
        for (int k = 0; k < 6; ++k) {
            d.total[k] = 9 * d.Mp[k] * d.Cin[k];
            if (d.total[k] > maxtotal) maxtotal = d.total[k];
        }
        dim3 g(CDIV(maxtotal, 256), 6);
        wtrans_all_kernel<<<g, 256, 0, stream>>>(d);
    }

    auto zb = [&](short* buf, int Hp, int Wp, int C8, int mode) {
        int ncell = mode ? (2 * Wp + 2 * (Hp - 2)) : (Wp + Hp - 1);
        int total = 32 * ncell * C8;
        zb2_kernel<<<CDIV(total, 256), 256, 0, stream>>>(buf, Hp, Wp, C8, mode, ncell,
                                                         total);
    };
    auto pad = [&](const float* src, short* pin, int C, int H, int W, int Hp, int Wp,
                   int po) {
        int C8 = C >> 3;
        int xt = (C8 >= 16) ? 16 : 32;
        int ct = 256 / xt;
        int nxt = CDIV(Wp, xt);
        dim3 g(nxt * (C8 / ct < 1 ? 1 : C8 / ct), Hp, 32);
        pad_kernel<<<g, 256, 0, stream>>>(src, pin, C, H, W, Hp, Wp, po, xt, nxt);
    };

    // 1. f8 = fusion(cont) -> F8 ; pad1: F8 -> pin1 (17x17x64, po=0)
    {
        int total = 32 * 16 * 16 * (16 >> 2);
        fusionC_kernel<0><<<CDIV(total, 256), 256, 0, stream>>>(cont, kv0, kh0, m0, F8,
                                                                32, 64, 16, 16, total);
    }
    pad(F8, pin1, 64, 16, 16, 17, 17, 0);

    // 2. conv1 (s2): pin1 -> t16b bf16 NCHW [32,512,32,32]
    {
        dim3 g(32 * 16 * 16 / 128, 512 / 128, 4);
        convt_mfma<128, 128, true, 2, 0, false><<<g, 256, 0, stream>>>(
            pin1, wt1, nullptr, t16b, 17, 17, 64, 512, 512, 32, 32, 16, 16, 0, 0, 0);
    }
    // 3. f16 = fusionL(t16b) -> F16 + pin2 (34x34x512 NHWC interior; zb2 borders)
    zb(pin2, 34, 34, 64, 1);
    {
        dim3 g(512 / 32, 32, 32);
        fusionL_kernel<32, 32, 256, true><<<g, 256, 0, stream>>>(
            t16b, kv1, kh1, m1, F16, pin2, 512, 32, 34, 34);
    }
    // 4. conv2 (s1): pin2 -> pin3 (33x33x256 NHWC). DBUF: grid=512=2/CU.
    zb(pin3, 33, 33, 32, 0);
    {
        dim3 g(32 * 32 * 32 / 128, 256 / 128, 1);
        convt_mfma<128, 128, false, 1, 0, true><<<g, 256, 0, stream>>>(
            pin2, wt2, nullptr, pin3, 34, 34, 512, 256, 256, 32, 32, 32, 32, 33, 33, 0);
    }
    // 5. conv3 (s2): pin3 -> t32bb bf16 NCHW [32,128,64,64]
    {
        dim3 g(32 * 32 * 32 / 128, 1, 4);
        convt_mfma<128, 128, true, 2, 0, false><<<g, 256, 0, stream>>>(
            pin3, wt3, nullptr, t32bb, 33, 33, 256, 128, 128, 64, 64, 32, 32, 0, 0, 0);
    }
    // 6. f32 = fusionL(t32bb) -> F32 + pin4 (66x66x128 NHWC interior; zb2 borders)
    zb(pin4, 66, 66, 16, 1);
    {
        dim3 g(128 / 32, 64, 32);
        fusionL_kernel<64, 32, 512, true><<<g, 512, 0, stream>>>(
            t32bb, kv2, kh2, m2, F32, pin4, 128, 64, 66, 66);
    }
    // 7. conv4 (s1): pin4 -> pin5 (65x65x128 NHWC)
    zb(pin5, 65, 65, 16, 0);
    {
        dim3 g(32 * 64 * 64 / 128, 1, 1);
        convt_mfma<128, 128, false, 1, 0, false><<<g, 256, 0, stream>>>(
            pin4, wt4, nullptr, pin5, 66, 66, 128, 128, 128, 64, 64, 64, 64, 65, 65, 0);
    }
    // 8. conv5 (s2): pin5 -> pin6 (130x130x64 NHWC, poff=1). BN=256: 32 MFMA/step.
    zb(pin6, 130, 130, 8, 1);
    {
        dim3 g(32 * 64 * 64 / 256, 1, 4);
        convt_mfma<64, 256, true, 1, 0, false><<<g, 256, 0, stream>>>(
            pin5, wt5, nullptr, pin6, 65, 65, 128, 64, 64, 128, 128, 64, 64, 130, 130, 1);
    }
    // 9. conv6 (s1): pin6 -> toutb bf16 NCHW [32,3,128,128] tanh. BN=256: 8 MFMA/step.
    {
        dim3 g(32 * 128 * 128 / 256, 1, 1);
        convt_mfma<16, 256, false, 2, 1, false><<<g, 256, 0, stream>>>(
            pin6, wt6, nullptr, toutb, 130, 130, 64, 16, 3, 128, 128, 128, 128, 0, 0, 0);
    }
    // 10. out = fusion(toutb) -> OUT0 (C=3, bf16 input)
    {
        int total = 32 * 3 * 128 * (128 >> 2);
        fusion4b_kernel<<<CDIV(total, 256), 256, 0, stream>>>(toutb, kv3, kh3, m3, OUT0,
                                                              32, 3, 128, 128, total);
    }
}

// Round 15
// 457.412 us; speedup vs baseline: 1.7470x; 1.0109x over previous
//
#include <hip/hip_runtime.h>
#include <hip/hip_bf16.h>
#include <cmath>

#define CDIV(a, b) (((a) + (b) - 1) / (b))

typedef __attribute__((ext_vector_type(8))) short bf16x8;
typedef __attribute__((ext_vector_type(4))) short s16x4;
typedef __attribute__((ext_vector_type(4))) float f32x4;
typedef __attribute__((ext_vector_type(2))) float f32x2;

__device__ __forceinline__ short f2bf(float f) {
    unsigned u = __float_as_uint(f);
    unsigned r = (u + 0x7fff + ((u >> 16) & 1)) >> 16;
    return (short)r;
}
__device__ __forceinline__ float bf2f(short s) {
    return __uint_as_float(((unsigned)(unsigned short)s) << 16);
}

__device__ __forceinline__ void gll16(const void* g, void* l) {
    __builtin_amdgcn_global_load_lds((const __attribute__((address_space(1))) void*)g,
                                     (__attribute__((address_space(3))) void*)l, 16, 0, 0);
}

// ---------------------------------------------------------------------------
// LDS-staged fusion (round-12 verified). bf16 NCHW in, fp32 NCHW out,
// optional bf16 NHWC pin out (line-complete, interior; borders via zb2).
// ---------------------------------------------------------------------------
template <int W, int CB, int THREADS, bool PIN>
__global__ void fusionL_kernel(const short* __restrict__ feat,
                               const float* __restrict__ kv,
                               const float* __restrict__ kh,
                               const float* __restrict__ m,
                               float* __restrict__ out, short* __restrict__ pin,
                               int C, int H, int Hp, int Wp) {
    constexpr int ROWF = W + 4;
    constexpr int W8 = W / 8;
    constexpr int XG = W / 4;
    __shared__ float L[CB * 5 * ROWF];
    __shared__ short Lout[PIN ? CB * W : 1];

    int tid = threadIdx.x;
    int cblk = blockIdx.x, y = blockIdx.y, b = blockIdx.z;
    int c0 = cblk * CB;
    int HW = H * W;

    int ry[5];
#pragma unroll
    for (int i = 0; i < 5; ++i) {
        int t = y + i - 2;
        ry[i] = t < 0 ? 0 : (t >= H ? H - 1 : t);
    }

    for (int s = tid; s < CB * 5 * W8; s += THREADS) {
        int c = s / (5 * W8);
        int rr = (s / W8) % 5;
        int xc = s % W8;
        const short* src = feat + ((size_t)(b * C + c0 + c) * H + ry[rr]) * W + xc * 8;
        bf16x8 v = *(const bf16x8*)src;
        float* dst = L + (c * 5 + rr) * ROWF + 2 + xc * 8;
#pragma unroll
        for (int k = 0; k < 8; k += 2) {
            f32x2 t2 = {bf2f(v[k]), bf2f(v[k + 1])};
            *(f32x2*)(dst + k) = t2;
        }
    }
    if (tid < CB * 5) {
        int c = tid / 5, rr = tid % 5;
        const short* srow = feat + ((size_t)(b * C + c0 + c) * H + ry[rr]) * W;
        float v0 = bf2f(srow[0]), v1 = bf2f(srow[W - 1]);
        float* base = L + (c * 5 + rr) * ROWF;
        base[0] = v0; base[1] = v0;
        base[W + 2] = v1; base[W + 3] = v1;
    }
    __syncthreads();

    int xg = tid % XG;
    int c = tid / XG;
    int x0 = xg * 4;

    const float* kvb = kv + ((size_t)b * 5 * H + y) * W + x0;
    const float* khb = kh + ((size_t)b * 5 * H + y) * W + x0;
    f32x4 kvv[5], khv[5];
#pragma unroll
    for (int i = 0; i < 5; ++i) {
        kvv[i] = *(const f32x4*)(kvb + (size_t)i * HW);
        khv[i] = *(const f32x4*)(khb + (size_t)i * HW);
    }
    f32x4 m4 = *(const f32x4*)(m + ((size_t)b * H + y) * W + x0);

    f32x4 acc = (f32x4){0.f, 0.f, 0.f, 0.f};
    f32x4 ctr;
    const float* Lc = L + c * 5 * ROWF + x0;
#pragma unroll
    for (int i = 0; i < 5; ++i) {
        f32x4 wa = *(const f32x4*)(Lc + i * ROWF);
        f32x4 wb = *(const f32x4*)(Lc + i * ROWF + 4);
        float w8[8] = {wa[0], wa[1], wa[2], wa[3], wb[0], wb[1], wb[2], wb[3]};
        if (i == 2) { ctr[0] = w8[2]; ctr[1] = w8[3]; ctr[2] = w8[4]; ctr[3] = w8[5]; }
#pragma unroll
        for (int o = 0; o < 4; ++o) {
            float r = 0.f;
#pragma unroll
            for (int j = 0; j < 5; ++j) r = fmaf(khv[j][o], w8[o + j], r);
            acc[o] = fmaf(kvv[i][o], r, acc[o]);
        }
    }
    f32x4 o4;
#pragma unroll
    for (int o = 0; o < 4; ++o) o4[o] = m4[o] * acc[o] + (1.f - m4[o]) * ctr[o];
    *(f32x4*)(out + (size_t)(b * C + c0 + c) * HW + (size_t)y * W + x0) = o4;

    if (PIN) {
#pragma unroll
        for (int o = 0; o < 4; ++o) Lout[(x0 + o) * CB + c] = f2bf(o4[o]);
        __syncthreads();
        constexpr int CK = CB / 8;
        for (int s = tid; s < W * CK; s += THREADS) {
            int xp = s / CK, ck = s % CK;
            bf16x8 v = *(const bf16x8*)(Lout + xp * CB + ck * 8);
            *(bf16x8*)(pin + (((size_t)b * Hp + y + 1) * Wp + xp + 1) * C + c0 + ck * 8) = v;
        }
    }
}

// ---------------------------------------------------------------------------
// C-blocked fusion (round-6 proven): 4 channels x 4 pixels, fp32 input.
// ---------------------------------------------------------------------------
template <int TIN>
__global__ void fusionC_kernel(const void* __restrict__ featv,
                               const float* __restrict__ kv,
                               const float* __restrict__ kh,
                               const float* __restrict__ m,
                               float* __restrict__ out,
                               int B, int C, int H, int W, int total) {
    int idx = blockIdx.x * blockDim.x + threadIdx.x;
    if (idx >= total) return;
    int Wg = W >> 2;
    int C4 = C >> 2;
    int g = idx % Wg;
    int cg = (idx / Wg) % C4;
    int y = (idx / (Wg * C4)) % H;
    int b = idx / (Wg * C4 * H);
    int x0 = g << 2, c0 = cg << 2;
    int HW = H * W;

    int yy[5];
#pragma unroll
    for (int i = 0; i < 5; ++i) {
        int t = y + i - 2;
        yy[i] = t < 0 ? 0 : (t >= H ? H - 1 : t);
    }
    const float* kvb = kv + ((size_t)b * 5 * H + y) * W + x0;
    const float* khb = kh + ((size_t)b * 5 * H + y) * W + x0;
    f32x4 kvv[5], khv[5];
#pragma unroll
    for (int i = 0; i < 5; ++i) {
        kvv[i] = *(const f32x4*)(kvb + (size_t)i * HW);
        khv[i] = *(const f32x4*)(khb + (size_t)i * HW);
    }
    f32x4 m4 = *(const f32x4*)(m + ((size_t)b * H + y) * W + x0);
    bool interior = (g >= 1 && g <= Wg - 2);

#pragma unroll
    for (int cc = 0; cc < 4; ++cc) {
        size_t plane = (size_t)(b * C + c0 + cc) * HW;
        const float* fpf = (const float*)featv + plane;
        const short* fpb = (const short*)featv + plane;
        f32x4 acc = (f32x4){0.f, 0.f, 0.f, 0.f};
        f32x4 ctr;
        if (interior) {
#pragma unroll
            for (int i = 0; i < 5; ++i) {
                float w8[8];
                if (TIN == 0) {
                    const float* row = fpf + (size_t)yy[i] * W + x0;
                    f32x4 Lv = *(const f32x4*)(row - 4);
                    f32x4 Cv = *(const f32x4*)(row);
                    f32x4 Rv = *(const f32x4*)(row + 4);
                    w8[0] = Lv[2]; w8[1] = Lv[3];
                    w8[2] = Cv[0]; w8[3] = Cv[1]; w8[4] = Cv[2]; w8[5] = Cv[3];
                    w8[6] = Rv[0]; w8[7] = Rv[1];
                    if (i == 2) ctr = Cv;
                } else {
                    const short* row = fpb + (size_t)yy[i] * W + x0;
                    s16x4 Lv = *(const s16x4*)(row - 4);
                    s16x4 Cv = *(const s16x4*)(row);
                    s16x4 Rv = *(const s16x4*)(row + 4);
                    w8[0] = bf2f(Lv[2]); w8[1] = bf2f(Lv[3]);
                    w8[2] = bf2f(Cv[0]); w8[3] = bf2f(Cv[1]);
                    w8[4] = bf2f(Cv[2]); w8[5] = bf2f(Cv[3]);
                    w8[6] = bf2f(Rv[0]); w8[7] = bf2f(Rv[1]);
                    if (i == 2) {
                        ctr[0] = w8[2]; ctr[1] = w8[3]; ctr[2] = w8[4]; ctr[3] = w8[5];
                    }
                }
#pragma unroll
                for (int o = 0; o < 4; ++o) {
                    float r = 0.f;
#pragma unroll
                    for (int j = 0; j < 5; ++j) r = fmaf(khv[j][o], w8[o + j], r);
                    acc[o] = fmaf(kvv[i][o], r, acc[o]);
                }
            }
        } else {
#pragma unroll
            for (int o = 0; o < 4; ++o) {
                int x = x0 + o;
                int xx[5];
#pragma unroll
                for (int j = 0; j < 5; ++j) {
                    int u = x + j - 2;
                    xx[j] = u < 0 ? 0 : (u >= W ? W - 1 : u);
                }
                float a = 0.f;
#pragma unroll
                for (int i = 0; i < 5; ++i) {
                    float r = 0.f;
#pragma unroll
                    for (int j = 0; j < 5; ++j) {
                        float fv = (TIN == 0) ? fpf[(size_t)yy[i] * W + xx[j]]
                                              : bf2f(fpb[(size_t)yy[i] * W + xx[j]]);
                        r = fmaf(khv[j][o], fv, r);
                    }
                    a = fmaf(kvv[i][o], r, a);
                }
                acc[o] = a;
                ctr[o] = (TIN == 0) ? fpf[(size_t)y * W + x] : bf2f(fpb[(size_t)y * W + x]);
            }
        }
        f32x4 o4;
#pragma unroll
        for (int o = 0; o < 4; ++o) o4[o] = m4[o] * acc[o] + (1.f - m4[o]) * ctr[o];
        *(f32x4*)(out + plane + (size_t)y * W + x0) = o4;
    }
}

// scalar-C fusion for C=3 final output, bf16 input (round-6 proven)
__global__ void fusion4b_kernel(const short* __restrict__ feat,
                                const float* __restrict__ kv,
                                const float* __restrict__ kh,
                                const float* __restrict__ m,
                                float* __restrict__ out,
                                int B, int C, int H, int W, int total) {
    int idx = blockIdx.x * blockDim.x + threadIdx.x;
    if (idx >= total) return;
    int Wg = W >> 2;
    int g = idx % Wg;
    int y = (idx / Wg) % H;
    int c = (idx / (Wg * H)) % C;
    int b = idx / (Wg * H * C);
    int x0 = g << 2;
    int HW = H * W;

    const short* fp = feat + (size_t)(b * C + c) * HW;
    int yy[5];
#pragma unroll
    for (int i = 0; i < 5; ++i) {
        int t = y + i - 2;
        yy[i] = t < 0 ? 0 : (t >= H ? H - 1 : t);
    }
    const float* kvb = kv + ((size_t)b * 5 * H + y) * W + x0;
    const float* khb = kh + ((size_t)b * 5 * H + y) * W + x0;

    f32x4 res, c4;
    if (g >= 1 && g <= Wg - 2) {
        f32x4 kvv[5], khv[5];
#pragma unroll
        for (int i = 0; i < 5; ++i) {
            kvv[i] = *(const f32x4*)(kvb + (size_t)i * HW);
            khv[i] = *(const f32x4*)(khb + (size_t)i * HW);
        }
        f32x4 acc = (f32x4){0.f, 0.f, 0.f, 0.f};
#pragma unroll
        for (int i = 0; i < 5; ++i) {
            const short* row = fp + (size_t)yy[i] * W + x0;
            s16x4 Lv = *(const s16x4*)(row - 4);
            s16x4 Cv = *(const s16x4*)(row);
            s16x4 Rv = *(const s16x4*)(row + 4);
            float w8[8] = {bf2f(Lv[2]), bf2f(Lv[3]), bf2f(Cv[0]), bf2f(Cv[1]),
                           bf2f(Cv[2]), bf2f(Cv[3]), bf2f(Rv[0]), bf2f(Rv[1])};
            if (i == 2) { c4[0] = w8[2]; c4[1] = w8[3]; c4[2] = w8[4]; c4[3] = w8[5]; }
#pragma unroll
            for (int o = 0; o < 4; ++o) {
                float r = 0.f;
#pragma unroll
                for (int j = 0; j < 5; ++j) r = fmaf(khv[j][o], w8[o + j], r);
                acc[o] = fmaf(kvv[i][o], r, acc[o]);
            }
        }
        res = acc;
    } else {
#pragma unroll
        for (int o = 0; o < 4; ++o) {
            int x = x0 + o;
            int xx[5];
#pragma unroll
            for (int j = 0; j < 5; ++j) {
                int u = x + j - 2;
                xx[j] = u < 0 ? 0 : (u >= W ? W - 1 : u);
            }
            float acc = 0.f;
#pragma unroll
            for (int i = 0; i < 5; ++i) {
                float r = 0.f;
#pragma unroll
                for (int j = 0; j < 5; ++j)
                    r = fmaf(khb[(size_t)j * HW + o], bf2f(fp[(size_t)yy[i] * W + xx[j]]), r);
                acc = fmaf(kvb[(size_t)i * HW + o], r, acc);
            }
            res[o] = acc;
            c4[o] = bf2f(fp[(size_t)y * W + x]);
        }
    }
    f32x4 m4 = *(const f32x4*)(m + ((size_t)b * H + y) * W + x0);
    f32x4 o4;
#pragma unroll
    for (int o = 0; o < 4; ++o) o4[o] = m4[o] * res[o] + (1.f - m4[o]) * c4[o];
    *(f32x4*)(out + ((size_t)(b * C + c) * H + y) * W + x0) = o4;
}

// ---------------------------------------------------------------------------
// Pad v2 (round-6 verified): used only for pin1.
// ---------------------------------------------------------------------------
__global__ void pad_kernel(const float* __restrict__ in, short* __restrict__ pin,
                           int C, int H, int W, int Hp, int Wp, int po,
                           int xt, int nxt) {
    int b = blockIdx.z, yp = blockIdx.y;
    int ct = 256 / xt;
    int xtile = blockIdx.x % nxt;
    int cb = blockIdx.x / nxt;
    int xl = threadIdx.x % xt;
    int cl = threadIdx.x / xt;
    int xp = xtile * xt + xl;
    int c8 = cb * ct + cl;
    if (xp >= Wp) return;

    int y = yp - po, x = xp - po;
    bf16x8 v;
    if (y >= 0 && y < H && x >= 0 && x < W) {
        const float* ip = in + ((size_t)(b * C + c8 * 8) * H + y) * W + x;
        size_t HW = (size_t)H * W;
#pragma unroll
        for (int k = 0; k < 8; ++k) v[k] = f2bf(ip[k * HW]);
    } else {
        v = (bf16x8)0;
    }
    *(bf16x8*)(pin + (((size_t)b * Hp + yp) * Wp + xp) * C + c8 * 8) = v;
}

// ---------------------------------------------------------------------------
// zb2: border-only zero of NHWC bf16 pin (round-13 verified).
// ---------------------------------------------------------------------------
__global__ void zb2_kernel(short* __restrict__ buf, int Hp, int Wp, int C8, int mode,
                           int ncell, int total) {
    int tid = blockIdx.x * blockDim.x + threadIdx.x;
    if (tid >= total) return;
    int c8 = tid % C8;
    int cell = (tid / C8) % ncell;
    int b = tid / (C8 * ncell);
    int yp, xp;
    if (mode) {
        if (cell < Wp) { yp = 0; xp = cell; }
        else if (cell < 2 * Wp) { yp = Hp - 1; xp = cell - Wp; }
        else { int r = cell - 2 * Wp; yp = 1 + (r >> 1); xp = (r & 1) ? (Wp - 1) : 0; }
    } else {
        if (cell < Wp) { yp = Hp - 1; xp = cell; }
        else { yp = cell - Wp; xp = Wp - 1; }
    }
    *(bf16x8*)(buf + (((size_t)b * Hp + yp) * Wp + xp) * (C8 * 8) + c8 * 8) = (bf16x8)0;
}

// ---------------------------------------------------------------------------
// Merged weight transform (round-13 verified).
// ---------------------------------------------------------------------------
struct WtAll {
    const float* w[6];
    short* wt[6];
    int Cin[6], Cout[6], Mp[6], stride[6], total[6];
};

__global__ void wtrans_all_kernel(WtAll d) {
    int wi = blockIdx.y;
    int tid = blockIdx.x * blockDim.x + threadIdx.x;
    if (tid >= d.total[wi]) return;
    int Cin = d.Cin[wi], Cout = d.Cout[wi], Mp = d.Mp[wi], stride = d.stride[wi];
    const float* w = d.w[wi];
    short* wt = d.wt[wi];

    int ci = tid % Cin;
    int mm = (tid / Cin) % Mp;
    int t9 = tid / (Cin * Mp);
    int i, j;
    if (stride == 1) {
        int a = t9 / 3, bb = t9 % 3;
        i = 2 - a; j = 2 - bb;
    } else {
        int py, px, a, bb;
        if (t9 == 0) { py = 0; px = 0; a = 0; bb = 0; }
        else if (t9 < 3) { py = 0; px = 1; a = 0; bb = t9 - 1; }
        else if (t9 < 5) { py = 1; px = 0; a = t9 - 3; bb = 0; }
        else { int tt = t9 - 5; py = 1; px = 1; a = tt >> 1; bb = tt & 1; }
        i = (py == 0) ? 1 : (a == 0 ? 2 : 0);
        j = (px == 0) ? 1 : (bb == 0 ? 2 : 0);
    }
    float v = 0.f;
    if (mm < Cout) v = w[((ci * Cout + mm) * 3 + i) * 3 + j];
    wt[tid] = f2bf(v);
}

#define WAITVM(n) asm volatile("s_waitcnt vmcnt(" #n ")" ::: "memory")

// ---------------------------------------------------------------------------
// Implicit-GEMM convT (round-10/12/14 verified), BM x BN tile, 4 waves, BK=64,
// XOR-swizzled LDS. cc outer, taps inner. DBUF: counted-vmcnt 2-phase
// (verified on conv2; now also conv4 -- identical tile/wave config).
// ---------------------------------------------------------------------------
template <int BM, int BN, bool S2, int OUTM, int ACT, bool DBUF>
__global__ void convt_mfma(const short* __restrict__ pin, const short* __restrict__ wtc,
                           float* __restrict__ outf, short* __restrict__ outb,
                           int Hpin, int Wpin, int Cin, int Mp, int Cout,
                           int Ho, int Wo, int Hu, int Wv,
                           int Hop, int Wop, int poff) {
    constexpr int WAVES_M = (BM >= 128) ? 2 : 1;
    constexpr int WM = BM / WAVES_M;
    constexpr int WN = BN / (4 / WAVES_M);
    constexpr int FM = WM / 16, FN = WN / 16;
    constexpr int RB = BN / 32;
    constexpr int AROUND = BM / 32;
    constexpr int NLOAD = AROUND + RB;
    constexpr int ABYTES = BM * 128;
    constexpr int BBYTES = BN * 128;
    __shared__ __align__(16) short Alds[(DBUF ? 2 : 1) * BM * 64];
    __shared__ __align__(16) short Blds[(DBUF ? 2 : 1) * BN * 64];

    int t = threadIdx.x, lane = t & 63, wid = t >> 6;
    int n0 = blockIdx.x * BN, m0 = blockIdx.y * BM;

    int py = 0, px = 0, ny = 3, nx = 3, dys = 0x210, dxs = 0x210, sy = 1;
    const short* wt = wtc;
    if (S2) {
        int pz = blockIdx.z;
        py = pz >> 1; px = pz & 1;
        ny = 1 + py; nx = 1 + px;
        dys = py ? 0x10 : 0; dxs = px ? 0x10 : 0;
        int pre = (pz == 0) ? 0 : (pz == 1) ? 1 : (pz == 2) ? 3 : 5;
        wt = wtc + (size_t)pre * Mp * Cin;
        sy = 2;
    }

    int rowS = t >> 3;
    int dS = (t & 7) ^ (rowS & 7);
    int HuWv = Hu * Wv;
    int pxg[RB];
#pragma unroll
    for (int rb = 0; rb < RB; ++rb) {
        int n = n0 + rowS + rb * 32;
        int b = n / HuWv, r = n % HuWv;
        int u = r / Wv, v = r % Wv;
        pxg[rb] = ((b * Hpin + u) * Wpin + v) * Cin + dS * 8;
    }
    int aoff = (m0 + rowS) * Cin + dS * 8;

    char* AB = (char*)Alds;
    char* BB = (char*)Blds;

    int wm = (WAVES_M == 2) ? (wid & 1) : 0;
    int wn = (WAVES_M == 2) ? (wid >> 1) : wid;
    int cb = lane >> 4;
    int rm[FM], rn[FN];
#pragma unroll
    for (int mf = 0; mf < FM; ++mf) rm[mf] = wm * WM + mf * 16 + (lane & 15);
#pragma unroll
    for (int nf = 0; nf < FN; ++nf) rn[nf] = wn * WN + nf * 16 + (lane & 15);

    f32x4 acc[FM][FN];
#pragma unroll
    for (int mf = 0; mf < FM; ++mf)
#pragma unroll
        for (int nf = 0; nf < FN; ++nf) acc[mf][nf] = (f32x4){0.f, 0.f, 0.f, 0.f};

    int ntap = ny * nx;
    int NK = (Cin >> 6) * ntap;

    auto COMPUTE = [&](int buf) {
        char* ABb = AB + buf * ABYTES;
        char* BBb = BB + buf * BBYTES;
#pragma unroll
        for (int h = 0; h < 2; ++h) {
            bf16x8 av[FM], bv[FN];
#pragma unroll
            for (int mf = 0; mf < FM; ++mf)
                av[mf] = *(const bf16x8*)(ABb + rm[mf] * 128 +
                                          (((h * 4 + cb) ^ (rm[mf] & 7)) << 4));
#pragma unroll
            for (int nf = 0; nf < FN; ++nf)
                bv[nf] = *(const bf16x8*)(BBb + rn[nf] * 128 +
                                          (((h * 4 + cb) ^ (rn[nf] & 7)) << 4));
#pragma unroll
            for (int mf = 0; mf < FM; ++mf)
#pragma unroll
                for (int nf = 0; nf < FN; ++nf)
                    acc[mf][nf] = __builtin_amdgcn_mfma_f32_16x16x32_bf16(
                        av[mf], bv[nf], acc[mf][nf], 0, 0, 0);
        }
    };

    if constexpr (DBUF) {
        auto STAGE = [&](int ks, int buf) {
            int ccq = ks / ntap;
            int ti = ks - ccq * ntap;
            int cc = ccq << 6;
            int a = ti / nx, bxx = ti - (ti / nx) * nx;
            int dy = (dys >> (4 * a)) & 15, dxv = (dxs >> (4 * bxx)) & 15;
            int tapoff = (dy * Wpin + dxv) * Cin;
            const short* wblk = wt + (size_t)ti * Mp * Cin;
            char* ABb = AB + buf * ABYTES;
            char* BBb = BB + buf * BBYTES;
#pragma unroll
            for (int r = 0; r < AROUND; ++r)
                gll16(wblk + cc + aoff + r * 32 * Cin, ABb + r * 4096 + (wid << 10));
#pragma unroll
            for (int rb = 0; rb < RB; ++rb)
                gll16(pin + tapoff + cc + pxg[rb], BBb + rb * 4096 + (wid << 10));
        };

        STAGE(0, 0);
        for (int ks = 0; ks < NK; ++ks) {
            int cur = ks & 1;
            bool more = (ks + 1 < NK);
            if (more) STAGE(ks + 1, cur ^ 1);
            if (more) {
                static_assert(!DBUF || NLOAD == 8, "vmcnt literal");
                WAITVM(8);
            } else {
                WAITVM(0);
            }
            __builtin_amdgcn_sched_barrier(0);
            __builtin_amdgcn_s_barrier();
            __builtin_amdgcn_sched_barrier(0);
            COMPUTE(cur);
            asm volatile("s_waitcnt lgkmcnt(0)" ::: "memory");
            __builtin_amdgcn_sched_barrier(0);
            __builtin_amdgcn_s_barrier();
        }
    } else {
        for (int ks = 0; ks < NK; ++ks) {
            int ccq = ks / ntap;
            int ti = ks - ccq * ntap;
            int cc = ccq << 6;
            int a = ti / nx, bxx = ti - (ti / nx) * nx;
            int dy = (dys >> (4 * a)) & 15, dxv = (dxs >> (4 * bxx)) & 15;
            int tapoff = (dy * Wpin + dxv) * Cin;
            const short* wblk = wt + (size_t)ti * Mp * Cin;
            __syncthreads();
            if (BM >= 32) {
#pragma unroll
                for (int r = 0; r < AROUND; ++r)
                    gll16(wblk + cc + aoff + r * 32 * Cin, AB + r * 4096 + (wid << 10));
            } else {
                if (wid < BM / 8) gll16(wblk + cc + aoff, AB + (wid << 10));
            }
#pragma unroll
            for (int rb = 0; rb < RB; ++rb)
                gll16(pin + tapoff + cc + pxg[rb], BB + rb * 4096 + (wid << 10));
            __syncthreads();
            COMPUTE(0);
        }
    }

#pragma unroll
    for (int mf = 0; mf < FM; ++mf) {
#pragma unroll
        for (int nf = 0; nf < FN; ++nf) {
            int p = n0 + wn * WN + nf * 16 + (lane & 15);
            int b = p / HuWv, r = p % HuWv;
            int u = r / Wv, v = r % Wv;
            int y = sy * u + py, x = sy * v + px;
            int cobase = m0 + wm * WM + mf * 16 + (lane >> 4) * 4;
            f32x4 vv = acc[mf][nf];
            if (OUTM == 1) {
                s16x4 pk;
#pragma unroll
                for (int reg = 0; reg < 4; ++reg) {
                    float f = vv[reg];
                    f = f > 0.f ? f : 0.f;
                    pk[reg] = f2bf(f);
                }
                *(s16x4*)(outb + (((size_t)b * Hop + y + poff) * Wop + (x + poff)) * Cout +
                          cobase) = pk;
            } else {
#pragma unroll
                for (int reg = 0; reg < 4; ++reg) {
                    int co = cobase + reg;
                    if (co < Cout) {
                        float f = vv[reg];
                        if (ACT == 0) f = f > 0.f ? f : 0.f;
                        else f = tanhf(f);
                        outb[((size_t)(b * Cout + co) * Ho + y) * Wo + x] = f2bf(f);
                    }
                }
            }
        }
    }
}

// ---------------------------------------------------------------------------

extern "C" void kernel_launch(void* const* d_in, const int* in_sizes, int n_in,
                              void* d_out, int out_size, void* d_ws, size_t ws_size,
                              hipStream_t stream) {
    const float* cont = (const float*)d_in[0];
    const float* w1 = (const float*)d_in[1];
    const float* w2 = (const float*)d_in[2];
    const float* w3 = (const float*)d_in[3];
    const float* w4 = (const float*)d_in[4];
    const float* w5 = (const float*)d_in[5];
    const float* w6 = (const float*)d_in[6];
    const float* kv0 = (const float*)d_in[7];
    const float* kh0 = (const float*)d_in[8];
    const float* m0 = (const float*)d_in[9];
    const float* kv1 = (const float*)d_in[10];
    const float* kh1 = (const float*)d_in[11];
    const float* m1 = (const float*)d_in[12];
    const float* kv2 = (const float*)d_in[13];
    const float* kh2 = (const float*)d_in[14];
    const float* m2 = (const float*)d_in[15];
    const float* kv3 = (const float*)d_in[16];
    const float* kh3 = (const float*)d_in[17];
    const float* m3 = (const float*)d_in[18];

    float* out = (float*)d_out;
    float* OUT0 = out;
    float* F8 = out + 1572864;
    float* F16 = out + 2097152;
    float* F32 = out + 18874368;

    const size_t MiB = 1 << 20;
    char* wsb = (char*)d_ws;
    short* WT = (short*)wsb;                  // [0,4)
    short* pin1 = (short*)(wsb + 4 * MiB);    // [4,5.2)
    short* t16b = (short*)(wsb + 6 * MiB);    // [6,39.6)
    short* pin2 = (short*)(wsb + 40 * MiB);   // [40,78)
    short* pin3 = (short*)(wsb + 80 * MiB);   // [80,97.8)
    short* t32bb = (short*)(wsb + 6 * MiB);   // [6,39.6)  (t16b dead)
    short* pin4 = (short*)(wsb + 40 * MiB);   // [40,75.7) (pin2 dead)
    short* pin5 = (short*)(wsb + 80 * MiB);   // [80,114.6)(pin3 dead)
    short* pin6 = (short*)(wsb + 6 * MiB);    // [6,75.2)  (t32bb,pin4 dead)
    short* toutb = (short*)(wsb + 76 * MiB);  // [76,79.2)

    short* wt1 = WT;                    // 9*512*64
    short* wt2 = wt1 + 294912;          // 9*256*512
    short* wt3 = wt2 + 1179648;         // 9*128*256
    short* wt4 = wt3 + 294912;          // 9*128*128
    short* wt5 = wt4 + 147456;          // 9*64*128
    short* wt6 = wt5 + 73728;           // 9*16*64

    // merged weight transform: 1 launch
    {
        WtAll d;
        d.w[0] = w1; d.wt[0] = wt1; d.Cin[0] = 64;  d.Cout[0] = 512; d.Mp[0] = 512; d.stride[0] = 2;
        d.w[1] = w2; d.wt[1] = wt2; d.Cin[1] = 512; d.Cout[1] = 256; d.Mp[1] = 256; d.stride[1] = 1;
        d.w[2] = w3; d.wt[2] = wt3; d.Cin[2] = 256; d.Cout[2] = 128; d.Mp[2] = 128; d.stride[2] = 2;
        d.w[3] = w4; d.wt[3] = wt4; d.Cin[3] = 128; d.Cout[3] = 128; d.Mp[3] = 128; d.stride[3] = 1;
        d.w[4] = w5; d.wt[4] = wt5; d.Cin[4] = 128; d.Cout[4] = 64;  d.Mp[4] = 64;  d.stride[4] = 2;
        d.w[5] = w6; d.wt[5] = wt6; d.Cin[5] = 64;  d.Cout[5] = 3;   d.Mp[5] = 16;  d.stride[5] = 1;
        int maxtotal = 0;
        for (int k = 0; k < 6; ++k) {
            d.total[k] = 9 * d.Mp[k] * d.Cin[k];
            if (d.total[k] > maxtotal) maxtotal = d.total[k];
        }
        dim3 g(CDIV(maxtotal, 256), 6);
        wtrans_all_kernel<<<g, 256, 0, stream>>>(d);
    }

    auto zb = [&](short* buf, int Hp, int Wp, int C8, int mode) {
        int ncell = mode ? (2 * Wp + 2 * (Hp - 2)) : (Wp + Hp - 1);
        int total = 32 * ncell * C8;
        zb2_kernel<<<CDIV(total, 256), 256, 0, stream>>>(buf, Hp, Wp, C8, mode, ncell,
                                                         total);
    };
    auto pad = [&](const float* src, short* pin, int C, int H, int W, int Hp, int Wp,
                   int po) {
        int C8 = C >> 3;
        int xt = (C8 >= 16) ? 16 : 32;
        int ct = 256 / xt;
        int nxt = CDIV(Wp, xt);
        dim3 g(nxt * (C8 / ct < 1 ? 1 : C8 / ct), Hp, 32);
        pad_kernel<<<g, 256, 0, stream>>>(src, pin, C, H, W, Hp, Wp, po, xt, nxt);
    };

    // 1. f8 = fusion(cont) -> F8 ; pad1: F8 -> pin1 (17x17x64, po=0)
    {
        int total = 32 * 16 * 16 * (16 >> 2);
        fusionC_kernel<0><<<CDIV(total, 256), 256, 0, stream>>>(cont, kv0, kh0, m0, F8,
                                                                32, 64, 16, 16, total);
    }
    pad(F8, pin1, 64, 16, 16, 17, 17, 0);

    // 2. conv1 (s2): pin1 -> t16b bf16 NCHW [32,512,32,32]
    {
        dim3 g(32 * 16 * 16 / 128, 512 / 128, 4);
        convt_mfma<128, 128, true, 2, 0, false><<<g, 256, 0, stream>>>(
            pin1, wt1, nullptr, t16b, 17, 17, 64, 512, 512, 32, 32, 16, 16, 0, 0, 0);
    }
    // 3. f16 = fusionL(t16b) -> F16 + pin2 (34x34x512 NHWC interior; zb2 borders)
    zb(pin2, 34, 34, 64, 1);
    {
        dim3 g(512 / 32, 32, 32);
        fusionL_kernel<32, 32, 256, true><<<g, 256, 0, stream>>>(
            t16b, kv1, kh1, m1, F16, pin2, 512, 32, 34, 34);
    }
    // 4. conv2 (s1): pin2 -> pin3 (33x33x256 NHWC). DBUF: grid=512=2/CU.
    zb(pin3, 33, 33, 32, 0);
    {
        dim3 g(32 * 32 * 32 / 128, 256 / 128, 1);
        convt_mfma<128, 128, false, 1, 0, true><<<g, 256, 0, stream>>>(
            pin2, wt2, nullptr, pin3, 34, 34, 512, 256, 256, 32, 32, 32, 32, 33, 33, 0);
    }
    // 5. conv3 (s2): pin3 -> t32bb bf16 NCHW [32,128,64,64]
    {
        dim3 g(32 * 32 * 32 / 128, 1, 4);
        convt_mfma<128, 128, true, 2, 0, false><<<g, 256, 0, stream>>>(
            pin3, wt3, nullptr, t32bb, 33, 33, 256, 128, 128, 64, 64, 32, 32, 0, 0, 0);
    }
    // 6. f32 = fusionL(t32bb) -> F32 + pin4 (66x66x128 NHWC interior; zb2 borders)
    zb(pin4, 66, 66, 16, 1);
    {
        dim3 g(128 / 32, 64, 32);
        fusionL_kernel<64, 32, 512, true><<<g, 512, 0, stream>>>(
            t32bb, kv2, kh2, m2, F32, pin4, 128, 64, 66, 66);
    }
    // 7. conv4 (s1): pin4 -> pin5 (65x65x128 NHWC). DBUF (conv2-analog, NK=18).
    zb(pin5, 65, 65, 16, 0);
    {
        dim3 g(32 * 64 * 64 / 128, 1, 1);
        convt_mfma<128, 128, false, 1, 0, true><<<g, 256, 0, stream>>>(
            pin4, wt4, nullptr, pin5, 66, 66, 128, 128, 128, 64, 64, 64, 64, 65, 65, 0);
    }
    // 8. conv5 (s2): pin5 -> pin6 (130x130x64 NHWC, poff=1). BN=256.
    zb(pin6, 130, 130, 8, 1);
    {
        dim3 g(32 * 64 * 64 / 256, 1, 4);
        convt_mfma<64, 256, true, 1, 0, false><<<g, 256, 0, stream>>>(
            pin5, wt5, nullptr, pin6, 65, 65, 128, 64, 64, 128, 128, 64, 64, 130, 130, 1);
    }
    // 9. conv6 (s1): pin6 -> toutb bf16 NCHW [32,3,128,128] tanh. BN=256.
    {
        dim3 g(32 * 128 * 128 / 256, 1, 1);
        convt_mfma<16, 256, false, 2, 1, false><<<g, 256, 0, stream>>>(
            pin6, wt6, nullptr, toutb, 130, 130, 64, 16, 3, 128, 128, 128, 128, 0, 0, 0);
    }
    // 10. out = fusion(toutb) -> OUT0 (C=3, bf16 input)
    {
        int total = 32 * 3 * 128 * (128 >> 2);
        fusion4b_kernel<<<CDIV(total, 256), 256, 0, stream>>>(toutb, kv3, kh3, m3, OUT0,
                                                              32, 3, 128, 128, total);
    }
}